// Round 3
// baseline (561.717 us; speedup 1.0000x reference)
//
#include <hip/hip_runtime.h>
#include <stdint.h>

typedef unsigned int u32;
typedef unsigned long long u64;

#define NCLS 80
#define NBOX 22743
#define PREK 4096
#define BCAP 65536
#define NIMG 8
#define SCORE_TH 0.01f
#define IOU_TH 0.45f
#define TOPK 200

// ---- workspace layout (bytes) ----
#define HIST_OFF 0
#define META_OFF 131072
#define WIN_OFF  131328
#define BND_OFF  393472
#define BOX_OFF  4587776
#define SKEY_OFF 7498880
#define SOBOX_OFF 7761024
#define SAREA_OFF 8285312
#define ZERO_BYTES 131200

__device__ __forceinline__ float sigmf(float x) { return 1.0f / (1.0f + expf(-x)); }

// window-offset for float-bit bins: s in (0.01,1] -> (bits>>14) in [61583, 65024]
#define BIN_BASE 61440u

// wave-aggregated list push: one atomicAdd per wave per call when any lane hits
__device__ __forceinline__ void agg_push(bool pred, u64 kv, int* ctr, u64* list, int cap) {
  u64 m = __ballot(pred);
  if (m == 0ull) return;
  const int lane = (int)(threadIdx.x & 63);
  const int ldr = __builtin_ctzll(m);
  int bpos = 0;
  if (lane == ldr) bpos = atomicAdd(ctr, (int)__popcll(m));
  bpos = __shfl(bpos, ldr);
  if (pred) {
    int pos = bpos + (int)__popcll(m & ((1ull << lane) - 1ull));
    if (pos < cap) list[pos] = kv;
  }
}

// ---------------- decode + hist, vectorized (HW % 4 == 0) ----------------
__global__ __launch_bounds__(256) void decode_hist_v4(const float* __restrict__ in, float4* __restrict__ boxes,
                              u32* __restrict__ hist,
                              int W, int HW, int lvl_off, float stride,
                              float aw0, float ah0, float aw1, float ah1, float aw2, float ah2) {
  __shared__ u32 lh[4096];
  const int img = blockIdx.y;
  for (int i = threadIdx.x; i < 4096; i += 256) lh[i] = 0;
  __syncthreads();

  const int HW4 = HW >> 2;
  const int idx = blockIdx.x * 256 + threadIdx.x;
  const bool act = idx < 3 * HW4;
  const float* base = in;
  float conf[4] = {0.f, 0.f, 0.f, 0.f};
  if (act) {
    const int a = idx / HW4;
    const int p0 = (idx - a * HW4) << 2;
    base = in + ((size_t)(img * 255 + a * 85)) * (size_t)HW + p0;
    const float aw = (a == 0) ? aw0 : ((a == 1) ? aw1 : aw2);
    const float ah = (a == 0) ? ah0 : ((a == 1) ? ah1 : ah2);
    float4 v0 = *(const float4*)(base);
    float4 v1 = *(const float4*)(base + (size_t)HW);
    float4 v2 = *(const float4*)(base + 2 * (size_t)HW);
    float4 v3 = *(const float4*)(base + 3 * (size_t)HW);
    float4 v4 = *(const float4*)(base + 4 * (size_t)HW);
    const float* t0 = (const float*)&v0;
    const float* t1 = (const float*)&v1;
    const float* t2 = (const float*)&v2;
    const float* t3 = (const float*)&v3;
    const float* t4 = (const float*)&v4;
    float4* bout = boxes + (size_t)img * NBOX + lvl_off + a * HW + p0;
#pragma unroll
    for (int i = 0; i < 4; ++i) {
      const int p = p0 + i;
      const int y = p / W, x = p - y * W;
      const float px = sigmf(t0[i]) + (float)x;
      const float py = sigmf(t1[i]) + (float)y;
      const float pw = expf(t2[i]) * aw;
      const float ph = expf(t3[i]) * ah;
      conf[i] = sigmf(t4[i]);
      const float cx = px * stride, cy = py * stride, bw = pw * stride, bh = ph * stride;
      bout[i] = make_float4(cx - bw * 0.5f, cy - bh * 0.5f, cx + bw * 0.5f, cy + bh * 0.5f);
    }
    for (int cc = 0; cc < NCLS; cc += 4) {
      float4 scv[4];
#pragma unroll
      for (int j = 0; j < 4; ++j)
        scv[j] = *(const float4*)(base + (size_t)(5 + cc + j) * HW);
#pragma unroll
      for (int j = 0; j < 4; ++j) {
        const float* s4 = (const float*)&scv[j];
#pragma unroll
        for (int i = 0; i < 4; ++i) {
          float s = conf[i] * sigmf(s4[i]);
          if (s > SCORE_TH) {
            u32 bin = (__float_as_uint(s) >> 14) - BIN_BASE;
            atomicAdd(&lh[bin], 1u);
          }
        }
      }
    }
  }
  __syncthreads();
  u32* gh = hist + (size_t)img * 4096;
  for (int i = threadIdx.x; i < 4096; i += 256) {
    u32 v = lh[i];
    if (v) atomicAdd(&gh[i], v);
  }
}

// ---------------- decode + hist, scalar (level 0) ----------------
__global__ __launch_bounds__(256) void decode_hist_s(const float* __restrict__ in, float4* __restrict__ boxes,
                              u32* __restrict__ hist,
                              int W, int HW, int lvl_off, float stride,
                              float aw0, float ah0, float aw1, float ah1, float aw2, float ah2) {
  __shared__ u32 lh[4096];
  const int img = blockIdx.y;
  for (int i = threadIdx.x; i < 4096; i += 256) lh[i] = 0;
  __syncthreads();

  const int r = blockIdx.x * 256 + threadIdx.x;
  const bool act = r < 3 * HW;
  const float* base = in;
  float conf = 0.f;
  if (act) {
    const int a = r / HW, p = r - a * HW;
    const int y = p / W, x = p - y * W;
    base = in + ((size_t)(img * 255 + a * 85)) * (size_t)HW + p;
    const float aw = (a == 0) ? aw0 : ((a == 1) ? aw1 : aw2);
    const float ah = (a == 0) ? ah0 : ((a == 1) ? ah1 : ah2);
    const float x0 = base[0];
    const float x1 = base[(size_t)HW];
    const float x2 = base[2 * (size_t)HW];
    const float x3 = base[3 * (size_t)HW];
    const float x4 = base[4 * (size_t)HW];
    const float px = sigmf(x0) + (float)x;
    const float py = sigmf(x1) + (float)y;
    const float pw = expf(x2) * aw;
    const float ph = expf(x3) * ah;
    conf = sigmf(x4);
    const float cx = px * stride, cy = py * stride, bw = pw * stride, bh = ph * stride;
    boxes[(size_t)img * NBOX + lvl_off + r] =
        make_float4(cx - bw * 0.5f, cy - bh * 0.5f, cx + bw * 0.5f, cy + bh * 0.5f);
    if (conf > SCORE_TH) {
      for (int cc = 0; cc < NCLS; cc += 4) {
        float l[4];
#pragma unroll
        for (int j = 0; j < 4; ++j) l[j] = base[(size_t)(5 + cc + j) * HW];
#pragma unroll
        for (int j = 0; j < 4; ++j) {
          float s = conf * sigmf(l[j]);
          if (s > SCORE_TH) {
            u32 bin = (__float_as_uint(s) >> 14) - BIN_BASE;
            atomicAdd(&lh[bin], 1u);
          }
        }
      }
    }
  }
  __syncthreads();
  u32* gh = hist + (size_t)img * 4096;
  for (int i = threadIdx.x; i < 4096; i += 256) {
    u32 v = lh[i];
    if (v) atomicAdd(&gh[i], v);
  }
}

// ---------------- find boundary bin B and residual T ----------------
__global__ void scan_k(const u32* __restrict__ hist, int* __restrict__ meta) {
  const int img = blockIdx.x;
  const u32* h = hist + (size_t)img * 4096;
  __shared__ u32 lsum[256];
  __shared__ u32 above[256];
  __shared__ u32 s_total;
  const int t = threadIdx.x;
  u32 s = 0;
  for (int j = 0; j < 16; ++j) s += h[t * 16 + j];
  lsum[t] = s;
  __syncthreads();
  if (t == 0) {
    u32 acc = 0;
    for (int i = 255; i >= 0; --i) { above[i] = acc; acc += lsum[i]; }
    s_total = acc;
  }
  __syncthreads();
  const u32 K = PREK;
  int* m = meta + img * 4;
  if (s_total < K) {
    if (t == 0) { m[0] = -1; m[1] = 0; }
  } else {
    if (above[t] < K && above[t] + lsum[t] >= K) {
      u32 cum = above[t];
      for (int j = 15; j >= 0; --j) {
        u32 hv = h[t * 16 + j];
        cum += hv;
        if (cum >= K) { m[0] = t * 16 + j; m[1] = (int)(K - (cum - hv)); break; }
      }
    }
  }
}

// ---------------- gather, vectorized (HW % 4 == 0) ----------------
__global__ __launch_bounds__(256) void gather_v4(const float* __restrict__ in, int* __restrict__ meta,
                         u64* __restrict__ winners, u64* __restrict__ boundary,
                         int HW, int lvl_off) {
  const int img = blockIdx.y;
  const int HW4 = HW >> 2;
  const int idx = blockIdx.x * 256 + threadIdx.x;
  const bool act = idx < 3 * HW4;
  const int B = meta[img * 4 + 0];
  const float* base = in;
  int boxg0 = 0;
  float conf[4] = {0.f, 0.f, 0.f, 0.f};
  if (act) {
    const int a = idx / HW4;
    const int p0 = (idx - a * HW4) << 2;
    base = in + ((size_t)(img * 255 + a * 85)) * (size_t)HW + p0;
    boxg0 = lvl_off + a * HW + p0;
    float4 v4 = *(const float4*)(base + 4 * (size_t)HW);
    const float* t4 = (const float*)&v4;
#pragma unroll
    for (int i = 0; i < 4; ++i) conf[i] = sigmf(t4[i]);
  }
  u64* wl = winners + (size_t)img * PREK;
  u64* bl = boundary + (size_t)img * BCAP;
  int* cw = &meta[img * 4 + 2];
  int* cb = &meta[img * 4 + 3];
  const float4 dummy = make_float4(-50.f, -50.f, -50.f, -50.f);
  for (int cc = 0; cc < NCLS; cc += 4) {
    float4 scv[4];
#pragma unroll
    for (int j = 0; j < 4; ++j)
      scv[j] = act ? *(const float4*)(base + (size_t)(5 + cc + j) * HW) : dummy;
#pragma unroll
    for (int j = 0; j < 4; ++j) {
      const float* s4 = (const float*)&scv[j];
      const int c = cc + j;
      u32 kb[4]; bool pw[4], pb[4];
      bool anyp = false;
#pragma unroll
      for (int i = 0; i < 4; ++i) {
        float s = conf[i] * sigmf(s4[i]);
        u32 key = __float_as_uint(s);
        int wbin = (int)((key >> 14) - BIN_BASE);
        pw[i] = (s > SCORE_TH) && (wbin > B);
        pb[i] = (s > SCORE_TH) && (wbin == B);
        kb[i] = key;
        anyp |= (pw[i] | pb[i]);
      }
      if (__ballot(anyp) != 0ull) {
#pragma unroll
        for (int i = 0; i < 4; ++i) {
          u64 kv = ((u64)kb[i] << 32) | (u64)(~(u32)((boxg0 + i) * NCLS + c));
          agg_push(pw[i], kv, cw, wl, PREK);
          agg_push(pb[i], kv, cb, bl, BCAP);
        }
      }
    }
  }
}

// ---------------- gather, scalar (level 0) ----------------
__global__ __launch_bounds__(256) void gather_s(const float* __restrict__ in, int* __restrict__ meta,
                         u64* __restrict__ winners, u64* __restrict__ boundary,
                         int HW, int lvl_off) {
  const int img = blockIdx.y;
  const int r = blockIdx.x * 256 + threadIdx.x;
  const bool act0 = r < 3 * HW;
  const int B = meta[img * 4 + 0];
  const float* base = in;
  float conf = 0.f;
  int boxg = 0;
  if (act0) {
    const int a = r / HW, p = r - a * HW;
    base = in + ((size_t)(img * 255 + a * 85)) * (size_t)HW + p;
    conf = sigmf(base[4 * (size_t)HW]);
    boxg = lvl_off + r;
  }
  const bool act = act0 && (conf > SCORE_TH);
  u64* wl = winners + (size_t)img * PREK;
  u64* bl = boundary + (size_t)img * BCAP;
  int* cw = &meta[img * 4 + 2];
  int* cb = &meta[img * 4 + 3];
  for (int cc = 0; cc < NCLS; cc += 4) {
    float l[4];
#pragma unroll
    for (int j = 0; j < 4; ++j) l[j] = act ? base[(size_t)(5 + cc + j) * HW] : -50.f;
#pragma unroll
    for (int j = 0; j < 4; ++j) {
      float s = conf * sigmf(l[j]);
      u32 key = __float_as_uint(s);
      int wbin = (int)((key >> 14) - BIN_BASE);
      bool pw = act && (s > SCORE_TH) && (wbin > B);
      bool pb = act && (s > SCORE_TH) && (wbin == B);
      if (__ballot(pw | pb) != 0ull) {
        u64 kv = ((u64)key << 32) | (u64)(~(u32)(boxg * NCLS + (cc + j)));
        agg_push(pw, kv, cw, wl, PREK);
        agg_push(pb, kv, cb, bl, BCAP);
      }
    }
  }
}

// ---------------- resolve boundary bin: pick exactly T more ----------------
__global__ void resolve_k(const u64* __restrict__ boundary, int* __restrict__ meta,
                          u64* __restrict__ winners) {
  const int img = blockIdx.x;
  const int T = meta[img * 4 + 1];
  int bc = meta[img * 4 + 3];
  if (bc > BCAP) bc = BCAP;
  if (T <= 0 || bc <= 0) return;
  const u64* bnd = boundary + (size_t)img * BCAP;
  u64* wl = winners + (size_t)img * PREK;

  __shared__ u32 h2[16384];
  __shared__ u32 lsum[256];
  __shared__ u32 above[256];
  __shared__ u32 s_total;
  __shared__ int sB2, sT2;
  __shared__ u64 ties[512];
  __shared__ int tcnt;
  const int t = threadIdx.x;
  for (int i = t; i < 16384; i += 256) h2[i] = 0;
  if (t == 0) { tcnt = 0; sB2 = -1; sT2 = 0; }
  __syncthreads();
  for (int i = t; i < bc; i += 256) atomicAdd(&h2[(u32)(bnd[i] >> 32) & 0x3FFFu], 1u);
  __syncthreads();
  u32 s = 0;
  for (int j = 0; j < 64; ++j) s += h2[t * 64 + j];
  lsum[t] = s;
  __syncthreads();
  if (t == 0) {
    u32 acc = 0;
    for (int i = 255; i >= 0; --i) { above[i] = acc; acc += lsum[i]; }
    s_total = acc;
  }
  __syncthreads();
  if ((int)s_total > T) {
    if (above[t] < (u32)T && above[t] + lsum[t] >= (u32)T) {
      u32 cum = above[t];
      for (int j = 63; j >= 0; --j) {
        u32 hv = h2[t * 64 + j];
        cum += hv;
        if (cum >= (u32)T) { sB2 = t * 64 + j; sT2 = (int)((u32)T - (cum - hv)); break; }
      }
    }
  }
  __syncthreads();
  const int B2 = sB2, T2 = sT2;
  for (int i = t; i < bc; i += 256) {
    u64 e = bnd[i];
    int low = (int)((u32)(e >> 32) & 0x3FFFu);
    if (low > B2) {
      int pos = atomicAdd(&meta[img * 4 + 2], 1);
      if (pos < PREK) wl[pos] = e;
    } else if (low == B2) {
      int tp = atomicAdd(&tcnt, 1);
      if (tp < 512) ties[tp] = e;
    }
  }
  __syncthreads();
  if (t == 0 && T2 > 0) {
    int tc = tcnt < 512 ? tcnt : 512;
    for (int k = 0; k < T2 && k < tc; ++k) {
      int bi = -1; u64 bk = 0;
      for (int i = 0; i < tc; ++i)
        if (ties[i] > bk) { bk = ties[i]; bi = i; }  // same score => larger ~idx = smaller idx first
      if (bi < 0) break;
      ties[bi] = 0;
      int pos = atomicAdd(&meta[img * 4 + 2], 1);
      if (pos < PREK) wl[pos] = bk;
    }
  }
}

// ---------------- exact sort by rank (keys unique) ----------------
__global__ __launch_bounds__(256) void rank_k(const u64* __restrict__ winners,
                                              const int* __restrict__ meta,
                                              const float4* __restrict__ boxes,
                                              u64* __restrict__ skey,
                                              float4* __restrict__ sobox,
                                              float* __restrict__ sarea) {
  __shared__ u64 lk[PREK];
  const int img = blockIdx.y;
  const int t = threadIdx.x;
  int wc = meta[img * 4 + 2]; if (wc > PREK) wc = PREK;
  for (int i = t; i < PREK; i += 256)
    lk[i] = (i < wc) ? winners[(size_t)img * PREK + i] : (u64)(~(u32)i);  // distinct pads, below all real keys
  __syncthreads();
  const int i = blockIdx.x * 256 + t;
  const u64 ki = lk[i];
  int rank = 0;
#pragma unroll 8
  for (int j = 0; j < PREK; ++j) rank += (lk[j] > ki) ? 1 : 0;
  skey[(size_t)img * PREK + rank] = ki;
  if (i < wc) {
    u32 ridx = ~(u32)ki;
    int c = (int)(ridx % NCLS);
    int bi = (int)(ridx / NCLS);
    float4 b = boxes[(size_t)img * NBOX + bi];
    float off = 4096.0f * (float)c;
    float4 ob = make_float4(b.x + off, b.y + off, b.z + off, b.w + off);
    sobox[(size_t)img * PREK + rank] = ob;
    sarea[(size_t)img * PREK + rank] = (ob.z - ob.x) * (ob.w - ob.y);
  } else {
    sobox[(size_t)img * PREK + rank] = make_float4(0.f, 0.f, 0.f, 0.f);
    sarea[(size_t)img * PREK + rank] = 0.f;
  }
}

// ---------------- sorted-scan greedy NMS: one wave per image ----------------
__global__ __launch_bounds__(64) void scan_nms_k(const u64* __restrict__ skey,
                                                 const float4* __restrict__ sobox,
                                                 const float* __restrict__ sarea,
                                                 float* __restrict__ out) {
  __shared__ float4 selb[TOPK];
  __shared__ float sela[TOPK];
  const int img = blockIdx.x;
  const int lane = threadIdx.x;
  float* orow = out + (size_t)img * (TOPK * 6);
  for (int i = lane; i < TOPK * 6; i += 64) orow[i] = 0.f;
  const u64* K = skey + (size_t)img * PREK;
  const float4* B = sobox + (size_t)img * PREK;
  const float* A = sarea + (size_t)img * PREK;
  int nsel = 0;
  for (int chunk = 0; chunk < PREK / 64 && nsel < TOPK; ++chunk) {
    const int j = chunk * 64 + lane;
    const u64 kj = K[j];
    const float score = __uint_as_float((u32)(kj >> 32));
    bool alive = (score > SCORE_TH);
    if (__ballot(alive) == 0ull) break;   // sorted: nothing below passes either
    const float4 ob = B[j];
    const float ar = A[j];
    for (int s = 0; s < nsel; ++s) {
      if ((s & 15) == 0 && __ballot(alive) == 0ull) break;
      const float4 sb = selb[s];
      const float sa = sela[s];
      if (alive) {
        float xx1 = fmaxf(sb.x, ob.x), yy1 = fmaxf(sb.y, ob.y);
        float xx2 = fminf(sb.z, ob.z), yy2 = fminf(sb.w, ob.w);
        float inter = fmaxf(xx2 - xx1, 0.f) * fmaxf(yy2 - yy1, 0.f);
        float iou = inter / (sa + ar - inter + 1e-9f);  // ref op order
        if (iou > IOU_TH) alive = false;
      }
    }
    u64 am = __ballot(alive);
    while (am != 0ull && nsel < TOPK) {
      const int b = __builtin_ctzll(am);
      const float bx = __shfl(ob.x, b), by = __shfl(ob.y, b);
      const float bz = __shfl(ob.z, b), bw = __shfl(ob.w, b);
      const float ba = __shfl(ar, b);
      if (lane == b) {
        selb[nsel] = ob; sela[nsel] = ar;
        u32 ridx = ~(u32)kj;
        int c = (int)(ridx % NCLS);
        float off = 4096.0f * (float)c;
        orow[nsel * 6 + 0] = ob.x - off;
        orow[nsel * 6 + 1] = ob.y - off;
        orow[nsel * 6 + 2] = ob.z - off;
        orow[nsel * 6 + 3] = ob.w - off;
        orow[nsel * 6 + 4] = (float)c;
        orow[nsel * 6 + 5] = score;
        alive = false;
      }
      nsel++;
      if (alive && lane > b) {
        float xx1 = fmaxf(bx, ob.x), yy1 = fmaxf(by, ob.y);
        float xx2 = fminf(bz, ob.z), yy2 = fminf(bw, ob.w);
        float inter = fmaxf(xx2 - xx1, 0.f) * fmaxf(yy2 - yy1, 0.f);
        float iou = inter / (ba + ar - inter + 1e-9f);
        if (iou > IOU_TH) alive = false;
      }
      am = __ballot(alive);
    }
  }
}

extern "C" void kernel_launch(void* const* d_in, const int* in_sizes, int n_in,
                              void* d_out, int out_size, void* d_ws, size_t ws_size,
                              hipStream_t stream) {
  const float* in0 = (const float*)d_in[0];
  const float* in1 = (const float*)d_in[5];
  const float* in2 = (const float*)d_in[10];
  char* ws = (char*)d_ws;
  u32* hist = (u32*)(ws + HIST_OFF);
  int* meta = (int*)(ws + META_OFF);
  u64* winners = (u64*)(ws + WIN_OFF);
  u64* boundary = (u64*)(ws + BND_OFF);
  float4* boxes = (float4*)(ws + BOX_OFF);
  u64* skey = (u64*)(ws + SKEY_OFF);
  float4* sobox = (float4*)(ws + SOBOX_OFF);
  float* sarea = (float*)(ws + SAREA_OFF);
  float* out = (float*)d_out;

  hipMemsetAsync(d_ws, 0, ZERO_BYTES, stream);

  // level 0: 19x19 (HW=361, odd) -> scalar; levels 1/2 vectorized (HW%4==0)
  decode_hist_s<<<dim3(5, 8), 256, 0, stream>>>(in0, boxes, hist, 19, 361, 0, 32.f,
                                                3.625f, 2.8125f, 4.875f, 6.1875f, 11.65625f, 10.1875f);
  decode_hist_v4<<<dim3(5, 8), 256, 0, stream>>>(in1, boxes, hist, 38, 1444, 1083, 16.f,
                                                 1.875f, 3.8125f, 3.875f, 2.8125f, 3.6875f, 7.4375f);
  decode_hist_v4<<<dim3(17, 8), 256, 0, stream>>>(in2, boxes, hist, 76, 5776, 5415, 8.f,
                                                  1.25f, 1.625f, 2.f, 3.75f, 4.125f, 2.875f);

  scan_k<<<8, 256, 0, stream>>>(hist, meta);

  gather_s<<<dim3(5, 8), 256, 0, stream>>>(in0, meta, winners, boundary, 361, 0);
  gather_v4<<<dim3(5, 8), 256, 0, stream>>>(in1, meta, winners, boundary, 1444, 1083);
  gather_v4<<<dim3(17, 8), 256, 0, stream>>>(in2, meta, winners, boundary, 5776, 5415);

  resolve_k<<<8, 256, 0, stream>>>(boundary, meta, winners);

  rank_k<<<dim3(16, 8), 256, 0, stream>>>(winners, meta, boxes, skey, sobox, sarea);
  scan_nms_k<<<8, 64, 0, stream>>>(skey, sobox, sarea, out);
}

// Round 4
// 444.426 us; speedup vs baseline: 1.2639x; 1.2639x over previous
//
#include <hip/hip_runtime.h>
#include <stdint.h>

typedef unsigned int u32;
typedef unsigned long long u64;

#define NCLS 80
#define NBOX 22743
#define PREK 4096
#define BCAP 65536
#define NIMG 8
#define SCORE_TH 0.01f
#define IOU_TH 0.45f
#define TOPK 200

// class-chunking: decode = 4 chunks x 20 classes, gather = 8 chunks x 10 classes
#define DCH 20
#define DNCH 4
#define GCH 10
#define GNCH 8

// ---- workspace layout (bytes) ----
#define HIST_OFF 0
#define META_OFF 131072
#define WIN_OFF  131328
#define BND_OFF  393472
#define BOX_OFF  4587776
#define SKEY_OFF 7498880
#define SOBOX_OFF 7761024
#define SAREA_OFF 8285312
#define ZERO_BYTES 131200

__device__ __forceinline__ float sigmf(float x) { return 1.0f / (1.0f + expf(-x)); }

// window-offset for float-bit bins: s in (0.01,1] -> (bits>>14) in [61583, 65024]
#define BIN_BASE 61440u

// wave-aggregated list push: one atomicAdd per wave per call when any lane hits
__device__ __forceinline__ void agg_push(bool pred, u64 kv, int* ctr, u64* list, int cap) {
  u64 m = __ballot(pred);
  if (m == 0ull) return;
  const int lane = (int)(threadIdx.x & 63);
  const int ldr = __builtin_ctzll(m);
  int bpos = 0;
  if (lane == ldr) bpos = atomicAdd(ctr, (int)__popcll(m));
  bpos = __shfl(bpos, ldr);
  if (pred) {
    int pos = bpos + (int)__popcll(m & ((1ull << lane) - 1ull));
    if (pos < cap) list[pos] = kv;
  }
}

// ---------------- decode + hist, vectorized (HW % 4 == 0), class-chunked ----------------
__global__ __launch_bounds__(256) void decode_hist_v4(const float* __restrict__ in, float4* __restrict__ boxes,
                              u32* __restrict__ hist,
                              int W, int HW, int lvl_off, float stride,
                              float aw0, float ah0, float aw1, float ah1, float aw2, float ah2) {
  __shared__ u32 lh[4096];
  const int img = blockIdx.y;
  const int c0 = blockIdx.z * DCH;
  for (int i = threadIdx.x; i < 4096; i += 256) lh[i] = 0;
  __syncthreads();

  const int HW4 = HW >> 2;
  const int idx = blockIdx.x * 256 + threadIdx.x;
  const bool act = idx < 3 * HW4;
  if (act) {
    const int a = idx / HW4;
    const int p0 = (idx - a * HW4) << 2;
    const float* base = in + ((size_t)(img * 255 + a * 85)) * (size_t)HW + p0;
    // issue all class-channel loads up front (deep MLP)
    float4 scv[DCH];
#pragma unroll
    for (int k = 0; k < DCH; ++k)
      scv[k] = *(const float4*)(base + (size_t)(5 + c0 + k) * HW);
    float4 v4 = *(const float4*)(base + 4 * (size_t)HW);
    const float* t4 = (const float*)&v4;
    float conf[4];
    if (c0 == 0) {  // chunk 0 also decodes boxes
      const float aw = (a == 0) ? aw0 : ((a == 1) ? aw1 : aw2);
      const float ah = (a == 0) ? ah0 : ((a == 1) ? ah1 : ah2);
      float4 v0 = *(const float4*)(base);
      float4 v1 = *(const float4*)(base + (size_t)HW);
      float4 v2 = *(const float4*)(base + 2 * (size_t)HW);
      float4 v3 = *(const float4*)(base + 3 * (size_t)HW);
      const float* t0 = (const float*)&v0;
      const float* t1 = (const float*)&v1;
      const float* t2 = (const float*)&v2;
      const float* t3 = (const float*)&v3;
      float4* bout = boxes + (size_t)img * NBOX + lvl_off + a * HW + p0;
#pragma unroll
      for (int i = 0; i < 4; ++i) {
        const int p = p0 + i;
        const int y = p / W, x = p - y * W;
        const float px = sigmf(t0[i]) + (float)x;
        const float py = sigmf(t1[i]) + (float)y;
        const float pw = expf(t2[i]) * aw;
        const float ph = expf(t3[i]) * ah;
        const float cx = px * stride, cy = py * stride, bw = pw * stride, bh = ph * stride;
        bout[i] = make_float4(cx - bw * 0.5f, cy - bh * 0.5f, cx + bw * 0.5f, cy + bh * 0.5f);
      }
    }
#pragma unroll
    for (int i = 0; i < 4; ++i) conf[i] = sigmf(t4[i]);
#pragma unroll
    for (int k = 0; k < DCH; ++k) {
      const float* s4 = (const float*)&scv[k];
#pragma unroll
      for (int i = 0; i < 4; ++i) {
        float s = conf[i] * sigmf(s4[i]);
        if (s > SCORE_TH) {
          u32 bin = (__float_as_uint(s) >> 14) - BIN_BASE;
          atomicAdd(&lh[bin], 1u);
        }
      }
    }
  }
  __syncthreads();
  u32* gh = hist + (size_t)img * 4096;
  for (int i = threadIdx.x; i < 4096; i += 256) {
    u32 v = lh[i];
    if (v) atomicAdd(&gh[i], v);
  }
}

// ---------------- decode + hist, scalar (level 0), class-chunked ----------------
__global__ __launch_bounds__(256) void decode_hist_s(const float* __restrict__ in, float4* __restrict__ boxes,
                              u32* __restrict__ hist,
                              int W, int HW, int lvl_off, float stride,
                              float aw0, float ah0, float aw1, float ah1, float aw2, float ah2) {
  __shared__ u32 lh[4096];
  const int img = blockIdx.y;
  const int c0 = blockIdx.z * DCH;
  for (int i = threadIdx.x; i < 4096; i += 256) lh[i] = 0;
  __syncthreads();

  const int r = blockIdx.x * 256 + threadIdx.x;
  const bool act = r < 3 * HW;
  if (act) {
    const int a = r / HW, p = r - a * HW;
    const int y = p / W, x = p - y * W;
    const float* base = in + ((size_t)(img * 255 + a * 85)) * (size_t)HW + p;
    float l[DCH];
#pragma unroll
    for (int k = 0; k < DCH; ++k) l[k] = base[(size_t)(5 + c0 + k) * HW];
    const float x4 = base[4 * (size_t)HW];
    if (c0 == 0) {
      const float aw = (a == 0) ? aw0 : ((a == 1) ? aw1 : aw2);
      const float ah = (a == 0) ? ah0 : ((a == 1) ? ah1 : ah2);
      const float x0 = base[0];
      const float x1 = base[(size_t)HW];
      const float x2 = base[2 * (size_t)HW];
      const float x3 = base[3 * (size_t)HW];
      const float px = sigmf(x0) + (float)x;
      const float py = sigmf(x1) + (float)y;
      const float pw = expf(x2) * aw;
      const float ph = expf(x3) * ah;
      const float cx = px * stride, cy = py * stride, bw = pw * stride, bh = ph * stride;
      boxes[(size_t)img * NBOX + lvl_off + r] =
          make_float4(cx - bw * 0.5f, cy - bh * 0.5f, cx + bw * 0.5f, cy + bh * 0.5f);
    }
    const float conf = sigmf(x4);
    if (conf > SCORE_TH) {
#pragma unroll
      for (int k = 0; k < DCH; ++k) {
        float s = conf * sigmf(l[k]);
        if (s > SCORE_TH) {
          u32 bin = (__float_as_uint(s) >> 14) - BIN_BASE;
          atomicAdd(&lh[bin], 1u);
        }
      }
    }
  }
  __syncthreads();
  u32* gh = hist + (size_t)img * 4096;
  for (int i = threadIdx.x; i < 4096; i += 256) {
    u32 v = lh[i];
    if (v) atomicAdd(&gh[i], v);
  }
}

// ---------------- find boundary bin B and residual T ----------------
__global__ void scan_k(const u32* __restrict__ hist, int* __restrict__ meta) {
  const int img = blockIdx.x;
  const u32* h = hist + (size_t)img * 4096;
  __shared__ u32 lsum[256];
  __shared__ u32 above[256];
  __shared__ u32 s_total;
  const int t = threadIdx.x;
  u32 s = 0;
  for (int j = 0; j < 16; ++j) s += h[t * 16 + j];
  lsum[t] = s;
  __syncthreads();
  if (t == 0) {
    u32 acc = 0;
    for (int i = 255; i >= 0; --i) { above[i] = acc; acc += lsum[i]; }
    s_total = acc;
  }
  __syncthreads();
  const u32 K = PREK;
  int* m = meta + img * 4;
  if (s_total < K) {
    if (t == 0) { m[0] = -1; m[1] = 0; }
  } else {
    if (above[t] < K && above[t] + lsum[t] >= K) {
      u32 cum = above[t];
      for (int j = 15; j >= 0; --j) {
        u32 hv = h[t * 16 + j];
        cum += hv;
        if (cum >= K) { m[0] = t * 16 + j; m[1] = (int)(K - (cum - hv)); break; }
      }
    }
  }
}

// ---------------- gather, vectorized (HW % 4 == 0), class-chunked ----------------
__global__ __launch_bounds__(256) void gather_v4(const float* __restrict__ in, int* __restrict__ meta,
                         u64* __restrict__ winners, u64* __restrict__ boundary,
                         int HW, int lvl_off) {
  const int img = blockIdx.y;
  const int c0 = blockIdx.z * GCH;
  const int HW4 = HW >> 2;
  const int idx = blockIdx.x * 256 + threadIdx.x;
  const bool act = idx < 3 * HW4;
  const int B = meta[img * 4 + 0];
  int boxg0 = 0;
  float conf[4] = {0.f, 0.f, 0.f, 0.f};
  float4 scv[GCH];
#pragma unroll
  for (int k = 0; k < GCH; ++k) scv[k] = make_float4(-50.f, -50.f, -50.f, -50.f);
  if (act) {
    const int a = idx / HW4;
    const int p0 = (idx - a * HW4) << 2;
    const float* base = in + ((size_t)(img * 255 + a * 85)) * (size_t)HW + p0;
    boxg0 = lvl_off + a * HW + p0;
#pragma unroll
    for (int k = 0; k < GCH; ++k)
      scv[k] = *(const float4*)(base + (size_t)(5 + c0 + k) * HW);
    float4 v4 = *(const float4*)(base + 4 * (size_t)HW);
    const float* t4 = (const float*)&v4;
#pragma unroll
    for (int i = 0; i < 4; ++i) conf[i] = sigmf(t4[i]);
  }
  u64* wl = winners + (size_t)img * PREK;
  u64* bl = boundary + (size_t)img * BCAP;
  int* cw = &meta[img * 4 + 2];
  int* cb = &meta[img * 4 + 3];
#pragma unroll
  for (int k = 0; k < GCH; ++k) {
    const float* s4 = (const float*)&scv[k];
    const int c = c0 + k;
    u32 kb[4]; bool pw[4], pb[4];
    bool anyp = false;
#pragma unroll
    for (int i = 0; i < 4; ++i) {
      float s = conf[i] * sigmf(s4[i]);
      u32 key = __float_as_uint(s);
      int wbin = (int)((key >> 14) - BIN_BASE);
      pw[i] = (s > SCORE_TH) && (wbin > B);
      pb[i] = (s > SCORE_TH) && (wbin == B);
      kb[i] = key;
      anyp |= (pw[i] | pb[i]);
    }
    if (__ballot(anyp) != 0ull) {
#pragma unroll
      for (int i = 0; i < 4; ++i) {
        u64 kv = ((u64)kb[i] << 32) | (u64)(~(u32)((boxg0 + i) * NCLS + c));
        agg_push(pw[i], kv, cw, wl, PREK);
        agg_push(pb[i], kv, cb, bl, BCAP);
      }
    }
  }
}

// ---------------- gather, scalar (level 0), class-chunked ----------------
__global__ __launch_bounds__(256) void gather_s(const float* __restrict__ in, int* __restrict__ meta,
                         u64* __restrict__ winners, u64* __restrict__ boundary,
                         int HW, int lvl_off) {
  const int img = blockIdx.y;
  const int c0 = blockIdx.z * GCH;
  const int r = blockIdx.x * 256 + threadIdx.x;
  const bool act0 = r < 3 * HW;
  const int B = meta[img * 4 + 0];
  float conf = 0.f;
  int boxg = 0;
  float l[GCH];
#pragma unroll
  for (int k = 0; k < GCH; ++k) l[k] = -50.f;
  if (act0) {
    const int a = r / HW, p = r - a * HW;
    const float* base = in + ((size_t)(img * 255 + a * 85)) * (size_t)HW + p;
#pragma unroll
    for (int k = 0; k < GCH; ++k) l[k] = base[(size_t)(5 + c0 + k) * HW];
    conf = sigmf(base[4 * (size_t)HW]);
    boxg = lvl_off + r;
  }
  u64* wl = winners + (size_t)img * PREK;
  u64* bl = boundary + (size_t)img * BCAP;
  int* cw = &meta[img * 4 + 2];
  int* cb = &meta[img * 4 + 3];
#pragma unroll
  for (int k = 0; k < GCH; ++k) {
    float s = conf * sigmf(l[k]);
    u32 key = __float_as_uint(s);
    int wbin = (int)((key >> 14) - BIN_BASE);
    bool pw = (s > SCORE_TH) && (wbin > B);
    bool pb = (s > SCORE_TH) && (wbin == B);
    if (__ballot(pw | pb) != 0ull) {
      u64 kv = ((u64)key << 32) | (u64)(~(u32)(boxg * NCLS + (c0 + k)));
      agg_push(pw, kv, cw, wl, PREK);
      agg_push(pb, kv, cb, bl, BCAP);
    }
  }
}

// ---------------- resolve boundary bin: pick exactly T more ----------------
__global__ void resolve_k(const u64* __restrict__ boundary, int* __restrict__ meta,
                          u64* __restrict__ winners) {
  const int img = blockIdx.x;
  const int T = meta[img * 4 + 1];
  int bc = meta[img * 4 + 3];
  if (bc > BCAP) bc = BCAP;
  if (T <= 0 || bc <= 0) return;
  const u64* bnd = boundary + (size_t)img * BCAP;
  u64* wl = winners + (size_t)img * PREK;

  __shared__ u32 h2[16384];
  __shared__ u32 lsum[256];
  __shared__ u32 above[256];
  __shared__ u32 s_total;
  __shared__ int sB2, sT2;
  __shared__ u64 ties[512];
  __shared__ int tcnt;
  const int t = threadIdx.x;
  for (int i = t; i < 16384; i += 256) h2[i] = 0;
  if (t == 0) { tcnt = 0; sB2 = -1; sT2 = 0; }
  __syncthreads();
  for (int i = t; i < bc; i += 256) atomicAdd(&h2[(u32)(bnd[i] >> 32) & 0x3FFFu], 1u);
  __syncthreads();
  u32 s = 0;
  for (int j = 0; j < 64; ++j) s += h2[t * 64 + j];
  lsum[t] = s;
  __syncthreads();
  if (t == 0) {
    u32 acc = 0;
    for (int i = 255; i >= 0; --i) { above[i] = acc; acc += lsum[i]; }
    s_total = acc;
  }
  __syncthreads();
  if ((int)s_total > T) {
    if (above[t] < (u32)T && above[t] + lsum[t] >= (u32)T) {
      u32 cum = above[t];
      for (int j = 63; j >= 0; --j) {
        u32 hv = h2[t * 64 + j];
        cum += hv;
        if (cum >= (u32)T) { sB2 = t * 64 + j; sT2 = (int)((u32)T - (cum - hv)); break; }
      }
    }
  }
  __syncthreads();
  const int B2 = sB2, T2 = sT2;
  for (int i = t; i < bc; i += 256) {
    u64 e = bnd[i];
    int low = (int)((u32)(e >> 32) & 0x3FFFu);
    if (low > B2) {
      int pos = atomicAdd(&meta[img * 4 + 2], 1);
      if (pos < PREK) wl[pos] = e;
    } else if (low == B2) {
      int tp = atomicAdd(&tcnt, 1);
      if (tp < 512) ties[tp] = e;
    }
  }
  __syncthreads();
  if (t == 0 && T2 > 0) {
    int tc = tcnt < 512 ? tcnt : 512;
    for (int k = 0; k < T2 && k < tc; ++k) {
      int bi = -1; u64 bk = 0;
      for (int i = 0; i < tc; ++i)
        if (ties[i] > bk) { bk = ties[i]; bi = i; }  // same score => larger ~idx = smaller idx first
      if (bi < 0) break;
      ties[bi] = 0;
      int pos = atomicAdd(&meta[img * 4 + 2], 1);
      if (pos < PREK) wl[pos] = bk;
    }
  }
}

// ---------------- exact sort by rank (keys unique) ----------------
__global__ __launch_bounds__(256) void rank_k(const u64* __restrict__ winners,
                                              const int* __restrict__ meta,
                                              const float4* __restrict__ boxes,
                                              u64* __restrict__ skey,
                                              float4* __restrict__ sobox,
                                              float* __restrict__ sarea) {
  __shared__ u64 lk[PREK];
  const int img = blockIdx.y;
  const int t = threadIdx.x;
  int wc = meta[img * 4 + 2]; if (wc > PREK) wc = PREK;
  for (int i = t; i < PREK; i += 256)
    lk[i] = (i < wc) ? winners[(size_t)img * PREK + i] : (u64)(~(u32)i);  // distinct pads, below all real keys
  __syncthreads();
  const int i = blockIdx.x * 256 + t;
  const u64 ki = lk[i];
  int rank = 0;
#pragma unroll 8
  for (int j = 0; j < PREK; ++j) rank += (lk[j] > ki) ? 1 : 0;
  skey[(size_t)img * PREK + rank] = ki;
  if (i < wc) {
    u32 ridx = ~(u32)ki;
    int c = (int)(ridx % NCLS);
    int bi = (int)(ridx / NCLS);
    float4 b = boxes[(size_t)img * NBOX + bi];
    float off = 4096.0f * (float)c;
    float4 ob = make_float4(b.x + off, b.y + off, b.z + off, b.w + off);
    sobox[(size_t)img * PREK + rank] = ob;
    sarea[(size_t)img * PREK + rank] = (ob.z - ob.x) * (ob.w - ob.y);
  } else {
    sobox[(size_t)img * PREK + rank] = make_float4(0.f, 0.f, 0.f, 0.f);
    sarea[(size_t)img * PREK + rank] = 0.f;
  }
}

// ---------------- sorted-scan greedy NMS: one wave per image ----------------
__global__ __launch_bounds__(64) void scan_nms_k(const u64* __restrict__ skey,
                                                 const float4* __restrict__ sobox,
                                                 const float* __restrict__ sarea,
                                                 float* __restrict__ out) {
  __shared__ float4 selb[TOPK];
  __shared__ float sela[TOPK];
  const int img = blockIdx.x;
  const int lane = threadIdx.x;
  float* orow = out + (size_t)img * (TOPK * 6);
  for (int i = lane; i < TOPK * 6; i += 64) orow[i] = 0.f;
  const u64* K = skey + (size_t)img * PREK;
  const float4* B = sobox + (size_t)img * PREK;
  const float* A = sarea + (size_t)img * PREK;
  int nsel = 0;
  for (int chunk = 0; chunk < PREK / 64 && nsel < TOPK; ++chunk) {
    const int j = chunk * 64 + lane;
    const u64 kj = K[j];
    const float score = __uint_as_float((u32)(kj >> 32));
    bool alive = (score > SCORE_TH);
    if (__ballot(alive) == 0ull) break;   // sorted: nothing below passes either
    const float4 ob = B[j];
    const float ar = A[j];
    for (int s = 0; s < nsel; ++s) {
      if ((s & 15) == 0 && __ballot(alive) == 0ull) break;
      const float4 sb = selb[s];
      const float sa = sela[s];
      if (alive) {
        float xx1 = fmaxf(sb.x, ob.x), yy1 = fmaxf(sb.y, ob.y);
        float xx2 = fminf(sb.z, ob.z), yy2 = fminf(sb.w, ob.w);
        float inter = fmaxf(xx2 - xx1, 0.f) * fmaxf(yy2 - yy1, 0.f);
        float iou = inter / (sa + ar - inter + 1e-9f);  // ref op order
        if (iou > IOU_TH) alive = false;
      }
    }
    u64 am = __ballot(alive);
    while (am != 0ull && nsel < TOPK) {
      const int b = __builtin_ctzll(am);
      const float bx = __shfl(ob.x, b), by = __shfl(ob.y, b);
      const float bz = __shfl(ob.z, b), bw = __shfl(ob.w, b);
      const float ba = __shfl(ar, b);
      if (lane == b) {
        selb[nsel] = ob; sela[nsel] = ar;
        u32 ridx = ~(u32)kj;
        int c = (int)(ridx % NCLS);
        float off = 4096.0f * (float)c;
        orow[nsel * 6 + 0] = ob.x - off;
        orow[nsel * 6 + 1] = ob.y - off;
        orow[nsel * 6 + 2] = ob.z - off;
        orow[nsel * 6 + 3] = ob.w - off;
        orow[nsel * 6 + 4] = (float)c;
        orow[nsel * 6 + 5] = score;
        alive = false;
      }
      nsel++;
      if (alive && lane > b) {
        float xx1 = fmaxf(bx, ob.x), yy1 = fmaxf(by, ob.y);
        float xx2 = fminf(bz, ob.z), yy2 = fminf(bw, ob.w);
        float inter = fmaxf(xx2 - xx1, 0.f) * fmaxf(yy2 - yy1, 0.f);
        float iou = inter / (ba + ar - inter + 1e-9f);
        if (iou > IOU_TH) alive = false;
      }
      am = __ballot(alive);
    }
  }
}

extern "C" void kernel_launch(void* const* d_in, const int* in_sizes, int n_in,
                              void* d_out, int out_size, void* d_ws, size_t ws_size,
                              hipStream_t stream) {
  const float* in0 = (const float*)d_in[0];
  const float* in1 = (const float*)d_in[5];
  const float* in2 = (const float*)d_in[10];
  char* ws = (char*)d_ws;
  u32* hist = (u32*)(ws + HIST_OFF);
  int* meta = (int*)(ws + META_OFF);
  u64* winners = (u64*)(ws + WIN_OFF);
  u64* boundary = (u64*)(ws + BND_OFF);
  float4* boxes = (float4*)(ws + BOX_OFF);
  u64* skey = (u64*)(ws + SKEY_OFF);
  float4* sobox = (float4*)(ws + SOBOX_OFF);
  float* sarea = (float*)(ws + SAREA_OFF);
  float* out = (float*)d_out;

  hipMemsetAsync(d_ws, 0, ZERO_BYTES, stream);

  // level 0: 19x19 (HW=361, odd) -> scalar; levels 1/2 vectorized (HW%4==0)
  decode_hist_s<<<dim3(5, 8, DNCH), 256, 0, stream>>>(in0, boxes, hist, 19, 361, 0, 32.f,
                                                3.625f, 2.8125f, 4.875f, 6.1875f, 11.65625f, 10.1875f);
  decode_hist_v4<<<dim3(5, 8, DNCH), 256, 0, stream>>>(in1, boxes, hist, 38, 1444, 1083, 16.f,
                                                 1.875f, 3.8125f, 3.875f, 2.8125f, 3.6875f, 7.4375f);
  decode_hist_v4<<<dim3(17, 8, DNCH), 256, 0, stream>>>(in2, boxes, hist, 76, 5776, 5415, 8.f,
                                                  1.25f, 1.625f, 2.f, 3.75f, 4.125f, 2.875f);

  scan_k<<<8, 256, 0, stream>>>(hist, meta);

  gather_s<<<dim3(5, 8, GNCH), 256, 0, stream>>>(in0, meta, winners, boundary, 361, 0);
  gather_v4<<<dim3(5, 8, GNCH), 256, 0, stream>>>(in1, meta, winners, boundary, 1444, 1083);
  gather_v4<<<dim3(17, 8, GNCH), 256, 0, stream>>>(in2, meta, winners, boundary, 5776, 5415);

  resolve_k<<<8, 256, 0, stream>>>(boundary, meta, winners);

  rank_k<<<dim3(16, 8), 256, 0, stream>>>(winners, meta, boxes, skey, sobox, sarea);
  scan_nms_k<<<8, 64, 0, stream>>>(skey, sobox, sarea, out);
}

// Round 5
// 275.651 us; speedup vs baseline: 2.0378x; 1.6123x over previous
//
#include <hip/hip_runtime.h>
#include <stdint.h>

typedef unsigned int u32;
typedef unsigned long long u64;

#define NCLS 80
#define NBOX 22743
#define PREK 4096
#define BCAP 65536
#define NIMG 8
#define SCORE_TH 0.01f
#define IOU_TH 0.45f
#define TOPK 200

// class-chunking: decode = 4 chunks x 20 classes, gather = 8 chunks x 10 classes
#define DCH 20
#define DNCH 4
#define GCH 10
#define GNCH 8

// per-block LDS staging capacity for gather hit lists
#define LCAP 1536

// ---- workspace layout (bytes) ----
// hist u32[8][4096] | meta int[8][4]{B,T,-,-} | cnt int[8][64] (win@0, bnd@32; 256B/img)
// winners u64[8][4096] | boundary u64[8][65536] | boxes float4[8][22743]
// skey u64[8][4096] | sobox float4[8][4096] | sarea float[8][4096]
#define HIST_OFF 0
#define META_OFF 131072
#define CNT_OFF  131200
#define ZERO_BYTES 133248
#define WIN_OFF  133248
#define BND_OFF  395392
#define BOX_OFF  4589696
#define SKEY_OFF 7500800
#define SOBOX_OFF 7762944
#define SAREA_OFF 8287232

__device__ __forceinline__ float sigmf(float x) { return 1.0f / (1.0f + expf(-x)); }

// window-offset for float-bit bins: s in (0.01,1] -> (bits>>14) in [61583, 65024]
#define BIN_BASE 61440u

// ---------------- decode + hist, vectorized (HW % 4 == 0), class-chunked ----------------
__global__ __launch_bounds__(256) void decode_hist_v4(const float* __restrict__ in, float4* __restrict__ boxes,
                              u32* __restrict__ hist,
                              int W, int HW, int lvl_off, float stride,
                              float aw0, float ah0, float aw1, float ah1, float aw2, float ah2) {
  __shared__ u32 lh[4096];
  const int img = blockIdx.y;
  const int c0 = blockIdx.z * DCH;
  for (int i = threadIdx.x; i < 4096; i += 256) lh[i] = 0;
  __syncthreads();

  const int HW4 = HW >> 2;
  const int idx = blockIdx.x * 256 + threadIdx.x;
  const bool act = idx < 3 * HW4;
  if (act) {
    const int a = idx / HW4;
    const int p0 = (idx - a * HW4) << 2;
    const float* base = in + ((size_t)(img * 255 + a * 85)) * (size_t)HW + p0;
    // issue all class-channel loads up front (deep MLP)
    float4 scv[DCH];
#pragma unroll
    for (int k = 0; k < DCH; ++k)
      scv[k] = *(const float4*)(base + (size_t)(5 + c0 + k) * HW);
    float4 v4 = *(const float4*)(base + 4 * (size_t)HW);
    const float* t4 = (const float*)&v4;
    float conf[4];
    if (c0 == 0) {  // chunk 0 also decodes boxes
      const float aw = (a == 0) ? aw0 : ((a == 1) ? aw1 : aw2);
      const float ah = (a == 0) ? ah0 : ((a == 1) ? ah1 : ah2);
      float4 v0 = *(const float4*)(base);
      float4 v1 = *(const float4*)(base + (size_t)HW);
      float4 v2 = *(const float4*)(base + 2 * (size_t)HW);
      float4 v3 = *(const float4*)(base + 3 * (size_t)HW);
      const float* t0 = (const float*)&v0;
      const float* t1 = (const float*)&v1;
      const float* t2 = (const float*)&v2;
      const float* t3 = (const float*)&v3;
      float4* bout = boxes + (size_t)img * NBOX + lvl_off + a * HW + p0;
#pragma unroll
      for (int i = 0; i < 4; ++i) {
        const int p = p0 + i;
        const int y = p / W, x = p - y * W;
        const float px = sigmf(t0[i]) + (float)x;
        const float py = sigmf(t1[i]) + (float)y;
        const float pw = expf(t2[i]) * aw;
        const float ph = expf(t3[i]) * ah;
        const float cx = px * stride, cy = py * stride, bw = pw * stride, bh = ph * stride;
        bout[i] = make_float4(cx - bw * 0.5f, cy - bh * 0.5f, cx + bw * 0.5f, cy + bh * 0.5f);
      }
    }
#pragma unroll
    for (int i = 0; i < 4; ++i) conf[i] = sigmf(t4[i]);
#pragma unroll
    for (int k = 0; k < DCH; ++k) {
      const float* s4 = (const float*)&scv[k];
#pragma unroll
      for (int i = 0; i < 4; ++i) {
        float s = conf[i] * sigmf(s4[i]);
        if (s > SCORE_TH) {
          u32 bin = (__float_as_uint(s) >> 14) - BIN_BASE;
          atomicAdd(&lh[bin], 1u);
        }
      }
    }
  }
  __syncthreads();
  u32* gh = hist + (size_t)img * 4096;
  for (int i = threadIdx.x; i < 4096; i += 256) {
    u32 v = lh[i];
    if (v) atomicAdd(&gh[i], v);
  }
}

// ---------------- decode + hist, scalar (level 0), class-chunked ----------------
__global__ __launch_bounds__(256) void decode_hist_s(const float* __restrict__ in, float4* __restrict__ boxes,
                              u32* __restrict__ hist,
                              int W, int HW, int lvl_off, float stride,
                              float aw0, float ah0, float aw1, float ah1, float aw2, float ah2) {
  __shared__ u32 lh[4096];
  const int img = blockIdx.y;
  const int c0 = blockIdx.z * DCH;
  for (int i = threadIdx.x; i < 4096; i += 256) lh[i] = 0;
  __syncthreads();

  const int r = blockIdx.x * 256 + threadIdx.x;
  const bool act = r < 3 * HW;
  if (act) {
    const int a = r / HW, p = r - a * HW;
    const int y = p / W, x = p - y * W;
    const float* base = in + ((size_t)(img * 255 + a * 85)) * (size_t)HW + p;
    float l[DCH];
#pragma unroll
    for (int k = 0; k < DCH; ++k) l[k] = base[(size_t)(5 + c0 + k) * HW];
    const float x4 = base[4 * (size_t)HW];
    if (c0 == 0) {
      const float aw = (a == 0) ? aw0 : ((a == 1) ? aw1 : aw2);
      const float ah = (a == 0) ? ah0 : ((a == 1) ? ah1 : ah2);
      const float x0 = base[0];
      const float x1 = base[(size_t)HW];
      const float x2 = base[2 * (size_t)HW];
      const float x3 = base[3 * (size_t)HW];
      const float px = sigmf(x0) + (float)x;
      const float py = sigmf(x1) + (float)y;
      const float pw = expf(x2) * aw;
      const float ph = expf(x3) * ah;
      const float cx = px * stride, cy = py * stride, bw = pw * stride, bh = ph * stride;
      boxes[(size_t)img * NBOX + lvl_off + r] =
          make_float4(cx - bw * 0.5f, cy - bh * 0.5f, cx + bw * 0.5f, cy + bh * 0.5f);
    }
    const float conf = sigmf(x4);
    if (conf > SCORE_TH) {
#pragma unroll
      for (int k = 0; k < DCH; ++k) {
        float s = conf * sigmf(l[k]);
        if (s > SCORE_TH) {
          u32 bin = (__float_as_uint(s) >> 14) - BIN_BASE;
          atomicAdd(&lh[bin], 1u);
        }
      }
    }
  }
  __syncthreads();
  u32* gh = hist + (size_t)img * 4096;
  for (int i = threadIdx.x; i < 4096; i += 256) {
    u32 v = lh[i];
    if (v) atomicAdd(&gh[i], v);
  }
}

// ---------------- find boundary bin B and residual T ----------------
__global__ void scan_k(const u32* __restrict__ hist, int* __restrict__ meta) {
  const int img = blockIdx.x;
  const u32* h = hist + (size_t)img * 4096;
  __shared__ u32 lsum[256];
  __shared__ u32 above[256];
  __shared__ u32 s_total;
  const int t = threadIdx.x;
  u32 s = 0;
  for (int j = 0; j < 16; ++j) s += h[t * 16 + j];
  lsum[t] = s;
  __syncthreads();
  if (t == 0) {
    u32 acc = 0;
    for (int i = 255; i >= 0; --i) { above[i] = acc; acc += lsum[i]; }
    s_total = acc;
  }
  __syncthreads();
  const u32 K = PREK;
  int* m = meta + img * 4;
  if (s_total < K) {
    if (t == 0) { m[0] = -1; m[1] = 0; }
  } else {
    if (above[t] < K && above[t] + lsum[t] >= K) {
      u32 cum = above[t];
      for (int j = 15; j >= 0; --j) {
        u32 hv = h[t * 16 + j];
        cum += hv;
        if (cum >= K) { m[0] = t * 16 + j; m[1] = (int)(K - (cum - hv)); break; }
      }
    }
  }
}

// ---- block-staged list flush: one global atomic per list per block ----
__device__ __forceinline__ void flush_list(const u64* llist, int lcnt, int cap,
                                           int* gctr, u64* glist, int gcap) {
  __shared__ int gbase_s;
  int n = lcnt < cap ? lcnt : cap;
  if (threadIdx.x == 0) gbase_s = n ? atomicAdd(gctr, n) : 0;
  __syncthreads();
  const int gb = gbase_s;
  for (int i = threadIdx.x; i < n; i += 256) {
    int pos = gb + i;
    if (pos < gcap) glist[pos] = llist[i];
  }
}

// ---------------- gather, vectorized (HW % 4 == 0), class-chunked, LDS-staged ----------------
__global__ __launch_bounds__(256) void gather_v4(const float* __restrict__ in,
                         const int* __restrict__ meta, int* __restrict__ cnt,
                         u64* __restrict__ winners, u64* __restrict__ boundary,
                         int HW, int lvl_off) {
  __shared__ u64 lwin[LCAP];
  __shared__ u64 lbnd[LCAP];
  __shared__ int lwc, lbc;
  const int img = blockIdx.y;
  const int c0 = blockIdx.z * GCH;
  if (threadIdx.x == 0) { lwc = 0; lbc = 0; }
  __syncthreads();

  const int HW4 = HW >> 2;
  const int idx = blockIdx.x * 256 + threadIdx.x;
  const bool act = idx < 3 * HW4;
  const int B = meta[img * 4 + 0];
  int* cw = &cnt[img * 64];
  int* cb = &cnt[img * 64 + 32];
  u64* wl = winners + (size_t)img * PREK;
  u64* bl = boundary + (size_t)img * BCAP;
  if (act) {
    const int a = idx / HW4;
    const int p0 = (idx - a * HW4) << 2;
    const float* base = in + ((size_t)(img * 255 + a * 85)) * (size_t)HW + p0;
    const int boxg0 = lvl_off + a * HW + p0;
    float4 scv[GCH];
#pragma unroll
    for (int k = 0; k < GCH; ++k)
      scv[k] = *(const float4*)(base + (size_t)(5 + c0 + k) * HW);
    float4 v4 = *(const float4*)(base + 4 * (size_t)HW);
    const float* t4 = (const float*)&v4;
    float conf[4];
#pragma unroll
    for (int i = 0; i < 4; ++i) conf[i] = sigmf(t4[i]);
#pragma unroll
    for (int k = 0; k < GCH; ++k) {
      const float* s4 = (const float*)&scv[k];
      const int c = c0 + k;
#pragma unroll
      for (int i = 0; i < 4; ++i) {
        float s = conf[i] * sigmf(s4[i]);
        if (s > SCORE_TH) {
          u32 key = __float_as_uint(s);
          int wbin = (int)((key >> 14) - BIN_BASE);
          if (wbin >= B) {
            u64 kv = ((u64)key << 32) | (u64)(~(u32)((boxg0 + i) * NCLS + c));
            if (wbin > B) {
              int p = atomicAdd(&lwc, 1);
              if (p < LCAP) lwin[p] = kv;
              else { int g = atomicAdd(cw, 1); if (g < PREK) wl[g] = kv; }  // spill (rare)
            } else {
              int p = atomicAdd(&lbc, 1);
              if (p < LCAP) lbnd[p] = kv;
              else { int g = atomicAdd(cb, 1); if (g < BCAP) bl[g] = kv; }
            }
          }
        }
      }
    }
  }
  __syncthreads();
  flush_list(lwin, lwc, LCAP, cw, wl, PREK);
  flush_list(lbnd, lbc, LCAP, cb, bl, BCAP);
}

// ---------------- gather, scalar (level 0), class-chunked, LDS-staged ----------------
__global__ __launch_bounds__(256) void gather_s(const float* __restrict__ in,
                         const int* __restrict__ meta, int* __restrict__ cnt,
                         u64* __restrict__ winners, u64* __restrict__ boundary,
                         int HW, int lvl_off) {
  __shared__ u64 lwin[LCAP];
  __shared__ u64 lbnd[LCAP];
  __shared__ int lwc, lbc;
  const int img = blockIdx.y;
  const int c0 = blockIdx.z * GCH;
  if (threadIdx.x == 0) { lwc = 0; lbc = 0; }
  __syncthreads();

  const int r = blockIdx.x * 256 + threadIdx.x;
  const bool act = r < 3 * HW;
  const int B = meta[img * 4 + 0];
  int* cw = &cnt[img * 64];
  int* cb = &cnt[img * 64 + 32];
  u64* wl = winners + (size_t)img * PREK;
  u64* bl = boundary + (size_t)img * BCAP;
  if (act) {
    const int a = r / HW, p = r - a * HW;
    const float* base = in + ((size_t)(img * 255 + a * 85)) * (size_t)HW + p;
    const int boxg = lvl_off + r;
    float l[GCH];
#pragma unroll
    for (int k = 0; k < GCH; ++k) l[k] = base[(size_t)(5 + c0 + k) * HW];
    const float conf = sigmf(base[4 * (size_t)HW]);
#pragma unroll
    for (int k = 0; k < GCH; ++k) {
      float s = conf * sigmf(l[k]);
      if (s > SCORE_TH) {
        u32 key = __float_as_uint(s);
        int wbin = (int)((key >> 14) - BIN_BASE);
        if (wbin >= B) {
          u64 kv = ((u64)key << 32) | (u64)(~(u32)(boxg * NCLS + (c0 + k)));
          if (wbin > B) {
            int p2 = atomicAdd(&lwc, 1);
            if (p2 < LCAP) lwin[p2] = kv;
            else { int g = atomicAdd(cw, 1); if (g < PREK) wl[g] = kv; }
          } else {
            int p2 = atomicAdd(&lbc, 1);
            if (p2 < LCAP) lbnd[p2] = kv;
            else { int g = atomicAdd(cb, 1); if (g < BCAP) bl[g] = kv; }
          }
        }
      }
    }
  }
  __syncthreads();
  flush_list(lwin, lwc, LCAP, cw, wl, PREK);
  flush_list(lbnd, lbc, LCAP, cb, bl, BCAP);
}

// ---------------- resolve boundary bin: pick exactly T more ----------------
__global__ void resolve_k(const u64* __restrict__ boundary, const int* __restrict__ meta,
                          int* __restrict__ cnt, u64* __restrict__ winners) {
  const int img = blockIdx.x;
  const int T = meta[img * 4 + 1];
  int bc = cnt[img * 64 + 32];
  if (bc > BCAP) bc = BCAP;
  if (T <= 0 || bc <= 0) return;
  const u64* bnd = boundary + (size_t)img * BCAP;
  u64* wl = winners + (size_t)img * PREK;
  int* cw = &cnt[img * 64];

  __shared__ u32 h2[16384];
  __shared__ u32 lsum[256];
  __shared__ u32 above[256];
  __shared__ u32 s_total;
  __shared__ int sB2, sT2;
  __shared__ u64 ties[512];
  __shared__ int tcnt;
  __shared__ u64 lw2[PREK];
  __shared__ int lw2c;
  __shared__ int gbase_s;
  const int t = threadIdx.x;
  for (int i = t; i < 16384; i += 256) h2[i] = 0;
  if (t == 0) { tcnt = 0; sB2 = -1; sT2 = 0; lw2c = 0; }
  __syncthreads();
  for (int i = t; i < bc; i += 256) atomicAdd(&h2[(u32)(bnd[i] >> 32) & 0x3FFFu], 1u);
  __syncthreads();
  u32 s = 0;
  for (int j = 0; j < 64; ++j) s += h2[t * 64 + j];
  lsum[t] = s;
  __syncthreads();
  if (t == 0) {
    u32 acc = 0;
    for (int i = 255; i >= 0; --i) { above[i] = acc; acc += lsum[i]; }
    s_total = acc;
  }
  __syncthreads();
  if ((int)s_total > T) {
    if (above[t] < (u32)T && above[t] + lsum[t] >= (u32)T) {
      u32 cum = above[t];
      for (int j = 63; j >= 0; --j) {
        u32 hv = h2[t * 64 + j];
        cum += hv;
        if (cum >= (u32)T) { sB2 = t * 64 + j; sT2 = (int)((u32)T - (cum - hv)); break; }
      }
    }
  }
  __syncthreads();
  const int B2 = sB2, T2 = sT2;
  for (int i = t; i < bc; i += 256) {
    u64 e = bnd[i];
    int low = (int)((u32)(e >> 32) & 0x3FFFu);
    if (low > B2) {
      int p = atomicAdd(&lw2c, 1);
      if (p < PREK) lw2[p] = e;
    } else if (low == B2) {
      int tp = atomicAdd(&tcnt, 1);
      if (tp < 512) ties[tp] = e;
    }
  }
  __syncthreads();
  int n = lw2c < PREK ? lw2c : PREK;
  if (t == 0) gbase_s = n ? atomicAdd(cw, n) : 0;
  __syncthreads();
  for (int i = t; i < n; i += 256) {
    int pos = gbase_s + i;
    if (pos < PREK) wl[pos] = lw2[i];
  }
  __syncthreads();
  if (t == 0 && T2 > 0) {
    int tc = tcnt < 512 ? tcnt : 512;
    for (int k = 0; k < T2 && k < tc; ++k) {
      int bi = -1; u64 bk = 0;
      for (int i = 0; i < tc; ++i)
        if (ties[i] > bk) { bk = ties[i]; bi = i; }  // same score => larger ~idx = smaller idx first
      if (bi < 0) break;
      ties[bi] = 0;
      int pos = atomicAdd(cw, 1);
      if (pos < PREK) wl[pos] = bk;
    }
  }
}

// ---------------- exact sort by rank (keys unique) ----------------
__global__ __launch_bounds__(256) void rank_k(const u64* __restrict__ winners,
                                              const int* __restrict__ cnt,
                                              const float4* __restrict__ boxes,
                                              u64* __restrict__ skey,
                                              float4* __restrict__ sobox,
                                              float* __restrict__ sarea) {
  __shared__ u64 lk[PREK];
  const int img = blockIdx.y;
  const int t = threadIdx.x;
  int wc = cnt[img * 64]; if (wc > PREK) wc = PREK;
  for (int i = t; i < PREK; i += 256)
    lk[i] = (i < wc) ? winners[(size_t)img * PREK + i] : (u64)(~(u32)i);  // distinct pads, below all real keys
  __syncthreads();
  const int i = blockIdx.x * 256 + t;
  const u64 ki = lk[i];
  int rank = 0;
#pragma unroll 8
  for (int j = 0; j < PREK; ++j) rank += (lk[j] > ki) ? 1 : 0;
  skey[(size_t)img * PREK + rank] = ki;
  if (i < wc) {
    u32 ridx = ~(u32)ki;
    int c = (int)(ridx % NCLS);
    int bi = (int)(ridx / NCLS);
    float4 b = boxes[(size_t)img * NBOX + bi];
    float off = 4096.0f * (float)c;
    float4 ob = make_float4(b.x + off, b.y + off, b.z + off, b.w + off);
    sobox[(size_t)img * PREK + rank] = ob;
    sarea[(size_t)img * PREK + rank] = (ob.z - ob.x) * (ob.w - ob.y);
  } else {
    sobox[(size_t)img * PREK + rank] = make_float4(0.f, 0.f, 0.f, 0.f);
    sarea[(size_t)img * PREK + rank] = 0.f;
  }
}

// ---------------- sorted-scan greedy NMS: one wave per image ----------------
__global__ __launch_bounds__(64) void scan_nms_k(const u64* __restrict__ skey,
                                                 const float4* __restrict__ sobox,
                                                 const float* __restrict__ sarea,
                                                 float* __restrict__ out) {
  __shared__ float4 selb[TOPK];
  __shared__ float sela[TOPK];
  const int img = blockIdx.x;
  const int lane = threadIdx.x;
  float* orow = out + (size_t)img * (TOPK * 6);
  for (int i = lane; i < TOPK * 6; i += 64) orow[i] = 0.f;
  const u64* K = skey + (size_t)img * PREK;
  const float4* B = sobox + (size_t)img * PREK;
  const float* A = sarea + (size_t)img * PREK;
  int nsel = 0;
  for (int chunk = 0; chunk < PREK / 64 && nsel < TOPK; ++chunk) {
    const int j = chunk * 64 + lane;
    const u64 kj = K[j];
    const float score = __uint_as_float((u32)(kj >> 32));
    bool alive = (score > SCORE_TH);
    if (__ballot(alive) == 0ull) break;   // sorted: nothing below passes either
    const float4 ob = B[j];
    const float ar = A[j];
    for (int s = 0; s < nsel; ++s) {
      if ((s & 15) == 0 && __ballot(alive) == 0ull) break;
      const float4 sb = selb[s];
      const float sa = sela[s];
      if (alive) {
        float xx1 = fmaxf(sb.x, ob.x), yy1 = fmaxf(sb.y, ob.y);
        float xx2 = fminf(sb.z, ob.z), yy2 = fminf(sb.w, ob.w);
        float inter = fmaxf(xx2 - xx1, 0.f) * fmaxf(yy2 - yy1, 0.f);
        float iou = inter / (sa + ar - inter + 1e-9f);  // ref op order
        if (iou > IOU_TH) alive = false;
      }
    }
    u64 am = __ballot(alive);
    while (am != 0ull && nsel < TOPK) {
      const int b = __builtin_ctzll(am);
      const float bx = __shfl(ob.x, b), by = __shfl(ob.y, b);
      const float bz = __shfl(ob.z, b), bw = __shfl(ob.w, b);
      const float ba = __shfl(ar, b);
      if (lane == b) {
        selb[nsel] = ob; sela[nsel] = ar;
        u32 ridx = ~(u32)kj;
        int c = (int)(ridx % NCLS);
        float off = 4096.0f * (float)c;
        orow[nsel * 6 + 0] = ob.x - off;
        orow[nsel * 6 + 1] = ob.y - off;
        orow[nsel * 6 + 2] = ob.z - off;
        orow[nsel * 6 + 3] = ob.w - off;
        orow[nsel * 6 + 4] = (float)c;
        orow[nsel * 6 + 5] = score;
        alive = false;
      }
      nsel++;
      if (alive && lane > b) {
        float xx1 = fmaxf(bx, ob.x), yy1 = fmaxf(by, ob.y);
        float xx2 = fminf(bz, ob.z), yy2 = fminf(bw, ob.w);
        float inter = fmaxf(xx2 - xx1, 0.f) * fmaxf(yy2 - yy1, 0.f);
        float iou = inter / (ba + ar - inter + 1e-9f);
        if (iou > IOU_TH) alive = false;
      }
      am = __ballot(alive);
    }
  }
}

extern "C" void kernel_launch(void* const* d_in, const int* in_sizes, int n_in,
                              void* d_out, int out_size, void* d_ws, size_t ws_size,
                              hipStream_t stream) {
  const float* in0 = (const float*)d_in[0];
  const float* in1 = (const float*)d_in[5];
  const float* in2 = (const float*)d_in[10];
  char* ws = (char*)d_ws;
  u32* hist = (u32*)(ws + HIST_OFF);
  int* meta = (int*)(ws + META_OFF);
  int* cnt = (int*)(ws + CNT_OFF);
  u64* winners = (u64*)(ws + WIN_OFF);
  u64* boundary = (u64*)(ws + BND_OFF);
  float4* boxes = (float4*)(ws + BOX_OFF);
  u64* skey = (u64*)(ws + SKEY_OFF);
  float4* sobox = (float4*)(ws + SOBOX_OFF);
  float* sarea = (float*)(ws + SAREA_OFF);
  float* out = (float*)d_out;

  hipMemsetAsync(d_ws, 0, ZERO_BYTES, stream);

  // level 0: 19x19 (HW=361, odd) -> scalar; levels 1/2 vectorized (HW%4==0)
  decode_hist_s<<<dim3(5, 8, DNCH), 256, 0, stream>>>(in0, boxes, hist, 19, 361, 0, 32.f,
                                                3.625f, 2.8125f, 4.875f, 6.1875f, 11.65625f, 10.1875f);
  decode_hist_v4<<<dim3(5, 8, DNCH), 256, 0, stream>>>(in1, boxes, hist, 38, 1444, 1083, 16.f,
                                                 1.875f, 3.8125f, 3.875f, 2.8125f, 3.6875f, 7.4375f);
  decode_hist_v4<<<dim3(17, 8, DNCH), 256, 0, stream>>>(in2, boxes, hist, 76, 5776, 5415, 8.f,
                                                  1.25f, 1.625f, 2.f, 3.75f, 4.125f, 2.875f);

  scan_k<<<8, 256, 0, stream>>>(hist, meta);

  gather_s<<<dim3(5, 8, GNCH), 256, 0, stream>>>(in0, meta, cnt, winners, boundary, 361, 0);
  gather_v4<<<dim3(5, 8, GNCH), 256, 0, stream>>>(in1, meta, cnt, winners, boundary, 1444, 1083);
  gather_v4<<<dim3(17, 8, GNCH), 256, 0, stream>>>(in2, meta, cnt, winners, boundary, 5776, 5415);

  resolve_k<<<8, 256, 0, stream>>>(boundary, meta, cnt, winners);

  rank_k<<<dim3(16, 8), 256, 0, stream>>>(winners, cnt, boxes, skey, sobox, sarea);
  scan_nms_k<<<8, 64, 0, stream>>>(skey, sobox, sarea, out);
}

// Round 6
// 229.193 us; speedup vs baseline: 2.4509x; 1.2027x over previous
//
#include <hip/hip_runtime.h>
#include <stdint.h>

typedef unsigned int u32;
typedef unsigned long long u64;

#define NCLS 80
#define NBOX 22743
#define PREK 4096
#define BCAP 65536
#define NIMG 8
#define SCORE_TH 0.01f
#define IOU_TH 0.45f
#define TOPK 200

// class-chunking: decode = 4 chunks x 20 classes, gather = 8 chunks x 10 classes
#define DCH 20
#define DNCH 4
#define GCH 10
#define GNCH 8

// per-block LDS staging capacity for gather hit lists
#define LCAP 1536

// NMS class-bucket params. Cross-class suppression requires w_a+w_b > 2*(4096-608)
// (and same in y) since cx,cy in (0,608) => at least one box has w>3488 || h>3488.
#define BKCAP 8
#define HCAP 224
#define HUGE_TH 3488.0f

// ---- workspace layout (bytes) ----
// hist u32[8][4096] | meta int[8][4]{B,T,-,-} | cnt int[8][64] (win@0, bnd@32; 256B/img)
// winners u64[8][4096] | boundary u64[8][65536] | boxes float4[8][22743]
// skey u64[8][4096] | sobox float4[8][4096] | sarea float[8][4096]
#define HIST_OFF 0
#define META_OFF 131072
#define CNT_OFF  131200
#define ZERO_BYTES 133248
#define WIN_OFF  133248
#define BND_OFF  395392
#define BOX_OFF  4589696
#define SKEY_OFF 7500800
#define SOBOX_OFF 7762944
#define SAREA_OFF 8287232

__device__ __forceinline__ float sigmf(float x) { return 1.0f / (1.0f + expf(-x)); }

// window-offset for float-bit bins: s in (0.01,1] -> (bits>>14) in [61583, 65024]
#define BIN_BASE 61440u

// ---------------- decode + hist, vectorized (HW % 4 == 0), class-chunked ----------------
__global__ __launch_bounds__(256) void decode_hist_v4(const float* __restrict__ in, float4* __restrict__ boxes,
                              u32* __restrict__ hist,
                              int W, int HW, int lvl_off, float stride,
                              float aw0, float ah0, float aw1, float ah1, float aw2, float ah2) {
  __shared__ u32 lh[4096];
  const int img = blockIdx.y;
  const int c0 = blockIdx.z * DCH;
  for (int i = threadIdx.x; i < 4096; i += 256) lh[i] = 0;
  __syncthreads();

  const int HW4 = HW >> 2;
  const int idx = blockIdx.x * 256 + threadIdx.x;
  const bool act = idx < 3 * HW4;
  if (act) {
    const int a = idx / HW4;
    const int p0 = (idx - a * HW4) << 2;
    const float* base = in + ((size_t)(img * 255 + a * 85)) * (size_t)HW + p0;
    // issue all class-channel loads up front (deep MLP)
    float4 scv[DCH];
#pragma unroll
    for (int k = 0; k < DCH; ++k)
      scv[k] = *(const float4*)(base + (size_t)(5 + c0 + k) * HW);
    float4 v4 = *(const float4*)(base + 4 * (size_t)HW);
    const float* t4 = (const float*)&v4;
    float conf[4];
    if (c0 == 0) {  // chunk 0 also decodes boxes
      const float aw = (a == 0) ? aw0 : ((a == 1) ? aw1 : aw2);
      const float ah = (a == 0) ? ah0 : ((a == 1) ? ah1 : ah2);
      float4 v0 = *(const float4*)(base);
      float4 v1 = *(const float4*)(base + (size_t)HW);
      float4 v2 = *(const float4*)(base + 2 * (size_t)HW);
      float4 v3 = *(const float4*)(base + 3 * (size_t)HW);
      const float* t0 = (const float*)&v0;
      const float* t1 = (const float*)&v1;
      const float* t2 = (const float*)&v2;
      const float* t3 = (const float*)&v3;
      float4* bout = boxes + (size_t)img * NBOX + lvl_off + a * HW + p0;
#pragma unroll
      for (int i = 0; i < 4; ++i) {
        const int p = p0 + i;
        const int y = p / W, x = p - y * W;
        const float px = sigmf(t0[i]) + (float)x;
        const float py = sigmf(t1[i]) + (float)y;
        const float pw = expf(t2[i]) * aw;
        const float ph = expf(t3[i]) * ah;
        const float cx = px * stride, cy = py * stride, bw = pw * stride, bh = ph * stride;
        bout[i] = make_float4(cx - bw * 0.5f, cy - bh * 0.5f, cx + bw * 0.5f, cy + bh * 0.5f);
      }
    }
#pragma unroll
    for (int i = 0; i < 4; ++i) conf[i] = sigmf(t4[i]);
#pragma unroll
    for (int k = 0; k < DCH; ++k) {
      const float* s4 = (const float*)&scv[k];
#pragma unroll
      for (int i = 0; i < 4; ++i) {
        float s = conf[i] * sigmf(s4[i]);
        if (s > SCORE_TH) {
          u32 bin = (__float_as_uint(s) >> 14) - BIN_BASE;
          atomicAdd(&lh[bin], 1u);
        }
      }
    }
  }
  __syncthreads();
  u32* gh = hist + (size_t)img * 4096;
  for (int i = threadIdx.x; i < 4096; i += 256) {
    u32 v = lh[i];
    if (v) atomicAdd(&gh[i], v);
  }
}

// ---------------- decode + hist, scalar (level 0), class-chunked ----------------
__global__ __launch_bounds__(256) void decode_hist_s(const float* __restrict__ in, float4* __restrict__ boxes,
                              u32* __restrict__ hist,
                              int W, int HW, int lvl_off, float stride,
                              float aw0, float ah0, float aw1, float ah1, float aw2, float ah2) {
  __shared__ u32 lh[4096];
  const int img = blockIdx.y;
  const int c0 = blockIdx.z * DCH;
  for (int i = threadIdx.x; i < 4096; i += 256) lh[i] = 0;
  __syncthreads();

  const int r = blockIdx.x * 256 + threadIdx.x;
  const bool act = r < 3 * HW;
  if (act) {
    const int a = r / HW, p = r - a * HW;
    const int y = p / W, x = p - y * W;
    const float* base = in + ((size_t)(img * 255 + a * 85)) * (size_t)HW + p;
    float l[DCH];
#pragma unroll
    for (int k = 0; k < DCH; ++k) l[k] = base[(size_t)(5 + c0 + k) * HW];
    const float x4 = base[4 * (size_t)HW];
    if (c0 == 0) {
      const float aw = (a == 0) ? aw0 : ((a == 1) ? aw1 : aw2);
      const float ah = (a == 0) ? ah0 : ((a == 1) ? ah1 : ah2);
      const float x0 = base[0];
      const float x1 = base[(size_t)HW];
      const float x2 = base[2 * (size_t)HW];
      const float x3 = base[3 * (size_t)HW];
      const float px = sigmf(x0) + (float)x;
      const float py = sigmf(x1) + (float)y;
      const float pw = expf(x2) * aw;
      const float ph = expf(x3) * ah;
      const float cx = px * stride, cy = py * stride, bw = pw * stride, bh = ph * stride;
      boxes[(size_t)img * NBOX + lvl_off + r] =
          make_float4(cx - bw * 0.5f, cy - bh * 0.5f, cx + bw * 0.5f, cy + bh * 0.5f);
    }
    const float conf = sigmf(x4);
    if (conf > SCORE_TH) {
#pragma unroll
      for (int k = 0; k < DCH; ++k) {
        float s = conf * sigmf(l[k]);
        if (s > SCORE_TH) {
          u32 bin = (__float_as_uint(s) >> 14) - BIN_BASE;
          atomicAdd(&lh[bin], 1u);
        }
      }
    }
  }
  __syncthreads();
  u32* gh = hist + (size_t)img * 4096;
  for (int i = threadIdx.x; i < 4096; i += 256) {
    u32 v = lh[i];
    if (v) atomicAdd(&gh[i], v);
  }
}

// ---------------- find boundary bin B and residual T ----------------
__global__ void scan_k(const u32* __restrict__ hist, int* __restrict__ meta) {
  const int img = blockIdx.x;
  const u32* h = hist + (size_t)img * 4096;
  __shared__ u32 lsum[256];
  __shared__ u32 above[256];
  __shared__ u32 s_total;
  const int t = threadIdx.x;
  u32 s = 0;
  for (int j = 0; j < 16; ++j) s += h[t * 16 + j];
  lsum[t] = s;
  __syncthreads();
  if (t == 0) {
    u32 acc = 0;
    for (int i = 255; i >= 0; --i) { above[i] = acc; acc += lsum[i]; }
    s_total = acc;
  }
  __syncthreads();
  const u32 K = PREK;
  int* m = meta + img * 4;
  if (s_total < K) {
    if (t == 0) { m[0] = -1; m[1] = 0; }
  } else {
    if (above[t] < K && above[t] + lsum[t] >= K) {
      u32 cum = above[t];
      for (int j = 15; j >= 0; --j) {
        u32 hv = h[t * 16 + j];
        cum += hv;
        if (cum >= K) { m[0] = t * 16 + j; m[1] = (int)(K - (cum - hv)); break; }
      }
    }
  }
}

// ---- block-staged list flush: one global atomic per list per block ----
__device__ __forceinline__ void flush_list(const u64* llist, int lcnt, int cap,
                                           int* gctr, u64* glist, int gcap) {
  __shared__ int gbase_s;
  int n = lcnt < cap ? lcnt : cap;
  if (threadIdx.x == 0) gbase_s = n ? atomicAdd(gctr, n) : 0;
  __syncthreads();
  const int gb = gbase_s;
  for (int i = threadIdx.x; i < n; i += 256) {
    int pos = gb + i;
    if (pos < gcap) glist[pos] = llist[i];
  }
}

// ---------------- gather, vectorized (HW % 4 == 0), class-chunked, LDS-staged ----------------
__global__ __launch_bounds__(256) void gather_v4(const float* __restrict__ in,
                         const int* __restrict__ meta, int* __restrict__ cnt,
                         u64* __restrict__ winners, u64* __restrict__ boundary,
                         int HW, int lvl_off) {
  __shared__ u64 lwin[LCAP];
  __shared__ u64 lbnd[LCAP];
  __shared__ int lwc, lbc;
  const int img = blockIdx.y;
  const int c0 = blockIdx.z * GCH;
  if (threadIdx.x == 0) { lwc = 0; lbc = 0; }
  __syncthreads();

  const int HW4 = HW >> 2;
  const int idx = blockIdx.x * 256 + threadIdx.x;
  const bool act = idx < 3 * HW4;
  const int B = meta[img * 4 + 0];
  int* cw = &cnt[img * 64];
  int* cb = &cnt[img * 64 + 32];
  u64* wl = winners + (size_t)img * PREK;
  u64* bl = boundary + (size_t)img * BCAP;
  if (act) {
    const int a = idx / HW4;
    const int p0 = (idx - a * HW4) << 2;
    const float* base = in + ((size_t)(img * 255 + a * 85)) * (size_t)HW + p0;
    const int boxg0 = lvl_off + a * HW + p0;
    float4 scv[GCH];
#pragma unroll
    for (int k = 0; k < GCH; ++k)
      scv[k] = *(const float4*)(base + (size_t)(5 + c0 + k) * HW);
    float4 v4 = *(const float4*)(base + 4 * (size_t)HW);
    const float* t4 = (const float*)&v4;
    float conf[4];
#pragma unroll
    for (int i = 0; i < 4; ++i) conf[i] = sigmf(t4[i]);
#pragma unroll
    for (int k = 0; k < GCH; ++k) {
      const float* s4 = (const float*)&scv[k];
      const int c = c0 + k;
#pragma unroll
      for (int i = 0; i < 4; ++i) {
        float s = conf[i] * sigmf(s4[i]);
        if (s > SCORE_TH) {
          u32 key = __float_as_uint(s);
          int wbin = (int)((key >> 14) - BIN_BASE);
          if (wbin >= B) {
            u64 kv = ((u64)key << 32) | (u64)(~(u32)((boxg0 + i) * NCLS + c));
            if (wbin > B) {
              int p = atomicAdd(&lwc, 1);
              if (p < LCAP) lwin[p] = kv;
              else { int g = atomicAdd(cw, 1); if (g < PREK) wl[g] = kv; }  // spill (rare)
            } else {
              int p = atomicAdd(&lbc, 1);
              if (p < LCAP) lbnd[p] = kv;
              else { int g = atomicAdd(cb, 1); if (g < BCAP) bl[g] = kv; }
            }
          }
        }
      }
    }
  }
  __syncthreads();
  flush_list(lwin, lwc, LCAP, cw, wl, PREK);
  flush_list(lbnd, lbc, LCAP, cb, bl, BCAP);
}

// ---------------- gather, scalar (level 0), class-chunked, LDS-staged ----------------
__global__ __launch_bounds__(256) void gather_s(const float* __restrict__ in,
                         const int* __restrict__ meta, int* __restrict__ cnt,
                         u64* __restrict__ winners, u64* __restrict__ boundary,
                         int HW, int lvl_off) {
  __shared__ u64 lwin[LCAP];
  __shared__ u64 lbnd[LCAP];
  __shared__ int lwc, lbc;
  const int img = blockIdx.y;
  const int c0 = blockIdx.z * GCH;
  if (threadIdx.x == 0) { lwc = 0; lbc = 0; }
  __syncthreads();

  const int r = blockIdx.x * 256 + threadIdx.x;
  const bool act = r < 3 * HW;
  const int B = meta[img * 4 + 0];
  int* cw = &cnt[img * 64];
  int* cb = &cnt[img * 64 + 32];
  u64* wl = winners + (size_t)img * PREK;
  u64* bl = boundary + (size_t)img * BCAP;
  if (act) {
    const int a = r / HW, p = r - a * HW;
    const float* base = in + ((size_t)(img * 255 + a * 85)) * (size_t)HW + p;
    const int boxg = lvl_off + r;
    float l[GCH];
#pragma unroll
    for (int k = 0; k < GCH; ++k) l[k] = base[(size_t)(5 + c0 + k) * HW];
    const float conf = sigmf(base[4 * (size_t)HW]);
#pragma unroll
    for (int k = 0; k < GCH; ++k) {
      float s = conf * sigmf(l[k]);
      if (s > SCORE_TH) {
        u32 key = __float_as_uint(s);
        int wbin = (int)((key >> 14) - BIN_BASE);
        if (wbin >= B) {
          u64 kv = ((u64)key << 32) | (u64)(~(u32)(boxg * NCLS + (c0 + k)));
          if (wbin > B) {
            int p2 = atomicAdd(&lwc, 1);
            if (p2 < LCAP) lwin[p2] = kv;
            else { int g = atomicAdd(cw, 1); if (g < PREK) wl[g] = kv; }
          } else {
            int p2 = atomicAdd(&lbc, 1);
            if (p2 < LCAP) lbnd[p2] = kv;
            else { int g = atomicAdd(cb, 1); if (g < BCAP) bl[g] = kv; }
          }
        }
      }
    }
  }
  __syncthreads();
  flush_list(lwin, lwc, LCAP, cw, wl, PREK);
  flush_list(lbnd, lbc, LCAP, cb, bl, BCAP);
}

// ---------------- resolve boundary bin: pick exactly T more ----------------
__global__ void resolve_k(const u64* __restrict__ boundary, const int* __restrict__ meta,
                          int* __restrict__ cnt, u64* __restrict__ winners) {
  const int img = blockIdx.x;
  const int T = meta[img * 4 + 1];
  int bc = cnt[img * 64 + 32];
  if (bc > BCAP) bc = BCAP;
  if (T <= 0 || bc <= 0) return;
  const u64* bnd = boundary + (size_t)img * BCAP;
  u64* wl = winners + (size_t)img * PREK;
  int* cw = &cnt[img * 64];

  __shared__ u32 h2[16384];
  __shared__ u32 lsum[256];
  __shared__ u32 above[256];
  __shared__ u32 s_total;
  __shared__ int sB2, sT2;
  __shared__ u64 ties[512];
  __shared__ int tcnt;
  __shared__ u64 lw2[PREK];
  __shared__ int lw2c;
  __shared__ int gbase_s;
  const int t = threadIdx.x;
  for (int i = t; i < 16384; i += 256) h2[i] = 0;
  if (t == 0) { tcnt = 0; sB2 = -1; sT2 = 0; lw2c = 0; }
  __syncthreads();
  for (int i = t; i < bc; i += 256) atomicAdd(&h2[(u32)(bnd[i] >> 32) & 0x3FFFu], 1u);
  __syncthreads();
  u32 s = 0;
  for (int j = 0; j < 64; ++j) s += h2[t * 64 + j];
  lsum[t] = s;
  __syncthreads();
  if (t == 0) {
    u32 acc = 0;
    for (int i = 255; i >= 0; --i) { above[i] = acc; acc += lsum[i]; }
    s_total = acc;
  }
  __syncthreads();
  if ((int)s_total > T) {
    if (above[t] < (u32)T && above[t] + lsum[t] >= (u32)T) {
      u32 cum = above[t];
      for (int j = 63; j >= 0; --j) {
        u32 hv = h2[t * 64 + j];
        cum += hv;
        if (cum >= (u32)T) { sB2 = t * 64 + j; sT2 = (int)((u32)T - (cum - hv)); break; }
      }
    }
  }
  __syncthreads();
  const int B2 = sB2, T2 = sT2;
  for (int i = t; i < bc; i += 256) {
    u64 e = bnd[i];
    int low = (int)((u32)(e >> 32) & 0x3FFFu);
    if (low > B2) {
      int p = atomicAdd(&lw2c, 1);
      if (p < PREK) lw2[p] = e;
    } else if (low == B2) {
      int tp = atomicAdd(&tcnt, 1);
      if (tp < 512) ties[tp] = e;
    }
  }
  __syncthreads();
  int n = lw2c < PREK ? lw2c : PREK;
  if (t == 0) gbase_s = n ? atomicAdd(cw, n) : 0;
  __syncthreads();
  for (int i = t; i < n; i += 256) {
    int pos = gbase_s + i;
    if (pos < PREK) wl[pos] = lw2[i];
  }
  __syncthreads();
  if (t == 0 && T2 > 0) {
    int tc = tcnt < 512 ? tcnt : 512;
    for (int k = 0; k < T2 && k < tc; ++k) {
      int bi = -1; u64 bk = 0;
      for (int i = 0; i < tc; ++i)
        if (ties[i] > bk) { bk = ties[i]; bi = i; }  // same score => larger ~idx = smaller idx first
      if (bi < 0) break;
      ties[bi] = 0;
      int pos = atomicAdd(cw, 1);
      if (pos < PREK) wl[pos] = bk;
    }
  }
}

// ---------------- exact sort by rank (keys unique) ----------------
__global__ __launch_bounds__(256) void rank_k(const u64* __restrict__ winners,
                                              const int* __restrict__ cnt,
                                              const float4* __restrict__ boxes,
                                              u64* __restrict__ skey,
                                              float4* __restrict__ sobox,
                                              float* __restrict__ sarea) {
  __shared__ u64 lk[PREK];
  const int img = blockIdx.y;
  const int t = threadIdx.x;
  int wc = cnt[img * 64]; if (wc > PREK) wc = PREK;
  for (int i = t; i < PREK; i += 256)
    lk[i] = (i < wc) ? winners[(size_t)img * PREK + i] : (u64)(~(u32)i);  // distinct pads, below all real keys
  __syncthreads();
  const int i = blockIdx.x * 256 + t;
  const u64 ki = lk[i];
  int rank = 0;
#pragma unroll 8
  for (int j = 0; j < PREK; ++j) rank += (lk[j] > ki) ? 1 : 0;
  skey[(size_t)img * PREK + rank] = ki;
  if (i < wc) {
    u32 ridx = ~(u32)ki;
    int c = (int)(ridx % NCLS);
    int bi = (int)(ridx / NCLS);
    float4 b = boxes[(size_t)img * NBOX + bi];
    float off = 4096.0f * (float)c;
    float4 ob = make_float4(b.x + off, b.y + off, b.z + off, b.w + off);
    sobox[(size_t)img * PREK + rank] = ob;
    sarea[(size_t)img * PREK + rank] = (ob.z - ob.x) * (ob.w - ob.y);
  } else {
    sobox[(size_t)img * PREK + rank] = make_float4(0.f, 0.f, 0.f, 0.f);
    sarea[(size_t)img * PREK + rank] = 0.f;
  }
}

// ---------------- sorted-scan greedy NMS with class buckets: one wave per image ----------------
// Exactness: reference tests every (selected, candidate) pair. Cross-class pairs can
// only have IoU>0 if w_a+w_b > 6976 (and h likewise), since cx,cy in (0,608) and the
// class offset is 4096 on x AND y. Hence at least one of the pair is "huge"
// (w>3488 || h>3488). Testing {same-class} + {vs huge selected} + {huge candidate vs all}
// is an exact superset; extra tests compute the identical IoU expression -> same result.
__global__ __launch_bounds__(64) void scan_nms_k(const u64* __restrict__ skey,
                                                 const float4* __restrict__ sobox,
                                                 const float* __restrict__ sarea,
                                                 float* __restrict__ out) {
  __shared__ float4 bxc[NCLS][BKCAP];
  __shared__ float  arc[NCLS][BKCAP];
  __shared__ int    cntc[NCLS];
  __shared__ float4 bxa[TOPK];
  __shared__ float  ara[TOPK];
  __shared__ float4 bxh[HCAP];
  __shared__ float  arh[HCAP];
  __shared__ int    nhuge_s;
  const int img = blockIdx.x;
  const int lane = threadIdx.x;
  float* orow = out + (size_t)img * (TOPK * 6);
  for (int i = lane; i < TOPK * 6; i += 64) orow[i] = 0.f;
  for (int i = lane; i < NCLS; i += 64) cntc[i] = 0;
  if (lane == 0) nhuge_s = 0;
  const u64* K = skey + (size_t)img * PREK;
  const float4* Bp = sobox + (size_t)img * PREK;
  const float* Ap = sarea + (size_t)img * PREK;
  int nsel = 0;
  for (int chunk = 0; chunk < PREK / 64 && nsel < TOPK; ++chunk) {
    const int j = chunk * 64 + lane;
    const u64 kj = K[j];
    const float score = __uint_as_float((u32)(kj >> 32));
    bool alive = (score > SCORE_TH);
    if (__ballot(alive) == 0ull) break;   // sorted: nothing below passes either
    const float4 ob = Bp[j];
    const float ar = Ap[j];
    const u32 ridx = ~(u32)kj;
    const int myc = (int)(ridx % NCLS);
    const bool huge = (ob.z - ob.x > HUGE_TH) || (ob.w - ob.y > HUGE_TH);

    // phase 1a: same-class bucket walk (per-lane divergent, 2-unrolled, clamped reads)
    {
      const int n = cntc[myc];
      for (int k = 0; __ballot(alive && k < n) != 0ull; k += 2) {
        const int k0 = (k < BKCAP - 1) ? k : (BKCAP - 1);
        const int k1 = (k + 1 < BKCAP - 1) ? (k + 1) : (BKCAP - 1);
        const float4 b0 = bxc[myc][k0]; const float a0 = arc[myc][k0];
        const float4 b1 = bxc[myc][k1]; const float a1 = arc[myc][k1];
        if (alive && k < n) {
          float xx1 = fmaxf(b0.x, ob.x), yy1 = fmaxf(b0.y, ob.y);
          float xx2 = fminf(b0.z, ob.z), yy2 = fminf(b0.w, ob.w);
          float inter = fmaxf(xx2 - xx1, 0.f) * fmaxf(yy2 - yy1, 0.f);
          float iou = inter / (a0 + ar - inter + 1e-9f);
          if (iou > IOU_TH) alive = false;
        }
        if (alive && k + 1 < n) {
          float xx1 = fmaxf(b1.x, ob.x), yy1 = fmaxf(b1.y, ob.y);
          float xx2 = fminf(b1.z, ob.z), yy2 = fminf(b1.w, ob.w);
          float inter = fmaxf(xx2 - xx1, 0.f) * fmaxf(yy2 - yy1, 0.f);
          float iou = inter / (a1 + ar - inter + 1e-9f);
          if (iou > IOU_TH) alive = false;
        }
      }
    }
    // phase 1b: vs huge selected (broadcast reads)
    {
      const int nh = nhuge_s;
      for (int k = 0; k < nh && __ballot(alive) != 0ull; k += 2) {
        const int k0 = (k < nh - 1) ? k : (nh - 1);
        const int k1 = (k + 1 < nh - 1) ? (k + 1) : (nh - 1);
        const float4 b0 = bxh[k0]; const float a0 = arh[k0];
        const float4 b1 = bxh[k1]; const float a1 = arh[k1];
        if (alive) {
          float xx1 = fmaxf(b0.x, ob.x), yy1 = fmaxf(b0.y, ob.y);
          float xx2 = fminf(b0.z, ob.z), yy2 = fminf(b0.w, ob.w);
          float inter = fmaxf(xx2 - xx1, 0.f) * fmaxf(yy2 - yy1, 0.f);
          float iou = inter / (a0 + ar - inter + 1e-9f);
          if (iou > IOU_TH) alive = false;
        }
        if (alive && k + 1 < nh) {
          float xx1 = fmaxf(b1.x, ob.x), yy1 = fmaxf(b1.y, ob.y);
          float xx2 = fminf(b1.z, ob.z), yy2 = fminf(b1.w, ob.w);
          float inter = fmaxf(xx2 - xx1, 0.f) * fmaxf(yy2 - yy1, 0.f);
          float iou = inter / (a1 + ar - inter + 1e-9f);
          if (iou > IOU_TH) alive = false;
        }
      }
    }
    // phase 1c: huge candidates vs ALL selected (rare)
    if (__ballot(alive && huge) != 0ull) {
      const int na = nsel;
      for (int k = 0; k < na; k += 2) {
        const int k0 = (k < na - 1) ? k : (na - 1);
        const int k1 = (k + 1 < na - 1) ? (k + 1) : (na - 1);
        const float4 b0 = bxa[k0]; const float a0 = ara[k0];
        const float4 b1 = bxa[k1]; const float a1 = ara[k1];
        if (alive && huge) {
          float xx1 = fmaxf(b0.x, ob.x), yy1 = fmaxf(b0.y, ob.y);
          float xx2 = fminf(b0.z, ob.z), yy2 = fminf(b0.w, ob.w);
          float inter = fmaxf(xx2 - xx1, 0.f) * fmaxf(yy2 - yy1, 0.f);
          float iou = inter / (a0 + ar - inter + 1e-9f);
          if (iou > IOU_TH) alive = false;
        }
        if (alive && huge && k + 1 < na) {
          float xx1 = fmaxf(b1.x, ob.x), yy1 = fmaxf(b1.y, ob.y);
          float xx2 = fminf(b1.z, ob.z), yy2 = fminf(b1.w, ob.w);
          float inter = fmaxf(xx2 - xx1, 0.f) * fmaxf(yy2 - yy1, 0.f);
          float iou = inter / (a1 + ar - inter + 1e-9f);
          if (iou > IOU_TH) alive = false;
        }
        if (__ballot(alive && huge) == 0ull) break;
      }
    }
    // phase 2: serial in-chunk resolution (ascending rank = ref selection order)
    u64 am = __ballot(alive);
    while (am != 0ull && nsel < TOPK) {
      const int b = __builtin_ctzll(am);
      const float bx = __shfl(ob.x, b), by = __shfl(ob.y, b);
      const float bz = __shfl(ob.z, b), bw = __shfl(ob.w, b);
      const float ba = __shfl(ar, b);
      if (lane == b) {
        bxa[nsel] = ob; ara[nsel] = ar;
        const int cc = cntc[myc];
        if (!huge && cc < BKCAP) {
          bxc[myc][cc] = ob; arc[myc][cc] = ar; cntc[myc] = cc + 1;
        } else {  // huge, or bucket overflow spill (tested-by-all => still exact)
          const int hn = nhuge_s;
          bxh[hn] = ob; arh[hn] = ar; nhuge_s = hn + 1;
        }
        const float off = 4096.0f * (float)myc;
        orow[nsel * 6 + 0] = ob.x - off;
        orow[nsel * 6 + 1] = ob.y - off;
        orow[nsel * 6 + 2] = ob.z - off;
        orow[nsel * 6 + 3] = ob.w - off;
        orow[nsel * 6 + 4] = (float)myc;
        orow[nsel * 6 + 5] = score;
        alive = false;
      }
      nsel++;
      if (alive && lane > b) {
        float xx1 = fmaxf(bx, ob.x), yy1 = fmaxf(by, ob.y);
        float xx2 = fminf(bz, ob.z), yy2 = fminf(bw, ob.w);
        float inter = fmaxf(xx2 - xx1, 0.f) * fmaxf(yy2 - yy1, 0.f);
        float iou = inter / (ba + ar - inter + 1e-9f);
        if (iou > IOU_TH) alive = false;
      }
      am = __ballot(alive);
    }
  }
}

extern "C" void kernel_launch(void* const* d_in, const int* in_sizes, int n_in,
                              void* d_out, int out_size, void* d_ws, size_t ws_size,
                              hipStream_t stream) {
  const float* in0 = (const float*)d_in[0];
  const float* in1 = (const float*)d_in[5];
  const float* in2 = (const float*)d_in[10];
  char* ws = (char*)d_ws;
  u32* hist = (u32*)(ws + HIST_OFF);
  int* meta = (int*)(ws + META_OFF);
  int* cnt = (int*)(ws + CNT_OFF);
  u64* winners = (u64*)(ws + WIN_OFF);
  u64* boundary = (u64*)(ws + BND_OFF);
  float4* boxes = (float4*)(ws + BOX_OFF);
  u64* skey = (u64*)(ws + SKEY_OFF);
  float4* sobox = (float4*)(ws + SOBOX_OFF);
  float* sarea = (float*)(ws + SAREA_OFF);
  float* out = (float*)d_out;

  hipMemsetAsync(d_ws, 0, ZERO_BYTES, stream);

  // level 0: 19x19 (HW=361, odd) -> scalar; levels 1/2 vectorized (HW%4==0)
  decode_hist_s<<<dim3(5, 8, DNCH), 256, 0, stream>>>(in0, boxes, hist, 19, 361, 0, 32.f,
                                                3.625f, 2.8125f, 4.875f, 6.1875f, 11.65625f, 10.1875f);
  decode_hist_v4<<<dim3(5, 8, DNCH), 256, 0, stream>>>(in1, boxes, hist, 38, 1444, 1083, 16.f,
                                                 1.875f, 3.8125f, 3.875f, 2.8125f, 3.6875f, 7.4375f);
  decode_hist_v4<<<dim3(17, 8, DNCH), 256, 0, stream>>>(in2, boxes, hist, 76, 5776, 5415, 8.f,
                                                  1.25f, 1.625f, 2.f, 3.75f, 4.125f, 2.875f);

  scan_k<<<8, 256, 0, stream>>>(hist, meta);

  gather_s<<<dim3(5, 8, GNCH), 256, 0, stream>>>(in0, meta, cnt, winners, boundary, 361, 0);
  gather_v4<<<dim3(5, 8, GNCH), 256, 0, stream>>>(in1, meta, cnt, winners, boundary, 1444, 1083);
  gather_v4<<<dim3(17, 8, GNCH), 256, 0, stream>>>(in2, meta, cnt, winners, boundary, 5776, 5415);

  resolve_k<<<8, 256, 0, stream>>>(boundary, meta, cnt, winners);

  rank_k<<<dim3(16, 8), 256, 0, stream>>>(winners, cnt, boxes, skey, sobox, sarea);
  scan_nms_k<<<8, 64, 0, stream>>>(skey, sobox, sarea, out);
}

// Round 7
// 177.659 us; speedup vs baseline: 3.1618x; 1.2901x over previous
//
#include <hip/hip_runtime.h>
#include <stdint.h>

typedef unsigned int u32;
typedef unsigned long long u64;

#define NCLS 80
#define NBOX 22743
#define PREK 4096
#define BCAP 65536
#define NIMG 8
#define SCORE_TH 0.01f
#define IOU_TH 0.45f
#define TOPK 200

// class-chunking: decode = 4 chunks x 20 classes, gather = 8 chunks x 10 classes
#define DCH 20
#define DNCH 4
#define GCH 10
#define GNCH 8

// per-block LDS staging capacity for gather hit lists
#define LCAP 1536

// NMS class-bucket params. Cross-class suppression requires w_a+w_b > 2*(4096-608)
// (and same in y) since cx,cy in (0,608) => at least one box has w>3488 || h>3488.
#define BKCAP 8
#define HCAP 224
#define HUGE_TH 3488.0f

// ---- workspace layout (bytes) ----
#define HIST_OFF 0
#define META_OFF 131072
#define CNT_OFF  131200
#define ZERO_BYTES 133248
#define WIN_OFF  133248
#define BND_OFF  395392
#define BOX_OFF  4589696
#define SKEY_OFF 7500800
#define SOBOX_OFF 7762944
#define SAREA_OFF 8287232

__device__ __forceinline__ float sigmf(float x) { return 1.0f / (1.0f + expf(-x)); }

// window-offset for float-bit bins: s in (0.01,1] -> (bits>>14) in [61583, 65024]
#define BIN_BASE 61440u

// ---------------- merged decode + hist (all 3 levels), class-chunked ----------------
// blockIdx.x: [0,5) lvl0 scalar | [5,10) lvl1 v4 | [10,27) lvl2 v4
__global__ __launch_bounds__(256) void decode_hist_all(const float* __restrict__ in0,
                              const float* __restrict__ in1, const float* __restrict__ in2,
                              float4* __restrict__ boxes, u32* __restrict__ hist) {
  __shared__ u32 lh[4096];
  const int img = blockIdx.y;
  const int c0 = blockIdx.z * DCH;
  for (int i = threadIdx.x; i < 4096; i += 256) lh[i] = 0;
  __syncthreads();

  const int bx = blockIdx.x;
  if (bx < 5) {
    // ---- level 0, scalar: W=19, HW=361, off=0, stride=32 ----
    const int W = 19, HW = 361;
    const int r = bx * 256 + threadIdx.x;
    if (r < 3 * HW) {
      const int a = r / HW, p = r - a * HW;
      const int y = p / W, x = p - y * W;
      const float* base = in0 + ((size_t)(img * 255 + a * 85)) * (size_t)HW + p;
      float l[DCH];
#pragma unroll
      for (int k = 0; k < DCH; ++k) l[k] = base[(size_t)(5 + c0 + k) * HW];
      const float x4 = base[4 * (size_t)HW];
      if (c0 == 0) {
        const float aw = (a == 0) ? 3.625f : ((a == 1) ? 4.875f : 11.65625f);
        const float ah = (a == 0) ? 2.8125f : ((a == 1) ? 6.1875f : 10.1875f);
        const float x0 = base[0];
        const float x1 = base[(size_t)HW];
        const float x2 = base[2 * (size_t)HW];
        const float x3 = base[3 * (size_t)HW];
        const float px = sigmf(x0) + (float)x;
        const float py = sigmf(x1) + (float)y;
        const float pw = expf(x2) * aw;
        const float ph = expf(x3) * ah;
        const float cx = px * 32.f, cy = py * 32.f, bw = pw * 32.f, bh = ph * 32.f;
        boxes[(size_t)img * NBOX + r] =
            make_float4(cx - bw * 0.5f, cy - bh * 0.5f, cx + bw * 0.5f, cy + bh * 0.5f);
      }
      const float conf = sigmf(x4);
      if (conf > SCORE_TH) {
#pragma unroll
        for (int k = 0; k < DCH; ++k) {
          float s = conf * sigmf(l[k]);
          if (s > SCORE_TH) {
            u32 bin = (__float_as_uint(s) >> 14) - BIN_BASE;
            atomicAdd(&lh[bin], 1u);
          }
        }
      }
    }
  } else {
    // ---- levels 1/2, vectorized ----
    const bool L1 = bx < 10;
    const float* in = L1 ? in1 : in2;
    const int W = L1 ? 38 : 76;
    const int HW = L1 ? 1444 : 5776;
    const int lvl_off = L1 ? 1083 : 5415;
    const float stride = L1 ? 16.f : 8.f;
    const int HW4 = HW >> 2;
    const int idx = (bx - (L1 ? 5 : 10)) * 256 + threadIdx.x;
    if (idx < 3 * HW4) {
      const int a = idx / HW4;
      const int p0 = (idx - a * HW4) << 2;
      const float* base = in + ((size_t)(img * 255 + a * 85)) * (size_t)HW + p0;
      float4 scv[DCH];
#pragma unroll
      for (int k = 0; k < DCH; ++k)
        scv[k] = *(const float4*)(base + (size_t)(5 + c0 + k) * HW);
      float4 v4 = *(const float4*)(base + 4 * (size_t)HW);
      const float* t4 = (const float*)&v4;
      float conf[4];
      if (c0 == 0) {
        const float aw = L1 ? ((a == 0) ? 1.875f : ((a == 1) ? 3.875f : 3.6875f))
                            : ((a == 0) ? 1.25f : ((a == 1) ? 2.f : 4.125f));
        const float ah = L1 ? ((a == 0) ? 3.8125f : ((a == 1) ? 2.8125f : 7.4375f))
                            : ((a == 0) ? 1.625f : ((a == 1) ? 3.75f : 2.875f));
        float4 v0 = *(const float4*)(base);
        float4 v1 = *(const float4*)(base + (size_t)HW);
        float4 v2 = *(const float4*)(base + 2 * (size_t)HW);
        float4 v3 = *(const float4*)(base + 3 * (size_t)HW);
        const float* t0 = (const float*)&v0;
        const float* t1 = (const float*)&v1;
        const float* t2 = (const float*)&v2;
        const float* t3 = (const float*)&v3;
        float4* bout = boxes + (size_t)img * NBOX + lvl_off + a * HW + p0;
#pragma unroll
        for (int i = 0; i < 4; ++i) {
          const int p = p0 + i;
          const int y = p / W, x = p - y * W;
          const float px = sigmf(t0[i]) + (float)x;
          const float py = sigmf(t1[i]) + (float)y;
          const float pw = expf(t2[i]) * aw;
          const float ph = expf(t3[i]) * ah;
          const float cx = px * stride, cy = py * stride, bw = pw * stride, bh = ph * stride;
          bout[i] = make_float4(cx - bw * 0.5f, cy - bh * 0.5f, cx + bw * 0.5f, cy + bh * 0.5f);
        }
      }
#pragma unroll
      for (int i = 0; i < 4; ++i) conf[i] = sigmf(t4[i]);
#pragma unroll
      for (int k = 0; k < DCH; ++k) {
        const float* s4 = (const float*)&scv[k];
#pragma unroll
        for (int i = 0; i < 4; ++i) {
          float s = conf[i] * sigmf(s4[i]);
          if (s > SCORE_TH) {
            u32 bin = (__float_as_uint(s) >> 14) - BIN_BASE;
            atomicAdd(&lh[bin], 1u);
          }
        }
      }
    }
  }
  __syncthreads();
  u32* gh = hist + (size_t)img * 4096;
  for (int i = threadIdx.x; i < 4096; i += 256) {
    u32 v = lh[i];
    if (v) atomicAdd(&gh[i], v);
  }
}

// ---------------- find boundary bin B and residual T ----------------
__global__ void scan_k(const u32* __restrict__ hist, int* __restrict__ meta) {
  const int img = blockIdx.x;
  const u32* h = hist + (size_t)img * 4096;
  __shared__ u32 lsum[256];
  __shared__ u32 above[256];
  __shared__ u32 s_total;
  const int t = threadIdx.x;
  u32 s = 0;
  for (int j = 0; j < 16; ++j) s += h[t * 16 + j];
  lsum[t] = s;
  __syncthreads();
  if (t == 0) {
    u32 acc = 0;
    for (int i = 255; i >= 0; --i) { above[i] = acc; acc += lsum[i]; }
    s_total = acc;
  }
  __syncthreads();
  const u32 K = PREK;
  int* m = meta + img * 4;
  if (s_total < K) {
    if (t == 0) { m[0] = -1; m[1] = 0; }
  } else {
    if (above[t] < K && above[t] + lsum[t] >= K) {
      u32 cum = above[t];
      for (int j = 15; j >= 0; --j) {
        u32 hv = h[t * 16 + j];
        cum += hv;
        if (cum >= K) { m[0] = t * 16 + j; m[1] = (int)(K - (cum - hv)); break; }
      }
    }
  }
}

// ---- block-staged list flush: one global atomic per list per block ----
__device__ __forceinline__ void flush_list(const u64* llist, int lcnt, int cap,
                                           int* gctr, u64* glist, int gcap) {
  __shared__ int gbase_s;
  int n = lcnt < cap ? lcnt : cap;
  if (threadIdx.x == 0) gbase_s = n ? atomicAdd(gctr, n) : 0;
  __syncthreads();
  const int gb = gbase_s;
  for (int i = threadIdx.x; i < n; i += 256) {
    int pos = gb + i;
    if (pos < gcap) glist[pos] = llist[i];
  }
}

// ---------------- merged gather (all 3 levels), class-chunked, LDS-staged ----------------
__global__ __launch_bounds__(256) void gather_all(const float* __restrict__ in0,
                         const float* __restrict__ in1, const float* __restrict__ in2,
                         const int* __restrict__ meta, int* __restrict__ cnt,
                         u64* __restrict__ winners, u64* __restrict__ boundary) {
  __shared__ u64 lwin[LCAP];
  __shared__ u64 lbnd[LCAP];
  __shared__ int lwc, lbc;
  const int img = blockIdx.y;
  const int c0 = blockIdx.z * GCH;
  if (threadIdx.x == 0) { lwc = 0; lbc = 0; }
  __syncthreads();

  const int B = meta[img * 4 + 0];
  int* cw = &cnt[img * 64];
  int* cb = &cnt[img * 64 + 32];
  u64* wl = winners + (size_t)img * PREK;
  u64* bl = boundary + (size_t)img * BCAP;
  const int bx = blockIdx.x;

  if (bx < 5) {
    // ---- level 0, scalar ----
    const int HW = 361;
    const int r = bx * 256 + threadIdx.x;
    if (r < 3 * HW) {
      const int a = r / HW, p = r - a * HW;
      const float* base = in0 + ((size_t)(img * 255 + a * 85)) * (size_t)HW + p;
      const int boxg = r;
      float l[GCH];
#pragma unroll
      for (int k = 0; k < GCH; ++k) l[k] = base[(size_t)(5 + c0 + k) * HW];
      const float conf = sigmf(base[4 * (size_t)HW]);
#pragma unroll
      for (int k = 0; k < GCH; ++k) {
        float s = conf * sigmf(l[k]);
        if (s > SCORE_TH) {
          u32 key = __float_as_uint(s);
          int wbin = (int)((key >> 14) - BIN_BASE);
          if (wbin >= B) {
            u64 kv = ((u64)key << 32) | (u64)(~(u32)(boxg * NCLS + (c0 + k)));
            if (wbin > B) {
              int p2 = atomicAdd(&lwc, 1);
              if (p2 < LCAP) lwin[p2] = kv;
              else { int g = atomicAdd(cw, 1); if (g < PREK) wl[g] = kv; }
            } else {
              int p2 = atomicAdd(&lbc, 1);
              if (p2 < LCAP) lbnd[p2] = kv;
              else { int g = atomicAdd(cb, 1); if (g < BCAP) bl[g] = kv; }
            }
          }
        }
      }
    }
  } else {
    // ---- levels 1/2, vectorized ----
    const bool L1 = bx < 10;
    const float* in = L1 ? in1 : in2;
    const int HW = L1 ? 1444 : 5776;
    const int lvl_off = L1 ? 1083 : 5415;
    const int HW4 = HW >> 2;
    const int idx = (bx - (L1 ? 5 : 10)) * 256 + threadIdx.x;
    if (idx < 3 * HW4) {
      const int a = idx / HW4;
      const int p0 = (idx - a * HW4) << 2;
      const float* base = in + ((size_t)(img * 255 + a * 85)) * (size_t)HW + p0;
      const int boxg0 = lvl_off + a * HW + p0;
      float4 scv[GCH];
#pragma unroll
      for (int k = 0; k < GCH; ++k)
        scv[k] = *(const float4*)(base + (size_t)(5 + c0 + k) * HW);
      float4 v4 = *(const float4*)(base + 4 * (size_t)HW);
      const float* t4 = (const float*)&v4;
      float conf[4];
#pragma unroll
      for (int i = 0; i < 4; ++i) conf[i] = sigmf(t4[i]);
#pragma unroll
      for (int k = 0; k < GCH; ++k) {
        const float* s4 = (const float*)&scv[k];
        const int c = c0 + k;
#pragma unroll
        for (int i = 0; i < 4; ++i) {
          float s = conf[i] * sigmf(s4[i]);
          if (s > SCORE_TH) {
            u32 key = __float_as_uint(s);
            int wbin = (int)((key >> 14) - BIN_BASE);
            if (wbin >= B) {
              u64 kv = ((u64)key << 32) | (u64)(~(u32)((boxg0 + i) * NCLS + c));
              if (wbin > B) {
                int p = atomicAdd(&lwc, 1);
                if (p < LCAP) lwin[p] = kv;
                else { int g = atomicAdd(cw, 1); if (g < PREK) wl[g] = kv; }
              } else {
                int p = atomicAdd(&lbc, 1);
                if (p < LCAP) lbnd[p] = kv;
                else { int g = atomicAdd(cb, 1); if (g < BCAP) bl[g] = kv; }
              }
            }
          }
        }
      }
    }
  }
  __syncthreads();
  flush_list(lwin, lwc, LCAP, cw, wl, PREK);
  flush_list(lbnd, lbc, LCAP, cb, bl, BCAP);
}

// ---------------- resolve boundary bin: pick exactly T more ----------------
__global__ void resolve_k(const u64* __restrict__ boundary, const int* __restrict__ meta,
                          int* __restrict__ cnt, u64* __restrict__ winners) {
  const int img = blockIdx.x;
  const int T = meta[img * 4 + 1];
  int bc = cnt[img * 64 + 32];
  if (bc > BCAP) bc = BCAP;
  if (T <= 0 || bc <= 0) return;
  const u64* bnd = boundary + (size_t)img * BCAP;
  u64* wl = winners + (size_t)img * PREK;
  int* cw = &cnt[img * 64];

  __shared__ u32 h2[16384];
  __shared__ u32 lsum[256];
  __shared__ u32 above[256];
  __shared__ u32 s_total;
  __shared__ int sB2, sT2;
  __shared__ u64 ties[512];
  __shared__ int tcnt;
  __shared__ u64 lw2[PREK];
  __shared__ int lw2c;
  __shared__ int gbase_s;
  const int t = threadIdx.x;
  for (int i = t; i < 16384; i += 256) h2[i] = 0;
  if (t == 0) { tcnt = 0; sB2 = -1; sT2 = 0; lw2c = 0; }
  __syncthreads();
  for (int i = t; i < bc; i += 256) atomicAdd(&h2[(u32)(bnd[i] >> 32) & 0x3FFFu], 1u);
  __syncthreads();
  u32 s = 0;
  for (int j = 0; j < 64; ++j) s += h2[t * 64 + j];
  lsum[t] = s;
  __syncthreads();
  if (t == 0) {
    u32 acc = 0;
    for (int i = 255; i >= 0; --i) { above[i] = acc; acc += lsum[i]; }
    s_total = acc;
  }
  __syncthreads();
  if ((int)s_total > T) {
    if (above[t] < (u32)T && above[t] + lsum[t] >= (u32)T) {
      u32 cum = above[t];
      for (int j = 63; j >= 0; --j) {
        u32 hv = h2[t * 64 + j];
        cum += hv;
        if (cum >= (u32)T) { sB2 = t * 64 + j; sT2 = (int)((u32)T - (cum - hv)); break; }
      }
    }
  }
  __syncthreads();
  const int B2 = sB2, T2 = sT2;
  for (int i = t; i < bc; i += 256) {
    u64 e = bnd[i];
    int low = (int)((u32)(e >> 32) & 0x3FFFu);
    if (low > B2) {
      int p = atomicAdd(&lw2c, 1);
      if (p < PREK) lw2[p] = e;
    } else if (low == B2) {
      int tp = atomicAdd(&tcnt, 1);
      if (tp < 512) ties[tp] = e;
    }
  }
  __syncthreads();
  int n = lw2c < PREK ? lw2c : PREK;
  if (t == 0) gbase_s = n ? atomicAdd(cw, n) : 0;
  __syncthreads();
  for (int i = t; i < n; i += 256) {
    int pos = gbase_s + i;
    if (pos < PREK) wl[pos] = lw2[i];
  }
  __syncthreads();
  if (t == 0 && T2 > 0) {
    int tc = tcnt < 512 ? tcnt : 512;
    for (int k = 0; k < T2 && k < tc; ++k) {
      int bi = -1; u64 bk = 0;
      for (int i = 0; i < tc; ++i)
        if (ties[i] > bk) { bk = ties[i]; bi = i; }  // same score => larger ~idx = smaller idx first
      if (bi < 0) break;
      ties[bi] = 0;
      int pos = atomicAdd(cw, 1);
      if (pos < PREK) wl[pos] = bk;
    }
  }
}

// ---------------- exact sort by rank (keys unique) ----------------
__global__ __launch_bounds__(256) void rank_k(const u64* __restrict__ winners,
                                              const int* __restrict__ cnt,
                                              const float4* __restrict__ boxes,
                                              u64* __restrict__ skey,
                                              float4* __restrict__ sobox,
                                              float* __restrict__ sarea) {
  __shared__ u64 lk[PREK];
  const int img = blockIdx.y;
  const int t = threadIdx.x;
  int wc = cnt[img * 64]; if (wc > PREK) wc = PREK;
  for (int i = t; i < PREK; i += 256)
    lk[i] = (i < wc) ? winners[(size_t)img * PREK + i] : (u64)(~(u32)i);  // distinct pads, below all real keys
  __syncthreads();
  const int i = blockIdx.x * 256 + t;
  const u64 ki = lk[i];
  int rank = 0;
#pragma unroll 8
  for (int j = 0; j < PREK; ++j) rank += (lk[j] > ki) ? 1 : 0;
  skey[(size_t)img * PREK + rank] = ki;
  if (i < wc) {
    u32 ridx = ~(u32)ki;
    int c = (int)(ridx % NCLS);
    int bi = (int)(ridx / NCLS);
    float4 b = boxes[(size_t)img * NBOX + bi];
    float off = 4096.0f * (float)c;
    float4 ob = make_float4(b.x + off, b.y + off, b.z + off, b.w + off);
    sobox[(size_t)img * PREK + rank] = ob;
    sarea[(size_t)img * PREK + rank] = (ob.z - ob.x) * (ob.w - ob.y);
  } else {
    sobox[(size_t)img * PREK + rank] = make_float4(0.f, 0.f, 0.f, 0.f);
    sarea[(size_t)img * PREK + rank] = 0.f;
  }
}

// ---------------- sorted-scan greedy NMS: pairwise matrix + scalar sweep ----------------
// Phase 1 (vs earlier-chunk selections) uses class buckets + huge lists (exact superset,
// see round-5 proof). In-chunk resolution: full 64x64 pairwise suppression masks (exact,
// no pruning), then a wave-uniform bit-sweep selecting in rank order; per selection the
// only cross-lane op is one ballot. Commit of selected lanes is fully parallel.
__global__ __launch_bounds__(64) void scan_nms_k(const u64* __restrict__ skey,
                                                 const float4* __restrict__ sobox,
                                                 const float* __restrict__ sarea,
                                                 float* __restrict__ out) {
  __shared__ float4 bxc[NCLS][BKCAP];
  __shared__ float  arc[NCLS][BKCAP];
  __shared__ int    cntc[NCLS];
  __shared__ float4 bxa[TOPK];
  __shared__ float  ara[TOPK];
  __shared__ float4 bxh[HCAP];
  __shared__ float  arh[HCAP];
  __shared__ int    nhuge_s;
  __shared__ float4 chb[64];
  __shared__ float  cha[64];
  const int img = blockIdx.x;
  const int lane = threadIdx.x;
  float* orow = out + (size_t)img * (TOPK * 6);
  for (int i = lane; i < TOPK * 6; i += 64) orow[i] = 0.f;
  for (int i = lane; i < NCLS; i += 64) cntc[i] = 0;
  if (lane == 0) nhuge_s = 0;
  const u64* K = skey + (size_t)img * PREK;
  const float4* Bp = sobox + (size_t)img * PREK;
  const float* Ap = sarea + (size_t)img * PREK;
  int nsel = 0;
  for (int chunk = 0; chunk < PREK / 64 && nsel < TOPK; ++chunk) {
    const int j = chunk * 64 + lane;
    const u64 kj = K[j];
    const float score = __uint_as_float((u32)(kj >> 32));
    bool alive = (score > SCORE_TH);
    if (__ballot(alive) == 0ull) break;   // sorted: nothing below passes either
    const float4 ob = Bp[j];
    const float ar = Ap[j];
    const u32 ridx = ~(u32)kj;
    const int myc = (int)(ridx % NCLS);
    const bool huge = (ob.z - ob.x > HUGE_TH) || (ob.w - ob.y > HUGE_TH);
    chb[lane] = ob; cha[lane] = ar;   // stash for pairwise matrix (single wave: no barrier)

    // phase 1a: same-class bucket walk
    {
      const int n0 = cntc[myc];
      const int n = n0 < BKCAP ? n0 : BKCAP;
      for (int k = 0; __ballot(alive && k < n) != 0ull; k += 2) {
        const int k0 = (k < BKCAP - 1) ? k : (BKCAP - 1);
        const int k1 = (k + 1 < BKCAP - 1) ? (k + 1) : (BKCAP - 1);
        const float4 b0 = bxc[myc][k0]; const float a0 = arc[myc][k0];
        const float4 b1 = bxc[myc][k1]; const float a1 = arc[myc][k1];
        if (alive && k < n) {
          float xx1 = fmaxf(b0.x, ob.x), yy1 = fmaxf(b0.y, ob.y);
          float xx2 = fminf(b0.z, ob.z), yy2 = fminf(b0.w, ob.w);
          float inter = fmaxf(xx2 - xx1, 0.f) * fmaxf(yy2 - yy1, 0.f);
          float iou = inter / (a0 + ar - inter + 1e-9f);
          if (iou > IOU_TH) alive = false;
        }
        if (alive && k + 1 < n) {
          float xx1 = fmaxf(b1.x, ob.x), yy1 = fmaxf(b1.y, ob.y);
          float xx2 = fminf(b1.z, ob.z), yy2 = fminf(b1.w, ob.w);
          float inter = fmaxf(xx2 - xx1, 0.f) * fmaxf(yy2 - yy1, 0.f);
          float iou = inter / (a1 + ar - inter + 1e-9f);
          if (iou > IOU_TH) alive = false;
        }
      }
    }
    // phase 1b: vs huge selected
    {
      const int nh = nhuge_s;
      for (int k = 0; k < nh && __ballot(alive) != 0ull; k += 2) {
        const int k0 = (k < nh - 1) ? k : (nh - 1);
        const int k1 = (k + 1 < nh - 1) ? (k + 1) : (nh - 1);
        const float4 b0 = bxh[k0]; const float a0 = arh[k0];
        const float4 b1 = bxh[k1]; const float a1 = arh[k1];
        if (alive) {
          float xx1 = fmaxf(b0.x, ob.x), yy1 = fmaxf(b0.y, ob.y);
          float xx2 = fminf(b0.z, ob.z), yy2 = fminf(b0.w, ob.w);
          float inter = fmaxf(xx2 - xx1, 0.f) * fmaxf(yy2 - yy1, 0.f);
          float iou = inter / (a0 + ar - inter + 1e-9f);
          if (iou > IOU_TH) alive = false;
        }
        if (alive && k + 1 < nh) {
          float xx1 = fmaxf(b1.x, ob.x), yy1 = fmaxf(b1.y, ob.y);
          float xx2 = fminf(b1.z, ob.z), yy2 = fminf(b1.w, ob.w);
          float inter = fmaxf(xx2 - xx1, 0.f) * fmaxf(yy2 - yy1, 0.f);
          float iou = inter / (a1 + ar - inter + 1e-9f);
          if (iou > IOU_TH) alive = false;
        }
      }
    }
    // phase 1c: huge candidates vs ALL selected (rare)
    if (__ballot(alive && huge) != 0ull) {
      const int na = nsel;
      for (int k = 0; k < na; k += 2) {
        const int k0 = (k < na - 1) ? k : (na - 1);
        const int k1 = (k + 1 < na - 1) ? (k + 1) : (na - 1);
        const float4 b0 = bxa[k0]; const float a0 = ara[k0];
        const float4 b1 = bxa[k1]; const float a1 = ara[k1];
        if (alive && huge) {
          float xx1 = fmaxf(b0.x, ob.x), yy1 = fmaxf(b0.y, ob.y);
          float xx2 = fminf(b0.z, ob.z), yy2 = fminf(b0.w, ob.w);
          float inter = fmaxf(xx2 - xx1, 0.f) * fmaxf(yy2 - yy1, 0.f);
          float iou = inter / (a0 + ar - inter + 1e-9f);
          if (iou > IOU_TH) alive = false;
        }
        if (alive && huge && k + 1 < na) {
          float xx1 = fmaxf(b1.x, ob.x), yy1 = fmaxf(b1.y, ob.y);
          float xx2 = fminf(b1.z, ob.z), yy2 = fminf(b1.w, ob.w);
          float inter = fmaxf(xx2 - xx1, 0.f) * fmaxf(yy2 - yy1, 0.f);
          float iou = inter / (a1 + ar - inter + 1e-9f);
          if (iou > IOU_TH) alive = false;
        }
        if (__ballot(alive && huge) == 0ull) break;
      }
    }
    // pairwise in-chunk suppression masks: sup[lane] bit jj = "jj (earlier rank) suppresses lane"
    u64 sup = 0ull;
#pragma unroll 4
    for (int jj = 0; jj < 64; ++jj) {
      const float4 bj = chb[jj];   // uniform jj -> broadcast read
      const float aj = cha[jj];
      float xx1 = fmaxf(bj.x, ob.x), yy1 = fmaxf(bj.y, ob.y);
      float xx2 = fminf(bj.z, ob.z), yy2 = fminf(bj.w, ob.w);
      float inter = fmaxf(xx2 - xx1, 0.f) * fmaxf(yy2 - yy1, 0.f);
      float iou = inter / (aj + ar - inter + 1e-9f);   // a_selected + a_candidate (commutative)
      if (jj < lane && iou > IOU_TH) sup |= (1ull << jj);
    }
    // scalar greedy sweep (wave-uniform; exact greedy order; 1 ballot per selection)
    u64 rem = __ballot(alive);
    u64 selbits = 0ull;
    while (rem != 0ull && nsel + (int)__popcll(selbits) < TOPK) {
      const int b = __builtin_ctzll(rem);
      selbits |= (1ull << b);
      rem &= ~(1ull << b);
      const u64 colb = __ballot((sup >> b) & 1ull);   // lanes suppressed by b
      rem &= ~colb;
    }
    // parallel commit
    const bool selme = (selbits >> lane) & 1ull;
    if (selme) {
      const int slot = nsel + (int)__popcll(selbits & ((1ull << lane) - 1ull));
      bxa[slot] = ob; ara[slot] = ar;
      if (!huge) {
        int cc = atomicAdd(&cntc[myc], 1);
        if (cc < BKCAP) { bxc[myc][cc] = ob; arc[myc][cc] = ar; }
        else { int hn = atomicAdd(&nhuge_s, 1); if (hn < HCAP) { bxh[hn] = ob; arh[hn] = ar; } }
      } else {
        int hn = atomicAdd(&nhuge_s, 1);
        if (hn < HCAP) { bxh[hn] = ob; arh[hn] = ar; }
      }
      const float off = 4096.0f * (float)myc;
      orow[slot * 6 + 0] = ob.x - off;
      orow[slot * 6 + 1] = ob.y - off;
      orow[slot * 6 + 2] = ob.z - off;
      orow[slot * 6 + 3] = ob.w - off;
      orow[slot * 6 + 4] = (float)myc;
      orow[slot * 6 + 5] = score;
    }
    nsel += (int)__popcll(selbits);
  }
}

extern "C" void kernel_launch(void* const* d_in, const int* in_sizes, int n_in,
                              void* d_out, int out_size, void* d_ws, size_t ws_size,
                              hipStream_t stream) {
  const float* in0 = (const float*)d_in[0];
  const float* in1 = (const float*)d_in[5];
  const float* in2 = (const float*)d_in[10];
  char* ws = (char*)d_ws;
  u32* hist = (u32*)(ws + HIST_OFF);
  int* meta = (int*)(ws + META_OFF);
  int* cnt = (int*)(ws + CNT_OFF);
  u64* winners = (u64*)(ws + WIN_OFF);
  u64* boundary = (u64*)(ws + BND_OFF);
  float4* boxes = (float4*)(ws + BOX_OFF);
  u64* skey = (u64*)(ws + SKEY_OFF);
  float4* sobox = (float4*)(ws + SOBOX_OFF);
  float* sarea = (float*)(ws + SAREA_OFF);
  float* out = (float*)d_out;

  hipMemsetAsync(d_ws, 0, ZERO_BYTES, stream);

  decode_hist_all<<<dim3(27, 8, DNCH), 256, 0, stream>>>(in0, in1, in2, boxes, hist);

  scan_k<<<8, 256, 0, stream>>>(hist, meta);

  gather_all<<<dim3(27, 8, GNCH), 256, 0, stream>>>(in0, in1, in2, meta, cnt, winners, boundary);

  resolve_k<<<8, 256, 0, stream>>>(boundary, meta, cnt, winners);

  rank_k<<<dim3(16, 8), 256, 0, stream>>>(winners, cnt, boxes, skey, sobox, sarea);
  scan_nms_k<<<8, 64, 0, stream>>>(skey, sobox, sarea, out);
}

// Round 8
// 138.297 us; speedup vs baseline: 4.0617x; 1.2846x over previous
//
#include <hip/hip_runtime.h>
#include <stdint.h>

typedef unsigned int u32;
typedef unsigned long long u64;

#define NCLS 80
#define NBOX 22743
#define PREK 4096
#define BCAP 65536
#define NIMG 8
#define SCORE_TH 0.01f
#define IOU_TH 0.45f
#define TOPK 200

// class-chunking: decode = 4 chunks x 20 classes, gather = 8 chunks x 10 classes
#define DCH 20
#define DNCH 4
#define GCH 10
#define GNCH 8

// per-block LDS staging capacity for gather hit lists
#define LCAP 1536

// NMS class-bucket params. Cross-class suppression requires w_a+w_b > 2*(4096-608)
// (and same in y) since cx,cy in (0,608) => at least one box has w>3488 || h>3488.
#define BKCAP 8
#define HCAP 224
#define HUGE_TH 3488.0f

// rank split: 4 j-chunks of 1024 keys
#define RJC 4
#define RJW 1024

// ---- workspace layout (bytes) ----
#define HIST_OFF 0
#define META_OFF 131072
#define CNT_OFF  131200
#define ZERO_BYTES 133248
#define WIN_OFF  133248
#define BND_OFF  395392
#define PART_OFF BND_OFF   // overlays boundary (consumed before rank phase)
#define BOX_OFF  4589696
#define SKEY_OFF 7500800
#define SOBOX_OFF 7762944
#define SAREA_OFF 8287232

__device__ __forceinline__ float sigmf(float x) { return 1.0f / (1.0f + expf(-x)); }

// window-offset for float-bit bins: s in (0.01,1] -> (bits>>14) in [61583, 65024]
#define BIN_BASE 61440u

__device__ __forceinline__ u64 pad_key(int i) { return (u64)(~(u32)i); }  // below all real keys, distinct

// ---------------- merged decode + hist (all 3 levels), class-chunked ----------------
// blockIdx.x: [0,5) lvl0 scalar | [5,10) lvl1 v4 | [10,27) lvl2 v4
__global__ __launch_bounds__(256) void decode_hist_all(const float* __restrict__ in0,
                              const float* __restrict__ in1, const float* __restrict__ in2,
                              float4* __restrict__ boxes, u32* __restrict__ hist) {
  __shared__ u32 lh[4096];
  const int img = blockIdx.y;
  const int c0 = blockIdx.z * DCH;
  for (int i = threadIdx.x; i < 4096; i += 256) lh[i] = 0;
  __syncthreads();

  const int bx = blockIdx.x;
  if (bx < 5) {
    // ---- level 0, scalar: W=19, HW=361, off=0, stride=32 ----
    const int W = 19, HW = 361;
    const int r = bx * 256 + threadIdx.x;
    if (r < 3 * HW) {
      const int a = r / HW, p = r - a * HW;
      const int y = p / W, x = p - y * W;
      const float* base = in0 + ((size_t)(img * 255 + a * 85)) * (size_t)HW + p;
      float l[DCH];
#pragma unroll
      for (int k = 0; k < DCH; ++k) l[k] = base[(size_t)(5 + c0 + k) * HW];
      const float x4 = base[4 * (size_t)HW];
      if (c0 == 0) {
        const float aw = (a == 0) ? 3.625f : ((a == 1) ? 4.875f : 11.65625f);
        const float ah = (a == 0) ? 2.8125f : ((a == 1) ? 6.1875f : 10.1875f);
        const float x0 = base[0];
        const float x1 = base[(size_t)HW];
        const float x2 = base[2 * (size_t)HW];
        const float x3 = base[3 * (size_t)HW];
        const float px = sigmf(x0) + (float)x;
        const float py = sigmf(x1) + (float)y;
        const float pw = expf(x2) * aw;
        const float ph = expf(x3) * ah;
        const float cx = px * 32.f, cy = py * 32.f, bw = pw * 32.f, bh = ph * 32.f;
        boxes[(size_t)img * NBOX + r] =
            make_float4(cx - bw * 0.5f, cy - bh * 0.5f, cx + bw * 0.5f, cy + bh * 0.5f);
      }
      const float conf = sigmf(x4);
      if (conf > SCORE_TH) {
#pragma unroll
        for (int k = 0; k < DCH; ++k) {
          float s = conf * sigmf(l[k]);
          if (s > SCORE_TH) {
            u32 bin = (__float_as_uint(s) >> 14) - BIN_BASE;
            atomicAdd(&lh[bin], 1u);
          }
        }
      }
    }
  } else {
    // ---- levels 1/2, vectorized ----
    const bool L1 = bx < 10;
    const float* in = L1 ? in1 : in2;
    const int W = L1 ? 38 : 76;
    const int HW = L1 ? 1444 : 5776;
    const int lvl_off = L1 ? 1083 : 5415;
    const float stride = L1 ? 16.f : 8.f;
    const int HW4 = HW >> 2;
    const int idx = (bx - (L1 ? 5 : 10)) * 256 + threadIdx.x;
    if (idx < 3 * HW4) {
      const int a = idx / HW4;
      const int p0 = (idx - a * HW4) << 2;
      const float* base = in + ((size_t)(img * 255 + a * 85)) * (size_t)HW + p0;
      float4 scv[DCH];
#pragma unroll
      for (int k = 0; k < DCH; ++k)
        scv[k] = *(const float4*)(base + (size_t)(5 + c0 + k) * HW);
      float4 v4 = *(const float4*)(base + 4 * (size_t)HW);
      const float* t4 = (const float*)&v4;
      float conf[4];
      if (c0 == 0) {
        const float aw = L1 ? ((a == 0) ? 1.875f : ((a == 1) ? 3.875f : 3.6875f))
                            : ((a == 0) ? 1.25f : ((a == 1) ? 2.f : 4.125f));
        const float ah = L1 ? ((a == 0) ? 3.8125f : ((a == 1) ? 2.8125f : 7.4375f))
                            : ((a == 0) ? 1.625f : ((a == 1) ? 3.75f : 2.875f));
        float4 v0 = *(const float4*)(base);
        float4 v1 = *(const float4*)(base + (size_t)HW);
        float4 v2 = *(const float4*)(base + 2 * (size_t)HW);
        float4 v3 = *(const float4*)(base + 3 * (size_t)HW);
        const float* t0 = (const float*)&v0;
        const float* t1 = (const float*)&v1;
        const float* t2 = (const float*)&v2;
        const float* t3 = (const float*)&v3;
        float4* bout = boxes + (size_t)img * NBOX + lvl_off + a * HW + p0;
#pragma unroll
        for (int i = 0; i < 4; ++i) {
          const int p = p0 + i;
          const int y = p / W, x = p - y * W;
          const float px = sigmf(t0[i]) + (float)x;
          const float py = sigmf(t1[i]) + (float)y;
          const float pw = expf(t2[i]) * aw;
          const float ph = expf(t3[i]) * ah;
          const float cx = px * stride, cy = py * stride, bw = pw * stride, bh = ph * stride;
          bout[i] = make_float4(cx - bw * 0.5f, cy - bh * 0.5f, cx + bw * 0.5f, cy + bh * 0.5f);
        }
      }
#pragma unroll
      for (int i = 0; i < 4; ++i) conf[i] = sigmf(t4[i]);
#pragma unroll
      for (int k = 0; k < DCH; ++k) {
        const float* s4 = (const float*)&scv[k];
#pragma unroll
        for (int i = 0; i < 4; ++i) {
          float s = conf[i] * sigmf(s4[i]);
          if (s > SCORE_TH) {
            u32 bin = (__float_as_uint(s) >> 14) - BIN_BASE;
            atomicAdd(&lh[bin], 1u);
          }
        }
      }
    }
  }
  __syncthreads();
  u32* gh = hist + (size_t)img * 4096;
  for (int i = threadIdx.x; i < 4096; i += 256) {
    u32 v = lh[i];
    if (v) atomicAdd(&gh[i], v);
  }
}

// ---------------- find boundary bin B and residual T ----------------
__global__ void scan_k(const u32* __restrict__ hist, int* __restrict__ meta) {
  const int img = blockIdx.x;
  const u32* h = hist + (size_t)img * 4096;
  __shared__ u32 lsum[256];
  __shared__ u32 above[256];
  __shared__ u32 s_total;
  const int t = threadIdx.x;
  u32 s = 0;
  for (int j = 0; j < 16; ++j) s += h[t * 16 + j];
  lsum[t] = s;
  __syncthreads();
  if (t == 0) {
    u32 acc = 0;
    for (int i = 255; i >= 0; --i) { above[i] = acc; acc += lsum[i]; }
    s_total = acc;
  }
  __syncthreads();
  const u32 K = PREK;
  int* m = meta + img * 4;
  if (s_total < K) {
    if (t == 0) { m[0] = -1; m[1] = 0; }
  } else {
    if (above[t] < K && above[t] + lsum[t] >= K) {
      u32 cum = above[t];
      for (int j = 15; j >= 0; --j) {
        u32 hv = h[t * 16 + j];
        cum += hv;
        if (cum >= K) { m[0] = t * 16 + j; m[1] = (int)(K - (cum - hv)); break; }
      }
    }
  }
}

// ---- block-staged list flush: one global atomic per list per block ----
__device__ __forceinline__ void flush_list(const u64* llist, int lcnt, int cap,
                                           int* gctr, u64* glist, int gcap) {
  __shared__ int gbase_s;
  int n = lcnt < cap ? lcnt : cap;
  if (threadIdx.x == 0) gbase_s = n ? atomicAdd(gctr, n) : 0;
  __syncthreads();
  const int gb = gbase_s;
  for (int i = threadIdx.x; i < n; i += 256) {
    int pos = gb + i;
    if (pos < gcap) glist[pos] = llist[i];
  }
}

// ---------------- merged gather (all 3 levels), class-chunked, LDS-staged ----------------
__global__ __launch_bounds__(256) void gather_all(const float* __restrict__ in0,
                         const float* __restrict__ in1, const float* __restrict__ in2,
                         const int* __restrict__ meta, int* __restrict__ cnt,
                         u64* __restrict__ winners, u64* __restrict__ boundary) {
  __shared__ u64 lwin[LCAP];
  __shared__ u64 lbnd[LCAP];
  __shared__ int lwc, lbc;
  const int img = blockIdx.y;
  const int c0 = blockIdx.z * GCH;
  if (threadIdx.x == 0) { lwc = 0; lbc = 0; }
  __syncthreads();

  const int B = meta[img * 4 + 0];
  int* cw = &cnt[img * 64];
  int* cb = &cnt[img * 64 + 32];
  u64* wl = winners + (size_t)img * PREK;
  u64* bl = boundary + (size_t)img * BCAP;
  const int bx = blockIdx.x;

  if (bx < 5) {
    // ---- level 0, scalar ----
    const int HW = 361;
    const int r = bx * 256 + threadIdx.x;
    if (r < 3 * HW) {
      const int a = r / HW, p = r - a * HW;
      const float* base = in0 + ((size_t)(img * 255 + a * 85)) * (size_t)HW + p;
      const int boxg = r;
      float l[GCH];
#pragma unroll
      for (int k = 0; k < GCH; ++k) l[k] = base[(size_t)(5 + c0 + k) * HW];
      const float conf = sigmf(base[4 * (size_t)HW]);
#pragma unroll
      for (int k = 0; k < GCH; ++k) {
        float s = conf * sigmf(l[k]);
        if (s > SCORE_TH) {
          u32 key = __float_as_uint(s);
          int wbin = (int)((key >> 14) - BIN_BASE);
          if (wbin >= B) {
            u64 kv = ((u64)key << 32) | (u64)(~(u32)(boxg * NCLS + (c0 + k)));
            if (wbin > B) {
              int p2 = atomicAdd(&lwc, 1);
              if (p2 < LCAP) lwin[p2] = kv;
              else { int g = atomicAdd(cw, 1); if (g < PREK) wl[g] = kv; }
            } else {
              int p2 = atomicAdd(&lbc, 1);
              if (p2 < LCAP) lbnd[p2] = kv;
              else { int g = atomicAdd(cb, 1); if (g < BCAP) bl[g] = kv; }
            }
          }
        }
      }
    }
  } else {
    // ---- levels 1/2, vectorized ----
    const bool L1 = bx < 10;
    const float* in = L1 ? in1 : in2;
    const int HW = L1 ? 1444 : 5776;
    const int lvl_off = L1 ? 1083 : 5415;
    const int HW4 = HW >> 2;
    const int idx = (bx - (L1 ? 5 : 10)) * 256 + threadIdx.x;
    if (idx < 3 * HW4) {
      const int a = idx / HW4;
      const int p0 = (idx - a * HW4) << 2;
      const float* base = in + ((size_t)(img * 255 + a * 85)) * (size_t)HW + p0;
      const int boxg0 = lvl_off + a * HW + p0;
      float4 scv[GCH];
#pragma unroll
      for (int k = 0; k < GCH; ++k)
        scv[k] = *(const float4*)(base + (size_t)(5 + c0 + k) * HW);
      float4 v4 = *(const float4*)(base + 4 * (size_t)HW);
      const float* t4 = (const float*)&v4;
      float conf[4];
#pragma unroll
      for (int i = 0; i < 4; ++i) conf[i] = sigmf(t4[i]);
#pragma unroll
      for (int k = 0; k < GCH; ++k) {
        const float* s4 = (const float*)&scv[k];
        const int c = c0 + k;
#pragma unroll
        for (int i = 0; i < 4; ++i) {
          float s = conf[i] * sigmf(s4[i]);
          if (s > SCORE_TH) {
            u32 key = __float_as_uint(s);
            int wbin = (int)((key >> 14) - BIN_BASE);
            if (wbin >= B) {
              u64 kv = ((u64)key << 32) | (u64)(~(u32)((boxg0 + i) * NCLS + c));
              if (wbin > B) {
                int p = atomicAdd(&lwc, 1);
                if (p < LCAP) lwin[p] = kv;
                else { int g = atomicAdd(cw, 1); if (g < PREK) wl[g] = kv; }
              } else {
                int p = atomicAdd(&lbc, 1);
                if (p < LCAP) lbnd[p] = kv;
                else { int g = atomicAdd(cb, 1); if (g < BCAP) bl[g] = kv; }
              }
            }
          }
        }
      }
    }
  }
  __syncthreads();
  flush_list(lwin, lwc, LCAP, cw, wl, PREK);
  flush_list(lbnd, lbc, LCAP, cb, bl, BCAP);
}

// ---------------- resolve boundary bin: pick exactly T more ----------------
__global__ void resolve_k(const u64* __restrict__ boundary, const int* __restrict__ meta,
                          int* __restrict__ cnt, u64* __restrict__ winners) {
  const int img = blockIdx.x;
  const int T = meta[img * 4 + 1];
  int bc = cnt[img * 64 + 32];
  if (bc > BCAP) bc = BCAP;
  if (T <= 0 || bc <= 0) return;
  const u64* bnd = boundary + (size_t)img * BCAP;
  u64* wl = winners + (size_t)img * PREK;
  int* cw = &cnt[img * 64];

  __shared__ u32 h2[16384];
  __shared__ u32 lsum[256];
  __shared__ u32 above[256];
  __shared__ u32 s_total;
  __shared__ int sB2, sT2;
  __shared__ u64 ties[512];
  __shared__ int tcnt;
  __shared__ u64 lw2[PREK];
  __shared__ int lw2c;
  __shared__ int gbase_s;
  const int t = threadIdx.x;
  for (int i = t; i < 16384; i += 256) h2[i] = 0;
  if (t == 0) { tcnt = 0; sB2 = -1; sT2 = 0; lw2c = 0; }
  __syncthreads();
  for (int i = t; i < bc; i += 256) atomicAdd(&h2[(u32)(bnd[i] >> 32) & 0x3FFFu], 1u);
  __syncthreads();
  u32 s = 0;
  for (int j = 0; j < 64; ++j) s += h2[t * 64 + j];
  lsum[t] = s;
  __syncthreads();
  if (t == 0) {
    u32 acc = 0;
    for (int i = 255; i >= 0; --i) { above[i] = acc; acc += lsum[i]; }
    s_total = acc;
  }
  __syncthreads();
  if ((int)s_total > T) {
    if (above[t] < (u32)T && above[t] + lsum[t] >= (u32)T) {
      u32 cum = above[t];
      for (int j = 63; j >= 0; --j) {
        u32 hv = h2[t * 64 + j];
        cum += hv;
        if (cum >= (u32)T) { sB2 = t * 64 + j; sT2 = (int)((u32)T - (cum - hv)); break; }
      }
    }
  }
  __syncthreads();
  const int B2 = sB2, T2 = sT2;
  for (int i = t; i < bc; i += 256) {
    u64 e = bnd[i];
    int low = (int)((u32)(e >> 32) & 0x3FFFu);
    if (low > B2) {
      int p = atomicAdd(&lw2c, 1);
      if (p < PREK) lw2[p] = e;
    } else if (low == B2) {
      int tp = atomicAdd(&tcnt, 1);
      if (tp < 512) ties[tp] = e;
    }
  }
  __syncthreads();
  int n = lw2c < PREK ? lw2c : PREK;
  if (t == 0) gbase_s = n ? atomicAdd(cw, n) : 0;
  __syncthreads();
  for (int i = t; i < n; i += 256) {
    int pos = gbase_s + i;
    if (pos < PREK) wl[pos] = lw2[i];
  }
  __syncthreads();
  if (t == 0 && T2 > 0) {
    int tc = tcnt < 512 ? tcnt : 512;
    for (int k = 0; k < T2 && k < tc; ++k) {
      int bi = -1; u64 bk = 0;
      for (int i = 0; i < tc; ++i)
        if (ties[i] > bk) { bk = ties[i]; bi = i; }  // same score => larger ~idx = smaller idx first
      if (bi < 0) break;
      ties[bi] = 0;
      int pos = atomicAdd(cw, 1);
      if (pos < PREK) wl[pos] = bk;
    }
  }
}

// ---------------- rank, split j-dimension: partial ranks (plain stores, no atomics) ----------------
__global__ __launch_bounds__(256) void rank_part_k(const u64* __restrict__ winners,
                                                   const int* __restrict__ cnt,
                                                   int* __restrict__ part) {
  __shared__ u64 lk[RJW];
  const int img = blockIdx.y;
  const int kc = blockIdx.x >> 2;       // 16 key-chunks of 256
  const int jc = blockIdx.x & 3;        // 4 j-chunks of 1024
  const int t = threadIdx.x;
  int wc = cnt[img * 64]; if (wc > PREK) wc = PREK;
  const u64* wl = winners + (size_t)img * PREK;
  for (int i = t; i < RJW; i += 256) {
    const int gj = jc * RJW + i;
    lk[i] = (gj < wc) ? wl[gj] : pad_key(gj);
  }
  __syncthreads();
  const int ki_idx = kc * 256 + t;
  const u64 ki = (ki_idx < wc) ? wl[ki_idx] : pad_key(ki_idx);
  int rank = 0;
#pragma unroll 8
  for (int j = 0; j < RJW; ++j) rank += (lk[j] > ki) ? 1 : 0;
  part[(((size_t)img * RJC) + jc) * PREK + ki_idx] = rank;
}

// ---------------- rank scatter: sum partials, write sorted arrays ----------------
__global__ __launch_bounds__(256) void rank_scatter_k(const u64* __restrict__ winners,
                                              const int* __restrict__ cnt,
                                              const int* __restrict__ part,
                                              const float4* __restrict__ boxes,
                                              u64* __restrict__ skey,
                                              float4* __restrict__ sobox,
                                              float* __restrict__ sarea) {
  const int img = blockIdx.y;
  const int i = blockIdx.x * 256 + threadIdx.x;
  int wc = cnt[img * 64]; if (wc > PREK) wc = PREK;
  const u64* wl = winners + (size_t)img * PREK;
  const u64 ki = (i < wc) ? wl[i] : pad_key(i);
  const int* pb = part + (size_t)img * RJC * PREK + i;
  int rank = pb[0] + pb[PREK] + pb[2 * PREK] + pb[3 * PREK];
  skey[(size_t)img * PREK + rank] = ki;
  if (i < wc) {
    u32 ridx = ~(u32)ki;
    int c = (int)(ridx % NCLS);
    int bi = (int)(ridx / NCLS);
    float4 b = boxes[(size_t)img * NBOX + bi];
    float off = 4096.0f * (float)c;
    float4 ob = make_float4(b.x + off, b.y + off, b.z + off, b.w + off);
    sobox[(size_t)img * PREK + rank] = ob;
    sarea[(size_t)img * PREK + rank] = (ob.z - ob.x) * (ob.w - ob.y);
  } else {
    sobox[(size_t)img * PREK + rank] = make_float4(0.f, 0.f, 0.f, 0.f);
    sarea[(size_t)img * PREK + rank] = 0.f;
  }
}

// ---------------- sorted-scan greedy NMS: pairwise matrix + scalar sweep ----------------
__global__ __launch_bounds__(64) void scan_nms_k(const u64* __restrict__ skey,
                                                 const float4* __restrict__ sobox,
                                                 const float* __restrict__ sarea,
                                                 float* __restrict__ out) {
  __shared__ float4 bxc[NCLS][BKCAP];
  __shared__ float  arc[NCLS][BKCAP];
  __shared__ int    cntc[NCLS];
  __shared__ float4 bxa[TOPK];
  __shared__ float  ara[TOPK];
  __shared__ float4 bxh[HCAP];
  __shared__ float  arh[HCAP];
  __shared__ int    nhuge_s;
  __shared__ float4 chb[64];
  __shared__ float  cha[64];
  const int img = blockIdx.x;
  const int lane = threadIdx.x;
  float* orow = out + (size_t)img * (TOPK * 6);
  for (int i = lane; i < TOPK * 6; i += 64) orow[i] = 0.f;
  for (int i = lane; i < NCLS; i += 64) cntc[i] = 0;
  if (lane == 0) nhuge_s = 0;
  const u64* K = skey + (size_t)img * PREK;
  const float4* Bp = sobox + (size_t)img * PREK;
  const float* Ap = sarea + (size_t)img * PREK;
  int nsel = 0;
  for (int chunk = 0; chunk < PREK / 64 && nsel < TOPK; ++chunk) {
    const int j = chunk * 64 + lane;
    const u64 kj = K[j];
    const float score = __uint_as_float((u32)(kj >> 32));
    bool alive = (score > SCORE_TH);
    if (__ballot(alive) == 0ull) break;   // sorted: nothing below passes either
    const float4 ob = Bp[j];
    const float ar = Ap[j];
    const u32 ridx = ~(u32)kj;
    const int myc = (int)(ridx % NCLS);
    const bool huge = (ob.z - ob.x > HUGE_TH) || (ob.w - ob.y > HUGE_TH);
    chb[lane] = ob; cha[lane] = ar;   // stash for pairwise matrix (single wave: no barrier)

    // phase 1a: same-class bucket walk
    {
      const int n0 = cntc[myc];
      const int n = n0 < BKCAP ? n0 : BKCAP;
      for (int k = 0; __ballot(alive && k < n) != 0ull; k += 2) {
        const int k0 = (k < BKCAP - 1) ? k : (BKCAP - 1);
        const int k1 = (k + 1 < BKCAP - 1) ? (k + 1) : (BKCAP - 1);
        const float4 b0 = bxc[myc][k0]; const float a0 = arc[myc][k0];
        const float4 b1 = bxc[myc][k1]; const float a1 = arc[myc][k1];
        if (alive && k < n) {
          float xx1 = fmaxf(b0.x, ob.x), yy1 = fmaxf(b0.y, ob.y);
          float xx2 = fminf(b0.z, ob.z), yy2 = fminf(b0.w, ob.w);
          float inter = fmaxf(xx2 - xx1, 0.f) * fmaxf(yy2 - yy1, 0.f);
          float iou = inter / (a0 + ar - inter + 1e-9f);
          if (iou > IOU_TH) alive = false;
        }
        if (alive && k + 1 < n) {
          float xx1 = fmaxf(b1.x, ob.x), yy1 = fmaxf(b1.y, ob.y);
          float xx2 = fminf(b1.z, ob.z), yy2 = fminf(b1.w, ob.w);
          float inter = fmaxf(xx2 - xx1, 0.f) * fmaxf(yy2 - yy1, 0.f);
          float iou = inter / (a1 + ar - inter + 1e-9f);
          if (iou > IOU_TH) alive = false;
        }
      }
    }
    // phase 1b: vs huge selected
    {
      const int nh = nhuge_s;
      for (int k = 0; k < nh && __ballot(alive) != 0ull; k += 2) {
        const int k0 = (k < nh - 1) ? k : (nh - 1);
        const int k1 = (k + 1 < nh - 1) ? (k + 1) : (nh - 1);
        const float4 b0 = bxh[k0]; const float a0 = arh[k0];
        const float4 b1 = bxh[k1]; const float a1 = arh[k1];
        if (alive) {
          float xx1 = fmaxf(b0.x, ob.x), yy1 = fmaxf(b0.y, ob.y);
          float xx2 = fminf(b0.z, ob.z), yy2 = fminf(b0.w, ob.w);
          float inter = fmaxf(xx2 - xx1, 0.f) * fmaxf(yy2 - yy1, 0.f);
          float iou = inter / (a0 + ar - inter + 1e-9f);
          if (iou > IOU_TH) alive = false;
        }
        if (alive && k + 1 < nh) {
          float xx1 = fmaxf(b1.x, ob.x), yy1 = fmaxf(b1.y, ob.y);
          float xx2 = fminf(b1.z, ob.z), yy2 = fminf(b1.w, ob.w);
          float inter = fmaxf(xx2 - xx1, 0.f) * fmaxf(yy2 - yy1, 0.f);
          float iou = inter / (a1 + ar - inter + 1e-9f);
          if (iou > IOU_TH) alive = false;
        }
      }
    }
    // phase 1c: huge candidates vs ALL selected (rare)
    if (__ballot(alive && huge) != 0ull) {
      const int na = nsel;
      for (int k = 0; k < na; k += 2) {
        const int k0 = (k < na - 1) ? k : (na - 1);
        const int k1 = (k + 1 < na - 1) ? (k + 1) : (na - 1);
        const float4 b0 = bxa[k0]; const float a0 = ara[k0];
        const float4 b1 = bxa[k1]; const float a1 = ara[k1];
        if (alive && huge) {
          float xx1 = fmaxf(b0.x, ob.x), yy1 = fmaxf(b0.y, ob.y);
          float xx2 = fminf(b0.z, ob.z), yy2 = fminf(b0.w, ob.w);
          float inter = fmaxf(xx2 - xx1, 0.f) * fmaxf(yy2 - yy1, 0.f);
          float iou = inter / (a0 + ar - inter + 1e-9f);
          if (iou > IOU_TH) alive = false;
        }
        if (alive && huge && k + 1 < na) {
          float xx1 = fmaxf(b1.x, ob.x), yy1 = fmaxf(b1.y, ob.y);
          float xx2 = fminf(b1.z, ob.z), yy2 = fminf(b1.w, ob.w);
          float inter = fmaxf(xx2 - xx1, 0.f) * fmaxf(yy2 - yy1, 0.f);
          float iou = inter / (a1 + ar - inter + 1e-9f);
          if (iou > IOU_TH) alive = false;
        }
        if (__ballot(alive && huge) == 0ull) break;
      }
    }
    // pairwise in-chunk suppression masks
    u64 sup = 0ull;
#pragma unroll 4
    for (int jj = 0; jj < 64; ++jj) {
      const float4 bj = chb[jj];   // uniform jj -> broadcast read
      const float aj = cha[jj];
      float xx1 = fmaxf(bj.x, ob.x), yy1 = fmaxf(bj.y, ob.y);
      float xx2 = fminf(bj.z, ob.z), yy2 = fminf(bj.w, ob.w);
      float inter = fmaxf(xx2 - xx1, 0.f) * fmaxf(yy2 - yy1, 0.f);
      float iou = inter / (aj + ar - inter + 1e-9f);   // commutative area sum
      if (jj < lane && iou > IOU_TH) sup |= (1ull << jj);
    }
    // scalar greedy sweep
    u64 rem = __ballot(alive);
    u64 selbits = 0ull;
    while (rem != 0ull && nsel + (int)__popcll(selbits) < TOPK) {
      const int b = __builtin_ctzll(rem);
      selbits |= (1ull << b);
      rem &= ~(1ull << b);
      const u64 colb = __ballot((sup >> b) & 1ull);   // lanes suppressed by b
      rem &= ~colb;
    }
    // parallel commit
    const bool selme = (selbits >> lane) & 1ull;
    if (selme) {
      const int slot = nsel + (int)__popcll(selbits & ((1ull << lane) - 1ull));
      bxa[slot] = ob; ara[slot] = ar;
      if (!huge) {
        int cc = atomicAdd(&cntc[myc], 1);
        if (cc < BKCAP) { bxc[myc][cc] = ob; arc[myc][cc] = ar; }
        else { int hn = atomicAdd(&nhuge_s, 1); if (hn < HCAP) { bxh[hn] = ob; arh[hn] = ar; } }
      } else {
        int hn = atomicAdd(&nhuge_s, 1);
        if (hn < HCAP) { bxh[hn] = ob; arh[hn] = ar; }
      }
      const float off = 4096.0f * (float)myc;
      orow[slot * 6 + 0] = ob.x - off;
      orow[slot * 6 + 1] = ob.y - off;
      orow[slot * 6 + 2] = ob.z - off;
      orow[slot * 6 + 3] = ob.w - off;
      orow[slot * 6 + 4] = (float)myc;
      orow[slot * 6 + 5] = score;
    }
    nsel += (int)__popcll(selbits);
  }
}

extern "C" void kernel_launch(void* const* d_in, const int* in_sizes, int n_in,
                              void* d_out, int out_size, void* d_ws, size_t ws_size,
                              hipStream_t stream) {
  const float* in0 = (const float*)d_in[0];
  const float* in1 = (const float*)d_in[5];
  const float* in2 = (const float*)d_in[10];
  char* ws = (char*)d_ws;
  u32* hist = (u32*)(ws + HIST_OFF);
  int* meta = (int*)(ws + META_OFF);
  int* cnt = (int*)(ws + CNT_OFF);
  u64* winners = (u64*)(ws + WIN_OFF);
  u64* boundary = (u64*)(ws + BND_OFF);
  int* part = (int*)(ws + PART_OFF);   // overlays boundary (safe: sequential kernels)
  float4* boxes = (float4*)(ws + BOX_OFF);
  u64* skey = (u64*)(ws + SKEY_OFF);
  float4* sobox = (float4*)(ws + SOBOX_OFF);
  float* sarea = (float*)(ws + SAREA_OFF);
  float* out = (float*)d_out;

  hipMemsetAsync(d_ws, 0, ZERO_BYTES, stream);

  decode_hist_all<<<dim3(27, 8, DNCH), 256, 0, stream>>>(in0, in1, in2, boxes, hist);

  scan_k<<<8, 256, 0, stream>>>(hist, meta);

  gather_all<<<dim3(27, 8, GNCH), 256, 0, stream>>>(in0, in1, in2, meta, cnt, winners, boundary);

  resolve_k<<<8, 256, 0, stream>>>(boundary, meta, cnt, winners);

  rank_part_k<<<dim3(64, 8), 256, 0, stream>>>(winners, cnt, part);
  rank_scatter_k<<<dim3(16, 8), 256, 0, stream>>>(winners, cnt, part, boxes, skey, sobox, sarea);
  scan_nms_k<<<8, 64, 0, stream>>>(skey, sobox, sarea, out);
}

// Round 9
// 117.127 us; speedup vs baseline: 4.7958x; 1.1807x over previous
//
#include <hip/hip_runtime.h>
#include <stdint.h>

typedef unsigned int u32;
typedef unsigned long long u64;

#define NCLS 80
#define NBOX 22743
#define PREK 4096
#define BCAP 65536
#define NIMG 8
#define SCORE_TH 0.01f
#define IOU_TH 0.45f
#define TOPK 200

// class-chunking: decode = 4 chunks x 20 classes, gather = 8 chunks x 10 classes
#define DCH 20
#define DNCH 4
#define GCH 10
#define GNCH 8

// per-block LDS staging capacity for gather hit lists
#define LCAP 1536

// NMS class-bucket params. Cross-class suppression requires w_a+w_b > 2*(4096-608)
// (and same in y) since cx,cy in (0,608) => at least one box has w>3488 || h>3488.
#define BKCAP 8
#define HCAP 224
#define HUGE_TH 3488.0f

// rank split: 4 j-chunks of 1024 keys
#define RJC 4
#define RJW 1024

// ---- workspace layout (bytes) ----
#define HIST_OFF 0
#define META_OFF 131072
#define CNT_OFF  131200
#define ZERO_BYTES 133248
#define WIN_OFF  133248
#define BND_OFF  395392
#define PART_OFF BND_OFF   // overlays boundary (consumed before rank phase)
#define BOX_OFF  4589696
#define SKEY_OFF 7500800
#define SOBOX_OFF 7762944
#define SAREA_OFF 8287232

__device__ __forceinline__ float sigmf(float x) { return 1.0f / (1.0f + expf(-x)); }

// window-offset for float-bit bins: s in (0.01,1] -> (bits>>14) in [61583, 65024]
#define BIN_BASE 61440u

__device__ __forceinline__ u64 pad_key(int i) { return (u64)(~(u32)i); }  // below all real keys, distinct

// ---------------- merged decode + hist (all 3 levels), class-chunked ----------------
// blockIdx.x: [0,5) lvl0 scalar | [5,10) lvl1 v4 | [10,27) lvl2 v4
__global__ __launch_bounds__(256) void decode_hist_all(const float* __restrict__ in0,
                              const float* __restrict__ in1, const float* __restrict__ in2,
                              float4* __restrict__ boxes, u32* __restrict__ hist) {
  __shared__ u32 lh[4096];
  const int img = blockIdx.y;
  const int c0 = blockIdx.z * DCH;
  for (int i = threadIdx.x; i < 4096; i += 256) lh[i] = 0;
  __syncthreads();

  const int bx = blockIdx.x;
  if (bx < 5) {
    // ---- level 0, scalar: W=19, HW=361, off=0, stride=32 ----
    const int W = 19, HW = 361;
    const int r = bx * 256 + threadIdx.x;
    if (r < 3 * HW) {
      const int a = r / HW, p = r - a * HW;
      const int y = p / W, x = p - y * W;
      const float* base = in0 + ((size_t)(img * 255 + a * 85)) * (size_t)HW + p;
      float l[DCH];
#pragma unroll
      for (int k = 0; k < DCH; ++k) l[k] = base[(size_t)(5 + c0 + k) * HW];
      const float x4 = base[4 * (size_t)HW];
      if (c0 == 0) {
        const float aw = (a == 0) ? 3.625f : ((a == 1) ? 4.875f : 11.65625f);
        const float ah = (a == 0) ? 2.8125f : ((a == 1) ? 6.1875f : 10.1875f);
        const float x0 = base[0];
        const float x1 = base[(size_t)HW];
        const float x2 = base[2 * (size_t)HW];
        const float x3 = base[3 * (size_t)HW];
        const float px = sigmf(x0) + (float)x;
        const float py = sigmf(x1) + (float)y;
        const float pw = expf(x2) * aw;
        const float ph = expf(x3) * ah;
        const float cx = px * 32.f, cy = py * 32.f, bw = pw * 32.f, bh = ph * 32.f;
        boxes[(size_t)img * NBOX + r] =
            make_float4(cx - bw * 0.5f, cy - bh * 0.5f, cx + bw * 0.5f, cy + bh * 0.5f);
      }
      const float conf = sigmf(x4);
      if (conf > SCORE_TH) {
#pragma unroll
        for (int k = 0; k < DCH; ++k) {
          float s = conf * sigmf(l[k]);
          if (s > SCORE_TH) {
            u32 bin = (__float_as_uint(s) >> 14) - BIN_BASE;
            atomicAdd(&lh[bin], 1u);
          }
        }
      }
    }
  } else {
    // ---- levels 1/2, vectorized ----
    const bool L1 = bx < 10;
    const float* in = L1 ? in1 : in2;
    const int W = L1 ? 38 : 76;
    const int HW = L1 ? 1444 : 5776;
    const int lvl_off = L1 ? 1083 : 5415;
    const float stride = L1 ? 16.f : 8.f;
    const int HW4 = HW >> 2;
    const int idx = (bx - (L1 ? 5 : 10)) * 256 + threadIdx.x;
    if (idx < 3 * HW4) {
      const int a = idx / HW4;
      const int p0 = (idx - a * HW4) << 2;
      const float* base = in + ((size_t)(img * 255 + a * 85)) * (size_t)HW + p0;
      float4 scv[DCH];
#pragma unroll
      for (int k = 0; k < DCH; ++k)
        scv[k] = *(const float4*)(base + (size_t)(5 + c0 + k) * HW);
      float4 v4 = *(const float4*)(base + 4 * (size_t)HW);
      const float* t4 = (const float*)&v4;
      float conf[4];
      if (c0 == 0) {
        const float aw = L1 ? ((a == 0) ? 1.875f : ((a == 1) ? 3.875f : 3.6875f))
                            : ((a == 0) ? 1.25f : ((a == 1) ? 2.f : 4.125f));
        const float ah = L1 ? ((a == 0) ? 3.8125f : ((a == 1) ? 2.8125f : 7.4375f))
                            : ((a == 0) ? 1.625f : ((a == 1) ? 3.75f : 2.875f));
        float4 v0 = *(const float4*)(base);
        float4 v1 = *(const float4*)(base + (size_t)HW);
        float4 v2 = *(const float4*)(base + 2 * (size_t)HW);
        float4 v3 = *(const float4*)(base + 3 * (size_t)HW);
        const float* t0 = (const float*)&v0;
        const float* t1 = (const float*)&v1;
        const float* t2 = (const float*)&v2;
        const float* t3 = (const float*)&v3;
        float4* bout = boxes + (size_t)img * NBOX + lvl_off + a * HW + p0;
#pragma unroll
        for (int i = 0; i < 4; ++i) {
          const int p = p0 + i;
          const int y = p / W, x = p - y * W;
          const float px = sigmf(t0[i]) + (float)x;
          const float py = sigmf(t1[i]) + (float)y;
          const float pw = expf(t2[i]) * aw;
          const float ph = expf(t3[i]) * ah;
          const float cx = px * stride, cy = py * stride, bw = pw * stride, bh = ph * stride;
          bout[i] = make_float4(cx - bw * 0.5f, cy - bh * 0.5f, cx + bw * 0.5f, cy + bh * 0.5f);
        }
      }
#pragma unroll
      for (int i = 0; i < 4; ++i) conf[i] = sigmf(t4[i]);
#pragma unroll
      for (int k = 0; k < DCH; ++k) {
        const float* s4 = (const float*)&scv[k];
#pragma unroll
        for (int i = 0; i < 4; ++i) {
          float s = conf[i] * sigmf(s4[i]);
          if (s > SCORE_TH) {
            u32 bin = (__float_as_uint(s) >> 14) - BIN_BASE;
            atomicAdd(&lh[bin], 1u);
          }
        }
      }
    }
  }
  __syncthreads();
  u32* gh = hist + (size_t)img * 4096;
  for (int i = threadIdx.x; i < 4096; i += 256) {
    u32 v = lh[i];
    if (v) atomicAdd(&gh[i], v);
  }
}

// ---------------- find boundary bin B and residual T ----------------
__global__ void scan_k(const u32* __restrict__ hist, int* __restrict__ meta) {
  const int img = blockIdx.x;
  const u32* h = hist + (size_t)img * 4096;
  __shared__ u32 lsum[256];
  __shared__ u32 above[256];
  __shared__ u32 s_total;
  const int t = threadIdx.x;
  u32 s = 0;
  for (int j = 0; j < 16; ++j) s += h[t * 16 + j];
  lsum[t] = s;
  __syncthreads();
  if (t == 0) {
    u32 acc = 0;
    for (int i = 255; i >= 0; --i) { above[i] = acc; acc += lsum[i]; }
    s_total = acc;
  }
  __syncthreads();
  const u32 K = PREK;
  int* m = meta + img * 4;
  if (s_total < K) {
    if (t == 0) { m[0] = -1; m[1] = 0; }
  } else {
    if (above[t] < K && above[t] + lsum[t] >= K) {
      u32 cum = above[t];
      for (int j = 15; j >= 0; --j) {
        u32 hv = h[t * 16 + j];
        cum += hv;
        if (cum >= K) { m[0] = t * 16 + j; m[1] = (int)(K - (cum - hv)); break; }
      }
    }
  }
}

// ---- block-staged list flush: one global atomic per list per block ----
__device__ __forceinline__ void flush_list(const u64* llist, int lcnt, int cap,
                                           int* gctr, u64* glist, int gcap) {
  __shared__ int gbase_s;
  int n = lcnt < cap ? lcnt : cap;
  if (threadIdx.x == 0) gbase_s = n ? atomicAdd(gctr, n) : 0;
  __syncthreads();
  const int gb = gbase_s;
  for (int i = threadIdx.x; i < n; i += 256) {
    int pos = gb + i;
    if (pos < gcap) glist[pos] = llist[i];
  }
}

// ---------------- merged gather (all 3 levels), class-chunked, LDS-staged ----------------
__global__ __launch_bounds__(256) void gather_all(const float* __restrict__ in0,
                         const float* __restrict__ in1, const float* __restrict__ in2,
                         const int* __restrict__ meta, int* __restrict__ cnt,
                         u64* __restrict__ winners, u64* __restrict__ boundary) {
  __shared__ u64 lwin[LCAP];
  __shared__ u64 lbnd[LCAP];
  __shared__ int lwc, lbc;
  const int img = blockIdx.y;
  const int c0 = blockIdx.z * GCH;
  if (threadIdx.x == 0) { lwc = 0; lbc = 0; }
  __syncthreads();

  const int B = meta[img * 4 + 0];
  int* cw = &cnt[img * 64];
  int* cb = &cnt[img * 64 + 32];
  u64* wl = winners + (size_t)img * PREK;
  u64* bl = boundary + (size_t)img * BCAP;
  const int bx = blockIdx.x;

  if (bx < 5) {
    // ---- level 0, scalar ----
    const int HW = 361;
    const int r = bx * 256 + threadIdx.x;
    if (r < 3 * HW) {
      const int a = r / HW, p = r - a * HW;
      const float* base = in0 + ((size_t)(img * 255 + a * 85)) * (size_t)HW + p;
      const int boxg = r;
      float l[GCH];
#pragma unroll
      for (int k = 0; k < GCH; ++k) l[k] = base[(size_t)(5 + c0 + k) * HW];
      const float conf = sigmf(base[4 * (size_t)HW]);
#pragma unroll
      for (int k = 0; k < GCH; ++k) {
        float s = conf * sigmf(l[k]);
        if (s > SCORE_TH) {
          u32 key = __float_as_uint(s);
          int wbin = (int)((key >> 14) - BIN_BASE);
          if (wbin >= B) {
            u64 kv = ((u64)key << 32) | (u64)(~(u32)(boxg * NCLS + (c0 + k)));
            if (wbin > B) {
              int p2 = atomicAdd(&lwc, 1);
              if (p2 < LCAP) lwin[p2] = kv;
              else { int g = atomicAdd(cw, 1); if (g < PREK) wl[g] = kv; }
            } else {
              int p2 = atomicAdd(&lbc, 1);
              if (p2 < LCAP) lbnd[p2] = kv;
              else { int g = atomicAdd(cb, 1); if (g < BCAP) bl[g] = kv; }
            }
          }
        }
      }
    }
  } else {
    // ---- levels 1/2, vectorized ----
    const bool L1 = bx < 10;
    const float* in = L1 ? in1 : in2;
    const int HW = L1 ? 1444 : 5776;
    const int lvl_off = L1 ? 1083 : 5415;
    const int HW4 = HW >> 2;
    const int idx = (bx - (L1 ? 5 : 10)) * 256 + threadIdx.x;
    if (idx < 3 * HW4) {
      const int a = idx / HW4;
      const int p0 = (idx - a * HW4) << 2;
      const float* base = in + ((size_t)(img * 255 + a * 85)) * (size_t)HW + p0;
      const int boxg0 = lvl_off + a * HW + p0;
      float4 scv[GCH];
#pragma unroll
      for (int k = 0; k < GCH; ++k)
        scv[k] = *(const float4*)(base + (size_t)(5 + c0 + k) * HW);
      float4 v4 = *(const float4*)(base + 4 * (size_t)HW);
      const float* t4 = (const float*)&v4;
      float conf[4];
#pragma unroll
      for (int i = 0; i < 4; ++i) conf[i] = sigmf(t4[i]);
#pragma unroll
      for (int k = 0; k < GCH; ++k) {
        const float* s4 = (const float*)&scv[k];
        const int c = c0 + k;
#pragma unroll
        for (int i = 0; i < 4; ++i) {
          float s = conf[i] * sigmf(s4[i]);
          if (s > SCORE_TH) {
            u32 key = __float_as_uint(s);
            int wbin = (int)((key >> 14) - BIN_BASE);
            if (wbin >= B) {
              u64 kv = ((u64)key << 32) | (u64)(~(u32)((boxg0 + i) * NCLS + c));
              if (wbin > B) {
                int p = atomicAdd(&lwc, 1);
                if (p < LCAP) lwin[p] = kv;
                else { int g = atomicAdd(cw, 1); if (g < PREK) wl[g] = kv; }
              } else {
                int p = atomicAdd(&lbc, 1);
                if (p < LCAP) lbnd[p] = kv;
                else { int g = atomicAdd(cb, 1); if (g < BCAP) bl[g] = kv; }
              }
            }
          }
        }
      }
    }
  }
  __syncthreads();
  flush_list(lwin, lwc, LCAP, cw, wl, PREK);
  flush_list(lbnd, lbc, LCAP, cb, bl, BCAP);
}

// ---------------- resolve boundary bin: pick exactly T more ----------------
__global__ void resolve_k(const u64* __restrict__ boundary, const int* __restrict__ meta,
                          int* __restrict__ cnt, u64* __restrict__ winners) {
  const int img = blockIdx.x;
  const int T = meta[img * 4 + 1];
  int bc = cnt[img * 64 + 32];
  if (bc > BCAP) bc = BCAP;
  if (T <= 0 || bc <= 0) return;
  const u64* bnd = boundary + (size_t)img * BCAP;
  u64* wl = winners + (size_t)img * PREK;
  int* cw = &cnt[img * 64];

  __shared__ u32 h2[16384];
  __shared__ u32 lsum[256];
  __shared__ u32 above[256];
  __shared__ u32 s_total;
  __shared__ int sB2, sT2;
  __shared__ u64 ties[512];
  __shared__ int tcnt;
  __shared__ u64 lw2[PREK];
  __shared__ int lw2c;
  __shared__ int gbase_s;
  const int t = threadIdx.x;
  for (int i = t; i < 16384; i += 256) h2[i] = 0;
  if (t == 0) { tcnt = 0; sB2 = -1; sT2 = 0; lw2c = 0; }
  __syncthreads();
  for (int i = t; i < bc; i += 256) atomicAdd(&h2[(u32)(bnd[i] >> 32) & 0x3FFFu], 1u);
  __syncthreads();
  u32 s = 0;
  for (int j = 0; j < 64; ++j) s += h2[t * 64 + j];
  lsum[t] = s;
  __syncthreads();
  if (t == 0) {
    u32 acc = 0;
    for (int i = 255; i >= 0; --i) { above[i] = acc; acc += lsum[i]; }
    s_total = acc;
  }
  __syncthreads();
  if ((int)s_total > T) {
    if (above[t] < (u32)T && above[t] + lsum[t] >= (u32)T) {
      u32 cum = above[t];
      for (int j = 63; j >= 0; --j) {
        u32 hv = h2[t * 64 + j];
        cum += hv;
        if (cum >= (u32)T) { sB2 = t * 64 + j; sT2 = (int)((u32)T - (cum - hv)); break; }
      }
    }
  }
  __syncthreads();
  const int B2 = sB2, T2 = sT2;
  for (int i = t; i < bc; i += 256) {
    u64 e = bnd[i];
    int low = (int)((u32)(e >> 32) & 0x3FFFu);
    if (low > B2) {
      int p = atomicAdd(&lw2c, 1);
      if (p < PREK) lw2[p] = e;
    } else if (low == B2) {
      int tp = atomicAdd(&tcnt, 1);
      if (tp < 512) ties[tp] = e;
    }
  }
  __syncthreads();
  int n = lw2c < PREK ? lw2c : PREK;
  if (t == 0) gbase_s = n ? atomicAdd(cw, n) : 0;
  __syncthreads();
  for (int i = t; i < n; i += 256) {
    int pos = gbase_s + i;
    if (pos < PREK) wl[pos] = lw2[i];
  }
  __syncthreads();
  if (t == 0 && T2 > 0) {
    int tc = tcnt < 512 ? tcnt : 512;
    for (int k = 0; k < T2 && k < tc; ++k) {
      int bi = -1; u64 bk = 0;
      for (int i = 0; i < tc; ++i)
        if (ties[i] > bk) { bk = ties[i]; bi = i; }  // same score => larger ~idx = smaller idx first
      if (bi < 0) break;
      ties[bi] = 0;
      int pos = atomicAdd(cw, 1);
      if (pos < PREK) wl[pos] = bk;
    }
  }
}

// ---------------- rank, split j-dimension: partial ranks (plain stores, no atomics) ----------------
__global__ __launch_bounds__(256) void rank_part_k(const u64* __restrict__ winners,
                                                   const int* __restrict__ cnt,
                                                   int* __restrict__ part) {
  __shared__ u64 lk[RJW];
  const int img = blockIdx.y;
  const int kc = blockIdx.x >> 2;       // 16 key-chunks of 256
  const int jc = blockIdx.x & 3;        // 4 j-chunks of 1024
  const int t = threadIdx.x;
  int wc = cnt[img * 64]; if (wc > PREK) wc = PREK;
  const u64* wl = winners + (size_t)img * PREK;
  for (int i = t; i < RJW; i += 256) {
    const int gj = jc * RJW + i;
    lk[i] = (gj < wc) ? wl[gj] : pad_key(gj);
  }
  __syncthreads();
  const int ki_idx = kc * 256 + t;
  const u64 ki = (ki_idx < wc) ? wl[ki_idx] : pad_key(ki_idx);
  int rank = 0;
#pragma unroll 8
  for (int j = 0; j < RJW; ++j) rank += (lk[j] > ki) ? 1 : 0;
  part[(((size_t)img * RJC) + jc) * PREK + ki_idx] = rank;
}

// ---------------- rank scatter: sum partials, write sorted arrays ----------------
__global__ __launch_bounds__(256) void rank_scatter_k(const u64* __restrict__ winners,
                                              const int* __restrict__ cnt,
                                              const int* __restrict__ part,
                                              const float4* __restrict__ boxes,
                                              u64* __restrict__ skey,
                                              float4* __restrict__ sobox,
                                              float* __restrict__ sarea) {
  const int img = blockIdx.y;
  const int i = blockIdx.x * 256 + threadIdx.x;
  int wc = cnt[img * 64]; if (wc > PREK) wc = PREK;
  const u64* wl = winners + (size_t)img * PREK;
  const u64 ki = (i < wc) ? wl[i] : pad_key(i);
  const int* pb = part + (size_t)img * RJC * PREK + i;
  int rank = pb[0] + pb[PREK] + pb[2 * PREK] + pb[3 * PREK];
  skey[(size_t)img * PREK + rank] = ki;
  if (i < wc) {
    u32 ridx = ~(u32)ki;
    int c = (int)(ridx % NCLS);
    int bi = (int)(ridx / NCLS);
    float4 b = boxes[(size_t)img * NBOX + bi];
    float off = 4096.0f * (float)c;
    float4 ob = make_float4(b.x + off, b.y + off, b.z + off, b.w + off);
    sobox[(size_t)img * PREK + rank] = ob;
    sarea[(size_t)img * PREK + rank] = (ob.z - ob.x) * (ob.w - ob.y);
  } else {
    sobox[(size_t)img * PREK + rank] = make_float4(0.f, 0.f, 0.f, 0.f);
    sarea[(size_t)img * PREK + rank] = 0.f;
  }
}

// ---------------- sorted-scan greedy NMS: ballot class-match + bit-iterated pairs ----------------
// Exact-superset argument (round-5): only same-class pairs or pairs involving a "huge"
// box (w>3488||h>3488) can have IoU>0 across the 4096*class offset. In-chunk pair tests
// are restricted to that superset via a 7-ballot class-match matrix; every tested pair
// uses the identical float IoU expression => bit-identical greedy decisions.
__global__ __launch_bounds__(64) void scan_nms_k(const u64* __restrict__ skey,
                                                 const float4* __restrict__ sobox,
                                                 const float* __restrict__ sarea,
                                                 float* __restrict__ out) {
  __shared__ float4 bxc[NCLS][BKCAP];
  __shared__ float  arc[NCLS][BKCAP];
  __shared__ int    cntc[NCLS];
  __shared__ float4 bxa[TOPK];
  __shared__ float  ara[TOPK];
  __shared__ float4 bxh[HCAP];
  __shared__ float  arh[HCAP];
  __shared__ int    nhuge_s;
  __shared__ float4 chb[64];
  __shared__ float  cha[64];
  const int img = blockIdx.x;
  const int lane = threadIdx.x;
  float* orow = out + (size_t)img * (TOPK * 6);
  for (int i = lane; i < TOPK * 6; i += 64) orow[i] = 0.f;
  for (int i = lane; i < NCLS; i += 64) cntc[i] = 0;
  if (lane == 0) nhuge_s = 0;
  const u64* K = skey + (size_t)img * PREK;
  const float4* Bp = sobox + (size_t)img * PREK;
  const float* Ap = sarea + (size_t)img * PREK;
  int nsel = 0;
  // software-pipelined chunk loads
  u64 kj = K[lane];
  float4 ob = Bp[lane];
  float ar = Ap[lane];
  for (int chunk = 0; chunk < PREK / 64 && nsel < TOPK; ++chunk) {
    // prefetch next chunk early (hidden under this chunk's compute)
    u64 kj_n = 0ull; float4 ob_n = make_float4(0.f, 0.f, 0.f, 0.f); float ar_n = 0.f;
    if (chunk + 1 < PREK / 64) {
      const int jn = (chunk + 1) * 64 + lane;
      kj_n = K[jn]; ob_n = Bp[jn]; ar_n = Ap[jn];
    }
    const float score = __uint_as_float((u32)(kj >> 32));
    bool alive = (score > SCORE_TH);
    if (__ballot(alive) == 0ull) break;   // sorted: nothing below passes either
    const u32 ridx = ~(u32)kj;
    const int myc = (int)(ridx % NCLS);
    const bool huge = (ob.z - ob.x > HUGE_TH) || (ob.w - ob.y > HUGE_TH);
    chb[lane] = ob; cha[lane] = ar;   // single wave: no barrier needed

    // 7-ballot class-match matrix: mm bit jj = (class_jj == myc)
    u64 mm = ~0ull;
#pragma unroll
    for (int k = 0; k < 7; ++k) {
      const u64 bk = __ballot(((myc >> k) & 1) != 0);
      mm &= (((myc >> k) & 1) != 0) ? bk : ~bk;
    }
    const u64 hb = __ballot(huge);

    // phase 1a: same-class bucket walk (vs earlier-chunk selections)
    {
      const int n0 = cntc[myc];
      const int n = n0 < BKCAP ? n0 : BKCAP;
      for (int k = 0; __ballot(alive && k < n) != 0ull; k += 2) {
        const int k0 = (k < BKCAP - 1) ? k : (BKCAP - 1);
        const int k1 = (k + 1 < BKCAP - 1) ? (k + 1) : (BKCAP - 1);
        const float4 b0 = bxc[myc][k0]; const float a0 = arc[myc][k0];
        const float4 b1 = bxc[myc][k1]; const float a1 = arc[myc][k1];
        if (alive && k < n) {
          float xx1 = fmaxf(b0.x, ob.x), yy1 = fmaxf(b0.y, ob.y);
          float xx2 = fminf(b0.z, ob.z), yy2 = fminf(b0.w, ob.w);
          float inter = fmaxf(xx2 - xx1, 0.f) * fmaxf(yy2 - yy1, 0.f);
          float iou = inter / (a0 + ar - inter + 1e-9f);
          if (iou > IOU_TH) alive = false;
        }
        if (alive && k + 1 < n) {
          float xx1 = fmaxf(b1.x, ob.x), yy1 = fmaxf(b1.y, ob.y);
          float xx2 = fminf(b1.z, ob.z), yy2 = fminf(b1.w, ob.w);
          float inter = fmaxf(xx2 - xx1, 0.f) * fmaxf(yy2 - yy1, 0.f);
          float iou = inter / (a1 + ar - inter + 1e-9f);
          if (iou > IOU_TH) alive = false;
        }
      }
    }
    // phase 1b: vs huge selected
    {
      const int nh = nhuge_s;
      for (int k = 0; k < nh && __ballot(alive) != 0ull; k += 2) {
        const int k0 = (k < nh - 1) ? k : (nh - 1);
        const int k1 = (k + 1 < nh - 1) ? (k + 1) : (nh - 1);
        const float4 b0 = bxh[k0]; const float a0 = arh[k0];
        const float4 b1 = bxh[k1]; const float a1 = arh[k1];
        if (alive) {
          float xx1 = fmaxf(b0.x, ob.x), yy1 = fmaxf(b0.y, ob.y);
          float xx2 = fminf(b0.z, ob.z), yy2 = fminf(b0.w, ob.w);
          float inter = fmaxf(xx2 - xx1, 0.f) * fmaxf(yy2 - yy1, 0.f);
          float iou = inter / (a0 + ar - inter + 1e-9f);
          if (iou > IOU_TH) alive = false;
        }
        if (alive && k + 1 < nh) {
          float xx1 = fmaxf(b1.x, ob.x), yy1 = fmaxf(b1.y, ob.y);
          float xx2 = fminf(b1.z, ob.z), yy2 = fminf(b1.w, ob.w);
          float inter = fmaxf(xx2 - xx1, 0.f) * fmaxf(yy2 - yy1, 0.f);
          float iou = inter / (a1 + ar - inter + 1e-9f);
          if (iou > IOU_TH) alive = false;
        }
      }
    }
    // phase 1c: huge candidates vs ALL selected (rare)
    if (__ballot(alive && huge) != 0ull) {
      const int na = nsel;
      for (int k = 0; k < na; k += 2) {
        const int k0 = (k < na - 1) ? k : (na - 1);
        const int k1 = (k + 1 < na - 1) ? (k + 1) : (na - 1);
        const float4 b0 = bxa[k0]; const float a0 = ara[k0];
        const float4 b1 = bxa[k1]; const float a1 = ara[k1];
        if (alive && huge) {
          float xx1 = fmaxf(b0.x, ob.x), yy1 = fmaxf(b0.y, ob.y);
          float xx2 = fminf(b0.z, ob.z), yy2 = fminf(b0.w, ob.w);
          float inter = fmaxf(xx2 - xx1, 0.f) * fmaxf(yy2 - yy1, 0.f);
          float iou = inter / (a0 + ar - inter + 1e-9f);
          if (iou > IOU_TH) alive = false;
        }
        if (alive && huge && k + 1 < na) {
          float xx1 = fmaxf(b1.x, ob.x), yy1 = fmaxf(b1.y, ob.y);
          float xx2 = fminf(b1.z, ob.z), yy2 = fminf(b1.w, ob.w);
          float inter = fmaxf(xx2 - xx1, 0.f) * fmaxf(yy2 - yy1, 0.f);
          float iou = inter / (a1 + ar - inter + 1e-9f);
          if (iou > IOU_TH) alive = false;
        }
        if (__ballot(alive && huge) == 0ull) break;
      }
    }
    // in-chunk suppression: only same-class / huge pairs among still-alive lanes.
    // selected lanes are a subset of alive-after-phase-1, so pruning dead jj is exact.
    const u64 amask = __ballot(alive);
    const u64 below = (1ull << lane) - 1ull;
    u64 tm = alive ? ((mm | hb | (huge ? ~0ull : 0ull)) & below & amask) : 0ull;
    u64 sup = 0ull;
    while (tm) {
      const int t = (int)__builtin_ctzll(tm);
      tm &= tm - 1ull;
      const float4 bj = chb[t];
      const float aj = cha[t];
      float xx1 = fmaxf(bj.x, ob.x), yy1 = fmaxf(bj.y, ob.y);
      float xx2 = fminf(bj.z, ob.z), yy2 = fminf(bj.w, ob.w);
      float inter = fmaxf(xx2 - xx1, 0.f) * fmaxf(yy2 - yy1, 0.f);
      float iou = inter / (aj + ar - inter + 1e-9f);   // suppressor-first area sum (ref order)
      if (iou > IOU_TH) sup |= (1ull << t);
    }
    // scalar greedy sweep (exact rank order; 1 ballot per selection)
    u64 rem = amask;
    u64 selbits = 0ull;
    while (rem != 0ull && nsel + (int)__popcll(selbits) < TOPK) {
      const int b = __builtin_ctzll(rem);
      selbits |= (1ull << b);
      rem &= ~(1ull << b);
      const u64 colb = __ballot((sup >> b) & 1ull);   // lanes suppressed by b
      rem &= ~colb;
    }
    // parallel commit
    const bool selme = (selbits >> lane) & 1ull;
    if (selme) {
      const int slot = nsel + (int)__popcll(selbits & ((1ull << lane) - 1ull));
      bxa[slot] = ob; ara[slot] = ar;
      if (!huge) {
        int cc = atomicAdd(&cntc[myc], 1);
        if (cc < BKCAP) { bxc[myc][cc] = ob; arc[myc][cc] = ar; }
        else { int hn = atomicAdd(&nhuge_s, 1); if (hn < HCAP) { bxh[hn] = ob; arh[hn] = ar; } }
      } else {
        int hn = atomicAdd(&nhuge_s, 1);
        if (hn < HCAP) { bxh[hn] = ob; arh[hn] = ar; }
      }
      const float off = 4096.0f * (float)myc;
      orow[slot * 6 + 0] = ob.x - off;
      orow[slot * 6 + 1] = ob.y - off;
      orow[slot * 6 + 2] = ob.z - off;
      orow[slot * 6 + 3] = ob.w - off;
      orow[slot * 6 + 4] = (float)myc;
      orow[slot * 6 + 5] = score;
    }
    nsel += (int)__popcll(selbits);
    kj = kj_n; ob = ob_n; ar = ar_n;
  }
}

extern "C" void kernel_launch(void* const* d_in, const int* in_sizes, int n_in,
                              void* d_out, int out_size, void* d_ws, size_t ws_size,
                              hipStream_t stream) {
  const float* in0 = (const float*)d_in[0];
  const float* in1 = (const float*)d_in[5];
  const float* in2 = (const float*)d_in[10];
  char* ws = (char*)d_ws;
  u32* hist = (u32*)(ws + HIST_OFF);
  int* meta = (int*)(ws + META_OFF);
  int* cnt = (int*)(ws + CNT_OFF);
  u64* winners = (u64*)(ws + WIN_OFF);
  u64* boundary = (u64*)(ws + BND_OFF);
  int* part = (int*)(ws + PART_OFF);   // overlays boundary (safe: sequential kernels)
  float4* boxes = (float4*)(ws + BOX_OFF);
  u64* skey = (u64*)(ws + SKEY_OFF);
  float4* sobox = (float4*)(ws + SOBOX_OFF);
  float* sarea = (float*)(ws + SAREA_OFF);
  float* out = (float*)d_out;

  hipMemsetAsync(d_ws, 0, ZERO_BYTES, stream);

  decode_hist_all<<<dim3(27, 8, DNCH), 256, 0, stream>>>(in0, in1, in2, boxes, hist);

  scan_k<<<8, 256, 0, stream>>>(hist, meta);

  gather_all<<<dim3(27, 8, GNCH), 256, 0, stream>>>(in0, in1, in2, meta, cnt, winners, boundary);

  resolve_k<<<8, 256, 0, stream>>>(boundary, meta, cnt, winners);

  rank_part_k<<<dim3(64, 8), 256, 0, stream>>>(winners, cnt, part);
  rank_scatter_k<<<dim3(16, 8), 256, 0, stream>>>(winners, cnt, part, boxes, skey, sobox, sarea);
  scan_nms_k<<<8, 64, 0, stream>>>(skey, sobox, sarea, out);
}

// Round 10
// 113.321 us; speedup vs baseline: 4.9569x; 1.0336x over previous
//
#include <hip/hip_runtime.h>
#include <stdint.h>

typedef unsigned int u32;
typedef unsigned long long u64;

#define NCLS 80
#define NBOX 22743
#define PREK 4096
#define BCAP 65536
#define NIMG 8
#define SCORE_TH 0.01f
#define IOU_TH 0.45f
#define TOPK 200

// class-chunking: decode = 4 chunks x 20 classes, gather = 8 chunks x 10 classes
#define DCH 20
#define DNCH 4
#define GCH 10
#define GNCH 8

// per-block LDS staging capacity for gather hit lists
#define LCAP 1536

// NMS class-bucket params. Cross-class suppression requires w_a+w_b > 2*(4096-608)
// (and same in y) since cx,cy in (0,608) => at least one box has w>3488 || h>3488.
#define BKCAP 8
#define HCAP 224
#define HUGE_TH 3488.0f

// rank split: 4 j-chunks of 1024 keys
#define RJC 4
#define RJW 1024

// ---- workspace layout (bytes) ----
#define HIST_OFF 0
#define CNT_OFF  131200
#define ZERO_BYTES 133248      // hist[8][4096] + pad + cnt[8][64]; 8328 uint4
#define WIN_OFF  133248
#define BND_OFF  395392
#define PART_OFF BND_OFF   // overlays boundary (consumed before rank phase)
#define BOX_OFF  4589696
#define SKEY_OFF 7500800
#define SOBOX_OFF 7762944
#define SAREA_OFF 8287232

__device__ __forceinline__ float sigmf(float x) { return 1.0f / (1.0f + expf(-x)); }

// window-offset for float-bit bins: s in (0.01,1] -> (bits>>14) in [61583, 65024]
#define BIN_BASE 61440u

__device__ __forceinline__ u64 pad_key(int i) { return (u64)(~(u32)i); }  // below all real keys, distinct

// ---------------- workspace zero-init (replaces hipMemsetAsync) ----------------
__global__ __launch_bounds__(256) void init_k(uint4* __restrict__ ws) {
  const int i = blockIdx.x * 256 + threadIdx.x;
  if (i < ZERO_BYTES / 16) ws[i] = make_uint4(0u, 0u, 0u, 0u);
}

// ---------------- merged decode + hist (all 3 levels), class-chunked ----------------
// blockIdx.x: [0,5) lvl0 scalar | [5,10) lvl1 v4 | [10,27) lvl2 v4
__global__ __launch_bounds__(256) void decode_hist_all(const float* __restrict__ in0,
                              const float* __restrict__ in1, const float* __restrict__ in2,
                              float4* __restrict__ boxes, u32* __restrict__ hist) {
  __shared__ u32 lh[4096];
  const int img = blockIdx.y;
  const int c0 = blockIdx.z * DCH;
  for (int i = threadIdx.x; i < 4096; i += 256) lh[i] = 0;
  __syncthreads();

  const int bx = blockIdx.x;
  if (bx < 5) {
    // ---- level 0, scalar: W=19, HW=361, off=0, stride=32 ----
    const int W = 19, HW = 361;
    const int r = bx * 256 + threadIdx.x;
    if (r < 3 * HW) {
      const int a = r / HW, p = r - a * HW;
      const int y = p / W, x = p - y * W;
      const float* base = in0 + ((size_t)(img * 255 + a * 85)) * (size_t)HW + p;
      float l[DCH];
#pragma unroll
      for (int k = 0; k < DCH; ++k) l[k] = base[(size_t)(5 + c0 + k) * HW];
      const float x4 = base[4 * (size_t)HW];
      if (c0 == 0) {
        const float aw = (a == 0) ? 3.625f : ((a == 1) ? 4.875f : 11.65625f);
        const float ah = (a == 0) ? 2.8125f : ((a == 1) ? 6.1875f : 10.1875f);
        const float x0 = base[0];
        const float x1 = base[(size_t)HW];
        const float x2 = base[2 * (size_t)HW];
        const float x3 = base[3 * (size_t)HW];
        const float px = sigmf(x0) + (float)x;
        const float py = sigmf(x1) + (float)y;
        const float pw = expf(x2) * aw;
        const float ph = expf(x3) * ah;
        const float cx = px * 32.f, cy = py * 32.f, bw = pw * 32.f, bh = ph * 32.f;
        boxes[(size_t)img * NBOX + r] =
            make_float4(cx - bw * 0.5f, cy - bh * 0.5f, cx + bw * 0.5f, cy + bh * 0.5f);
      }
      const float conf = sigmf(x4);
      if (conf > SCORE_TH) {
#pragma unroll
        for (int k = 0; k < DCH; ++k) {
          float s = conf * sigmf(l[k]);
          if (s > SCORE_TH) {
            u32 bin = (__float_as_uint(s) >> 14) - BIN_BASE;
            atomicAdd(&lh[bin], 1u);
          }
        }
      }
    }
  } else {
    // ---- levels 1/2, vectorized ----
    const bool L1 = bx < 10;
    const float* in = L1 ? in1 : in2;
    const int W = L1 ? 38 : 76;
    const int HW = L1 ? 1444 : 5776;
    const int lvl_off = L1 ? 1083 : 5415;
    const float stride = L1 ? 16.f : 8.f;
    const int HW4 = HW >> 2;
    const int idx = (bx - (L1 ? 5 : 10)) * 256 + threadIdx.x;
    if (idx < 3 * HW4) {
      const int a = idx / HW4;
      const int p0 = (idx - a * HW4) << 2;
      const float* base = in + ((size_t)(img * 255 + a * 85)) * (size_t)HW + p0;
      float4 scv[DCH];
#pragma unroll
      for (int k = 0; k < DCH; ++k)
        scv[k] = *(const float4*)(base + (size_t)(5 + c0 + k) * HW);
      float4 v4 = *(const float4*)(base + 4 * (size_t)HW);
      const float* t4 = (const float*)&v4;
      float conf[4];
      if (c0 == 0) {
        const float aw = L1 ? ((a == 0) ? 1.875f : ((a == 1) ? 3.875f : 3.6875f))
                            : ((a == 0) ? 1.25f : ((a == 1) ? 2.f : 4.125f));
        const float ah = L1 ? ((a == 0) ? 3.8125f : ((a == 1) ? 2.8125f : 7.4375f))
                            : ((a == 0) ? 1.625f : ((a == 1) ? 3.75f : 2.875f));
        float4 v0 = *(const float4*)(base);
        float4 v1 = *(const float4*)(base + (size_t)HW);
        float4 v2 = *(const float4*)(base + 2 * (size_t)HW);
        float4 v3 = *(const float4*)(base + 3 * (size_t)HW);
        const float* t0 = (const float*)&v0;
        const float* t1 = (const float*)&v1;
        const float* t2 = (const float*)&v2;
        const float* t3 = (const float*)&v3;
        float4* bout = boxes + (size_t)img * NBOX + lvl_off + a * HW + p0;
#pragma unroll
        for (int i = 0; i < 4; ++i) {
          const int p = p0 + i;
          const int y = p / W, x = p - y * W;
          const float px = sigmf(t0[i]) + (float)x;
          const float py = sigmf(t1[i]) + (float)y;
          const float pw = expf(t2[i]) * aw;
          const float ph = expf(t3[i]) * ah;
          const float cx = px * stride, cy = py * stride, bw = pw * stride, bh = ph * stride;
          bout[i] = make_float4(cx - bw * 0.5f, cy - bh * 0.5f, cx + bw * 0.5f, cy + bh * 0.5f);
        }
      }
#pragma unroll
      for (int i = 0; i < 4; ++i) conf[i] = sigmf(t4[i]);
#pragma unroll
      for (int k = 0; k < DCH; ++k) {
        const float* s4 = (const float*)&scv[k];
#pragma unroll
        for (int i = 0; i < 4; ++i) {
          float s = conf[i] * sigmf(s4[i]);
          if (s > SCORE_TH) {
            u32 bin = (__float_as_uint(s) >> 14) - BIN_BASE;
            atomicAdd(&lh[bin], 1u);
          }
        }
      }
    }
  }
  __syncthreads();
  u32* gh = hist + (size_t)img * 4096;
  for (int i = threadIdx.x; i < 4096; i += 256) {
    u32 v = lh[i];
    if (v) atomicAdd(&gh[i], v);
  }
}

// ---- block-staged list flush: one global atomic per list per block ----
__device__ __forceinline__ void flush_list(const u64* llist, int lcnt, int cap,
                                           int* gctr, u64* glist, int gcap) {
  __shared__ int gbase_s;
  int n = lcnt < cap ? lcnt : cap;
  if (threadIdx.x == 0) gbase_s = n ? atomicAdd(gctr, n) : 0;
  __syncthreads();
  const int gb = gbase_s;
  for (int i = threadIdx.x; i < n; i += 256) {
    int pos = gb + i;
    if (pos < gcap) glist[pos] = llist[i];
  }
}

// ---------------- merged gather (all 3 levels) with fused boundary-bin scan ----------------
// Each block recomputes B from the (L2-resident) per-image histogram: identical
// deterministic result to the old scan_k, one fewer kernel launch.
__global__ __launch_bounds__(256) void gather_all(const float* __restrict__ in0,
                         const float* __restrict__ in1, const float* __restrict__ in2,
                         const u32* __restrict__ hist, int* __restrict__ cnt,
                         u64* __restrict__ winners, u64* __restrict__ boundary) {
  __shared__ u64 lwin[LCAP];
  __shared__ u64 lbnd[LCAP];
  __shared__ int lwc, lbc;
  __shared__ u32 s_wsum[4];
  __shared__ int sB;
  const int img = blockIdx.y;
  const int c0 = blockIdx.z * GCH;
  const int t = threadIdx.x;
  if (t == 0) { lwc = 0; lbc = 0; sB = -1; }

  // fused scan: B = boundary bin (suffix counts >= PREK), -1 if total < PREK
  {
    const u32* gh = hist + (size_t)img * 4096;
    u32 hv[16]; u32 s = 0;
#pragma unroll
    for (int j = 0; j < 16; ++j) { hv[j] = gh[t * 16 + j]; s += hv[j]; }
    const int lane = t & 63;
    u32 v = s;
#pragma unroll
    for (int off = 1; off < 64; off <<= 1) {
      u32 o = __shfl_down(v, off);
      if (lane + off < 64) v += o;
    }
    if (lane == 0) s_wsum[t >> 6] = v;   // wave suffix total
    __syncthreads();
    u32 hi = 0;
    for (int w = (t >> 6) + 1; w < 4; ++w) hi += s_wsum[w];
    const u32 above = hi + (v - s);      // strictly-above-this-group suffix sum
    if (above < (u32)PREK && above + s >= (u32)PREK) {
      u32 cum = above;
      for (int j = 15; j >= 0; --j) {
        cum += hv[j];
        if (cum >= (u32)PREK) { sB = t * 16 + j; break; }
      }
    }
    __syncthreads();
  }
  const int B = sB;

  int* cw = &cnt[img * 64];
  int* cb = &cnt[img * 64 + 32];
  u64* wl = winners + (size_t)img * PREK;
  u64* bl = boundary + (size_t)img * BCAP;
  const int bx = blockIdx.x;

  if (bx < 5) {
    // ---- level 0, scalar ----
    const int HW = 361;
    const int r = bx * 256 + t;
    if (r < 3 * HW) {
      const int a = r / HW, p = r - a * HW;
      const float* base = in0 + ((size_t)(img * 255 + a * 85)) * (size_t)HW + p;
      const int boxg = r;
      float l[GCH];
#pragma unroll
      for (int k = 0; k < GCH; ++k) l[k] = base[(size_t)(5 + c0 + k) * HW];
      const float conf = sigmf(base[4 * (size_t)HW]);
#pragma unroll
      for (int k = 0; k < GCH; ++k) {
        float s = conf * sigmf(l[k]);
        if (s > SCORE_TH) {
          u32 key = __float_as_uint(s);
          int wbin = (int)((key >> 14) - BIN_BASE);
          if (wbin >= B) {
            u64 kv = ((u64)key << 32) | (u64)(~(u32)(boxg * NCLS + (c0 + k)));
            if (wbin > B) {
              int p2 = atomicAdd(&lwc, 1);
              if (p2 < LCAP) lwin[p2] = kv;
              else { int g = atomicAdd(cw, 1); if (g < PREK) wl[g] = kv; }
            } else {
              int p2 = atomicAdd(&lbc, 1);
              if (p2 < LCAP) lbnd[p2] = kv;
              else { int g = atomicAdd(cb, 1); if (g < BCAP) bl[g] = kv; }
            }
          }
        }
      }
    }
  } else {
    // ---- levels 1/2, vectorized ----
    const bool L1 = bx < 10;
    const float* in = L1 ? in1 : in2;
    const int HW = L1 ? 1444 : 5776;
    const int lvl_off = L1 ? 1083 : 5415;
    const int HW4 = HW >> 2;
    const int idx = (bx - (L1 ? 5 : 10)) * 256 + t;
    if (idx < 3 * HW4) {
      const int a = idx / HW4;
      const int p0 = (idx - a * HW4) << 2;
      const float* base = in + ((size_t)(img * 255 + a * 85)) * (size_t)HW + p0;
      const int boxg0 = lvl_off + a * HW + p0;
      float4 scv[GCH];
#pragma unroll
      for (int k = 0; k < GCH; ++k)
        scv[k] = *(const float4*)(base + (size_t)(5 + c0 + k) * HW);
      float4 v4 = *(const float4*)(base + 4 * (size_t)HW);
      const float* t4 = (const float*)&v4;
      float conf[4];
#pragma unroll
      for (int i = 0; i < 4; ++i) conf[i] = sigmf(t4[i]);
#pragma unroll
      for (int k = 0; k < GCH; ++k) {
        const float* s4 = (const float*)&scv[k];
        const int c = c0 + k;
#pragma unroll
        for (int i = 0; i < 4; ++i) {
          float s = conf[i] * sigmf(s4[i]);
          if (s > SCORE_TH) {
            u32 key = __float_as_uint(s);
            int wbin = (int)((key >> 14) - BIN_BASE);
            if (wbin >= B) {
              u64 kv = ((u64)key << 32) | (u64)(~(u32)((boxg0 + i) * NCLS + c));
              if (wbin > B) {
                int p = atomicAdd(&lwc, 1);
                if (p < LCAP) lwin[p] = kv;
                else { int g = atomicAdd(cw, 1); if (g < PREK) wl[g] = kv; }
              } else {
                int p = atomicAdd(&lbc, 1);
                if (p < LCAP) lbnd[p] = kv;
                else { int g = atomicAdd(cb, 1); if (g < BCAP) bl[g] = kv; }
              }
            }
          }
        }
      }
    }
  }
  __syncthreads();
  flush_list(lwin, lwc, LCAP, cw, wl, PREK);
  flush_list(lbnd, lbc, LCAP, cb, bl, BCAP);
}

// ---------------- resolve boundary bin: pick exactly T more ----------------
// T = PREK - (#winners pushed by gather) == old scan_k's K - count(bins > B).
__global__ void resolve_k(const u64* __restrict__ boundary,
                          int* __restrict__ cnt, u64* __restrict__ winners) {
  const int img = blockIdx.x;
  const int cw_pre = cnt[img * 64];
  const int T = PREK - cw_pre;
  int bc = cnt[img * 64 + 32];
  if (bc > BCAP) bc = BCAP;
  if (T <= 0 || bc <= 0) return;
  const u64* bnd = boundary + (size_t)img * BCAP;
  u64* wl = winners + (size_t)img * PREK;
  int* cw = &cnt[img * 64];

  __shared__ u32 h2[16384];
  __shared__ u32 lsum[256];
  __shared__ u32 above[256];
  __shared__ u32 s_total;
  __shared__ int sB2, sT2;
  __shared__ u64 ties[512];
  __shared__ int tcnt;
  __shared__ u64 lw2[PREK];
  __shared__ int lw2c;
  __shared__ int gbase_s;
  const int t = threadIdx.x;
  for (int i = t; i < 16384; i += 256) h2[i] = 0;
  if (t == 0) { tcnt = 0; sB2 = -1; sT2 = 0; lw2c = 0; }
  __syncthreads();
  for (int i = t; i < bc; i += 256) atomicAdd(&h2[(u32)(bnd[i] >> 32) & 0x3FFFu], 1u);
  __syncthreads();
  u32 s = 0;
  for (int j = 0; j < 64; ++j) s += h2[t * 64 + j];
  lsum[t] = s;
  __syncthreads();
  if (t == 0) {
    u32 acc = 0;
    for (int i = 255; i >= 0; --i) { above[i] = acc; acc += lsum[i]; }
    s_total = acc;
  }
  __syncthreads();
  if ((int)s_total > T) {
    if (above[t] < (u32)T && above[t] + lsum[t] >= (u32)T) {
      u32 cum = above[t];
      for (int j = 63; j >= 0; --j) {
        u32 hv = h2[t * 64 + j];
        cum += hv;
        if (cum >= (u32)T) { sB2 = t * 64 + j; sT2 = (int)((u32)T - (cum - hv)); break; }
      }
    }
  }
  __syncthreads();
  const int B2 = sB2, T2 = sT2;
  for (int i = t; i < bc; i += 256) {
    u64 e = bnd[i];
    int low = (int)((u32)(e >> 32) & 0x3FFFu);
    if (low > B2) {
      int p = atomicAdd(&lw2c, 1);
      if (p < PREK) lw2[p] = e;
    } else if (low == B2) {
      int tp = atomicAdd(&tcnt, 1);
      if (tp < 512) ties[tp] = e;
    }
  }
  __syncthreads();
  int n = lw2c < PREK ? lw2c : PREK;
  if (t == 0) gbase_s = n ? atomicAdd(cw, n) : 0;
  __syncthreads();
  for (int i = t; i < n; i += 256) {
    int pos = gbase_s + i;
    if (pos < PREK) wl[pos] = lw2[i];
  }
  __syncthreads();
  if (t == 0 && T2 > 0) {
    int tc = tcnt < 512 ? tcnt : 512;
    for (int k = 0; k < T2 && k < tc; ++k) {
      int bi = -1; u64 bk = 0;
      for (int i = 0; i < tc; ++i)
        if (ties[i] > bk) { bk = ties[i]; bi = i; }  // same score => larger ~idx = smaller idx first
      if (bi < 0) break;
      ties[bi] = 0;
      int pos = atomicAdd(cw, 1);
      if (pos < PREK) wl[pos] = bk;
    }
  }
}

// ---------------- rank, split j-dimension: partial ranks (plain stores, no atomics) ----------------
__global__ __launch_bounds__(256) void rank_part_k(const u64* __restrict__ winners,
                                                   const int* __restrict__ cnt,
                                                   int* __restrict__ part) {
  __shared__ u64 lk[RJW];
  const int img = blockIdx.y;
  const int kc = blockIdx.x >> 2;       // 16 key-chunks of 256
  const int jc = blockIdx.x & 3;        // 4 j-chunks of 1024
  const int t = threadIdx.x;
  int wc = cnt[img * 64]; if (wc > PREK) wc = PREK;
  const u64* wl = winners + (size_t)img * PREK;
  for (int i = t; i < RJW; i += 256) {
    const int gj = jc * RJW + i;
    lk[i] = (gj < wc) ? wl[gj] : pad_key(gj);
  }
  __syncthreads();
  const int ki_idx = kc * 256 + t;
  const u64 ki = (ki_idx < wc) ? wl[ki_idx] : pad_key(ki_idx);
  int rank = 0;
#pragma unroll 8
  for (int j = 0; j < RJW; ++j) rank += (lk[j] > ki) ? 1 : 0;
  part[(((size_t)img * RJC) + jc) * PREK + ki_idx] = rank;
}

// ---------------- rank scatter: sum partials, write sorted arrays ----------------
__global__ __launch_bounds__(256) void rank_scatter_k(const u64* __restrict__ winners,
                                              const int* __restrict__ cnt,
                                              const int* __restrict__ part,
                                              const float4* __restrict__ boxes,
                                              u64* __restrict__ skey,
                                              float4* __restrict__ sobox,
                                              float* __restrict__ sarea) {
  const int img = blockIdx.y;
  const int i = blockIdx.x * 256 + threadIdx.x;
  int wc = cnt[img * 64]; if (wc > PREK) wc = PREK;
  const u64* wl = winners + (size_t)img * PREK;
  const u64 ki = (i < wc) ? wl[i] : pad_key(i);
  const int* pb = part + (size_t)img * RJC * PREK + i;
  int rank = pb[0] + pb[PREK] + pb[2 * PREK] + pb[3 * PREK];
  skey[(size_t)img * PREK + rank] = ki;
  if (i < wc) {
    u32 ridx = ~(u32)ki;
    int c = (int)(ridx % NCLS);
    int bi = (int)(ridx / NCLS);
    float4 b = boxes[(size_t)img * NBOX + bi];
    float off = 4096.0f * (float)c;
    float4 ob = make_float4(b.x + off, b.y + off, b.z + off, b.w + off);
    sobox[(size_t)img * PREK + rank] = ob;
    sarea[(size_t)img * PREK + rank] = (ob.z - ob.x) * (ob.w - ob.y);
  } else {
    sobox[(size_t)img * PREK + rank] = make_float4(0.f, 0.f, 0.f, 0.f);
    sarea[(size_t)img * PREK + rank] = 0.f;
  }
}

// ---------------- sorted-scan greedy NMS: ballot class-match + bit-iterated pairs ----------------
__global__ __launch_bounds__(64) void scan_nms_k(const u64* __restrict__ skey,
                                                 const float4* __restrict__ sobox,
                                                 const float* __restrict__ sarea,
                                                 float* __restrict__ out) {
  __shared__ float4 bxc[NCLS][BKCAP];
  __shared__ float  arc[NCLS][BKCAP];
  __shared__ int    cntc[NCLS];
  __shared__ float4 bxa[TOPK];
  __shared__ float  ara[TOPK];
  __shared__ float4 bxh[HCAP];
  __shared__ float  arh[HCAP];
  __shared__ int    nhuge_s;
  __shared__ float4 chb[64];
  __shared__ float  cha[64];
  const int img = blockIdx.x;
  const int lane = threadIdx.x;
  float* orow = out + (size_t)img * (TOPK * 6);
  for (int i = lane; i < TOPK * 6; i += 64) orow[i] = 0.f;
  for (int i = lane; i < NCLS; i += 64) cntc[i] = 0;
  if (lane == 0) nhuge_s = 0;
  const u64* K = skey + (size_t)img * PREK;
  const float4* Bp = sobox + (size_t)img * PREK;
  const float* Ap = sarea + (size_t)img * PREK;
  int nsel = 0;
  // software-pipelined chunk loads
  u64 kj = K[lane];
  float4 ob = Bp[lane];
  float ar = Ap[lane];
  for (int chunk = 0; chunk < PREK / 64 && nsel < TOPK; ++chunk) {
    u64 kj_n = 0ull; float4 ob_n = make_float4(0.f, 0.f, 0.f, 0.f); float ar_n = 0.f;
    if (chunk + 1 < PREK / 64) {
      const int jn = (chunk + 1) * 64 + lane;
      kj_n = K[jn]; ob_n = Bp[jn]; ar_n = Ap[jn];
    }
    const float score = __uint_as_float((u32)(kj >> 32));
    bool alive = (score > SCORE_TH);
    if (__ballot(alive) == 0ull) break;   // sorted: nothing below passes either
    const u32 ridx = ~(u32)kj;
    const int myc = (int)(ridx % NCLS);
    const bool huge = (ob.z - ob.x > HUGE_TH) || (ob.w - ob.y > HUGE_TH);
    chb[lane] = ob; cha[lane] = ar;   // single wave: no barrier needed

    // 7-ballot class-match matrix: mm bit jj = (class_jj == myc)
    u64 mm = ~0ull;
#pragma unroll
    for (int k = 0; k < 7; ++k) {
      const u64 bk = __ballot(((myc >> k) & 1) != 0);
      mm &= (((myc >> k) & 1) != 0) ? bk : ~bk;
    }
    const u64 hb = __ballot(huge);

    // phase 1a: same-class bucket walk (divergent per-lane loop; n<=8)
    {
      const int n0 = cntc[myc];
      const int n = n0 < BKCAP ? n0 : BKCAP;
      for (int k = 0; k < n && alive; ++k) {
        const float4 b0 = bxc[myc][k]; const float a0 = arc[myc][k];
        float xx1 = fmaxf(b0.x, ob.x), yy1 = fmaxf(b0.y, ob.y);
        float xx2 = fminf(b0.z, ob.z), yy2 = fminf(b0.w, ob.w);
        float inter = fmaxf(xx2 - xx1, 0.f) * fmaxf(yy2 - yy1, 0.f);
        float iou = inter / (a0 + ar - inter + 1e-9f);
        if (iou > IOU_TH) alive = false;
      }
    }
    // phase 1b: vs huge selected (uniform bound, usually 0)
    {
      const int nh = nhuge_s;
      for (int k = 0; k < nh; ++k) {
        if (alive) {
          const float4 b0 = bxh[k]; const float a0 = arh[k];
          float xx1 = fmaxf(b0.x, ob.x), yy1 = fmaxf(b0.y, ob.y);
          float xx2 = fminf(b0.z, ob.z), yy2 = fminf(b0.w, ob.w);
          float inter = fmaxf(xx2 - xx1, 0.f) * fmaxf(yy2 - yy1, 0.f);
          float iou = inter / (a0 + ar - inter + 1e-9f);
          if (iou > IOU_TH) alive = false;
        }
      }
    }
    // phase 1c: huge candidates vs ALL selected (rare)
    if (__ballot(alive && huge) != 0ull) {
      const int na = nsel;
      for (int k = 0; k < na; ++k) {
        if (alive && huge) {
          const float4 b0 = bxa[k]; const float a0 = ara[k];
          float xx1 = fmaxf(b0.x, ob.x), yy1 = fmaxf(b0.y, ob.y);
          float xx2 = fminf(b0.z, ob.z), yy2 = fminf(b0.w, ob.w);
          float inter = fmaxf(xx2 - xx1, 0.f) * fmaxf(yy2 - yy1, 0.f);
          float iou = inter / (a0 + ar - inter + 1e-9f);
          if (iou > IOU_TH) alive = false;
        }
      }
    }
    // in-chunk suppression: only same-class / huge pairs among still-alive lanes.
    const u64 amask = __ballot(alive);
    const u64 below = (1ull << lane) - 1ull;
    u64 tm = alive ? ((mm | hb | (huge ? ~0ull : 0ull)) & below & amask) : 0ull;
    u64 sup = 0ull;
    while (tm) {
      const int tb = (int)__builtin_ctzll(tm);
      tm &= tm - 1ull;
      const float4 bj = chb[tb];
      const float aj = cha[tb];
      float xx1 = fmaxf(bj.x, ob.x), yy1 = fmaxf(bj.y, ob.y);
      float xx2 = fminf(bj.z, ob.z), yy2 = fminf(bj.w, ob.w);
      float inter = fmaxf(xx2 - xx1, 0.f) * fmaxf(yy2 - yy1, 0.f);
      float iou = inter / (aj + ar - inter + 1e-9f);   // suppressor-first area sum (ref order)
      if (iou > IOU_TH) sup |= (1ull << tb);
    }
    // scalar greedy sweep (exact rank order; 1 ballot per selection)
    u64 rem = amask;
    u64 selbits = 0ull;
    while (rem != 0ull && nsel + (int)__popcll(selbits) < TOPK) {
      const int b = __builtin_ctzll(rem);
      selbits |= (1ull << b);
      rem &= ~(1ull << b);
      const u64 colb = __ballot((sup >> b) & 1ull);   // lanes suppressed by b
      rem &= ~colb;
    }
    // parallel commit
    const bool selme = (selbits >> lane) & 1ull;
    if (selme) {
      const int slot = nsel + (int)__popcll(selbits & ((1ull << lane) - 1ull));
      bxa[slot] = ob; ara[slot] = ar;
      if (!huge) {
        int cc = atomicAdd(&cntc[myc], 1);
        if (cc < BKCAP) { bxc[myc][cc] = ob; arc[myc][cc] = ar; }
        else { int hn = atomicAdd(&nhuge_s, 1); if (hn < HCAP) { bxh[hn] = ob; arh[hn] = ar; } }
      } else {
        int hn = atomicAdd(&nhuge_s, 1);
        if (hn < HCAP) { bxh[hn] = ob; arh[hn] = ar; }
      }
      const float off = 4096.0f * (float)myc;
      orow[slot * 6 + 0] = ob.x - off;
      orow[slot * 6 + 1] = ob.y - off;
      orow[slot * 6 + 2] = ob.z - off;
      orow[slot * 6 + 3] = ob.w - off;
      orow[slot * 6 + 4] = (float)myc;
      orow[slot * 6 + 5] = score;
    }
    nsel += (int)__popcll(selbits);
    kj = kj_n; ob = ob_n; ar = ar_n;
  }
}

extern "C" void kernel_launch(void* const* d_in, const int* in_sizes, int n_in,
                              void* d_out, int out_size, void* d_ws, size_t ws_size,
                              hipStream_t stream) {
  const float* in0 = (const float*)d_in[0];
  const float* in1 = (const float*)d_in[5];
  const float* in2 = (const float*)d_in[10];
  char* ws = (char*)d_ws;
  u32* hist = (u32*)(ws + HIST_OFF);
  int* cnt = (int*)(ws + CNT_OFF);
  u64* winners = (u64*)(ws + WIN_OFF);
  u64* boundary = (u64*)(ws + BND_OFF);
  int* part = (int*)(ws + PART_OFF);   // overlays boundary (safe: sequential kernels)
  float4* boxes = (float4*)(ws + BOX_OFF);
  u64* skey = (u64*)(ws + SKEY_OFF);
  float4* sobox = (float4*)(ws + SOBOX_OFF);
  float* sarea = (float*)(ws + SAREA_OFF);
  float* out = (float*)d_out;

  init_k<<<(ZERO_BYTES / 16 + 255) / 256, 256, 0, stream>>>((uint4*)ws);

  decode_hist_all<<<dim3(27, 8, DNCH), 256, 0, stream>>>(in0, in1, in2, boxes, hist);

  gather_all<<<dim3(27, 8, GNCH), 256, 0, stream>>>(in0, in1, in2, hist, cnt, winners, boundary);

  resolve_k<<<8, 256, 0, stream>>>(boundary, cnt, winners);

  rank_part_k<<<dim3(64, 8), 256, 0, stream>>>(winners, cnt, part);
  rank_scatter_k<<<dim3(16, 8), 256, 0, stream>>>(winners, cnt, part, boxes, skey, sobox, sarea);
  scan_nms_k<<<8, 64, 0, stream>>>(skey, sobox, sarea, out);
}

// Round 11
// 113.198 us; speedup vs baseline: 4.9623x; 1.0011x over previous
//
#include <hip/hip_runtime.h>
#include <stdint.h>

typedef unsigned int u32;
typedef unsigned long long u64;

#define NCLS 80
#define NBOX 22743
#define PREK 4096
#define BCAP 65536
#define NIMG 8
#define SCORE_TH 0.01f
#define IOU_TH 0.45f
#define TOPK 200

// class-chunking: decode = 4 chunks x 20 classes, gather = 8 chunks x 10 classes
#define DCH 20
#define DNCH 4
#define GCH 10
#define GNCH 8

// per-block LDS staging capacity for gather hit lists
#define LCAP 1536

// NMS class-bucket params (round-5 exactness proof)
#define BKCAP 8
#define HCAP 224
#define HUGE_TH 3488.0f

// rank split: 4 j-chunks of 1024 keys
#define RJC 4
#define RJW 1024

// stage-1 coarse score bins: (bits>>17)-7680; s in (0.01,1] -> [18,448] < 512.
// 8x fewer global merge atomics than bits>>14; resolve refines exactly.
#define CBINS 512
#define CBIN_BASE 7680u

// ---- workspace layout (bytes) ----
// hist u32[8][512] | cnt int[8][64] | winners | boundary(/part) | boxes | skey | sobox | sarea
#define HIST_OFF 0
#define CNT_OFF  16384
#define ZERO_BYTES 18432
#define WIN_OFF  18432
#define BND_OFF  280576
#define PART_OFF BND_OFF   // overlays boundary (consumed before rank phase)
#define BOX_OFF  4474880
#define SKEY_OFF 7385984
#define SOBOX_OFF 7648128
#define SAREA_OFF 8172416

__device__ __forceinline__ float sigmf(float x) { return 1.0f / (1.0f + expf(-x)); }

__device__ __forceinline__ u64 pad_key(int i) { return (u64)(~(u32)i); }  // below all real keys, distinct

// ---------------- workspace zero-init ----------------
__global__ __launch_bounds__(256) void init_k(uint4* __restrict__ ws) {
  const int i = blockIdx.x * 256 + threadIdx.x;
  if (i < ZERO_BYTES / 16) ws[i] = make_uint4(0u, 0u, 0u, 0u);
}

// ---------------- merged decode + coarse hist (all 3 levels), class-chunked ----------------
// blockIdx.x: [0,5) lvl0 scalar | [5,10) lvl1 v4 | [10,27) lvl2 v4
__global__ __launch_bounds__(256) void decode_hist_all(const float* __restrict__ in0,
                              const float* __restrict__ in1, const float* __restrict__ in2,
                              float4* __restrict__ boxes, u32* __restrict__ hist) {
  __shared__ u32 lh[CBINS];
  const int img = blockIdx.y;
  const int c0 = blockIdx.z * DCH;
  for (int i = threadIdx.x; i < CBINS; i += 256) lh[i] = 0;
  __syncthreads();

  const int bx = blockIdx.x;
  if (bx < 5) {
    // ---- level 0, scalar: W=19, HW=361, off=0, stride=32 ----
    const int W = 19, HW = 361;
    const int r = bx * 256 + threadIdx.x;
    if (r < 3 * HW) {
      const int a = r / HW, p = r - a * HW;
      const int y = p / W, x = p - y * W;
      const float* base = in0 + ((size_t)(img * 255 + a * 85)) * (size_t)HW + p;
      float l[DCH];
#pragma unroll
      for (int k = 0; k < DCH; ++k) l[k] = base[(size_t)(5 + c0 + k) * HW];
      const float x4 = base[4 * (size_t)HW];
      if (c0 == 0) {
        const float aw = (a == 0) ? 3.625f : ((a == 1) ? 4.875f : 11.65625f);
        const float ah = (a == 0) ? 2.8125f : ((a == 1) ? 6.1875f : 10.1875f);
        const float x0 = base[0];
        const float x1 = base[(size_t)HW];
        const float x2 = base[2 * (size_t)HW];
        const float x3 = base[3 * (size_t)HW];
        const float px = sigmf(x0) + (float)x;
        const float py = sigmf(x1) + (float)y;
        const float pw = expf(x2) * aw;
        const float ph = expf(x3) * ah;
        const float cx = px * 32.f, cy = py * 32.f, bw = pw * 32.f, bh = ph * 32.f;
        boxes[(size_t)img * NBOX + r] =
            make_float4(cx - bw * 0.5f, cy - bh * 0.5f, cx + bw * 0.5f, cy + bh * 0.5f);
      }
      const float conf = sigmf(x4);
      if (conf > SCORE_TH) {
#pragma unroll
        for (int k = 0; k < DCH; ++k) {
          float s = conf * sigmf(l[k]);
          if (s > SCORE_TH) {
            u32 bin = (__float_as_uint(s) >> 17) - CBIN_BASE;
            atomicAdd(&lh[bin], 1u);
          }
        }
      }
    }
  } else {
    // ---- levels 1/2, vectorized ----
    const bool L1 = bx < 10;
    const float* in = L1 ? in1 : in2;
    const int W = L1 ? 38 : 76;
    const int HW = L1 ? 1444 : 5776;
    const int lvl_off = L1 ? 1083 : 5415;
    const float stride = L1 ? 16.f : 8.f;
    const int HW4 = HW >> 2;
    const int idx = (bx - (L1 ? 5 : 10)) * 256 + threadIdx.x;
    if (idx < 3 * HW4) {
      const int a = idx / HW4;
      const int p0 = (idx - a * HW4) << 2;
      const float* base = in + ((size_t)(img * 255 + a * 85)) * (size_t)HW + p0;
      float4 scv[DCH];
#pragma unroll
      for (int k = 0; k < DCH; ++k)
        scv[k] = *(const float4*)(base + (size_t)(5 + c0 + k) * HW);
      float4 v4 = *(const float4*)(base + 4 * (size_t)HW);
      const float* t4 = (const float*)&v4;
      float conf[4];
      if (c0 == 0) {
        const float aw = L1 ? ((a == 0) ? 1.875f : ((a == 1) ? 3.875f : 3.6875f))
                            : ((a == 0) ? 1.25f : ((a == 1) ? 2.f : 4.125f));
        const float ah = L1 ? ((a == 0) ? 3.8125f : ((a == 1) ? 2.8125f : 7.4375f))
                            : ((a == 0) ? 1.625f : ((a == 1) ? 3.75f : 2.875f));
        float4 v0 = *(const float4*)(base);
        float4 v1 = *(const float4*)(base + (size_t)HW);
        float4 v2 = *(const float4*)(base + 2 * (size_t)HW);
        float4 v3 = *(const float4*)(base + 3 * (size_t)HW);
        const float* t0 = (const float*)&v0;
        const float* t1 = (const float*)&v1;
        const float* t2 = (const float*)&v2;
        const float* t3 = (const float*)&v3;
        float4* bout = boxes + (size_t)img * NBOX + lvl_off + a * HW + p0;
#pragma unroll
        for (int i = 0; i < 4; ++i) {
          const int p = p0 + i;
          const int y = p / W, x = p - y * W;
          const float px = sigmf(t0[i]) + (float)x;
          const float py = sigmf(t1[i]) + (float)y;
          const float pw = expf(t2[i]) * aw;
          const float ph = expf(t3[i]) * ah;
          const float cx = px * stride, cy = py * stride, bw = pw * stride, bh = ph * stride;
          bout[i] = make_float4(cx - bw * 0.5f, cy - bh * 0.5f, cx + bw * 0.5f, cy + bh * 0.5f);
        }
      }
#pragma unroll
      for (int i = 0; i < 4; ++i) conf[i] = sigmf(t4[i]);
#pragma unroll
      for (int k = 0; k < DCH; ++k) {
        const float* s4 = (const float*)&scv[k];
#pragma unroll
        for (int i = 0; i < 4; ++i) {
          float s = conf[i] * sigmf(s4[i]);
          if (s > SCORE_TH) {
            u32 bin = (__float_as_uint(s) >> 17) - CBIN_BASE;
            atomicAdd(&lh[bin], 1u);
          }
        }
      }
    }
  }
  __syncthreads();
  u32* gh = hist + (size_t)img * CBINS;
  for (int i = threadIdx.x; i < CBINS; i += 256) {
    u32 v = lh[i];
    if (v) atomicAdd(&gh[i], v);
  }
}

// ---- block-staged list flush: one global atomic per list per block ----
__device__ __forceinline__ void flush_list(const u64* llist, int lcnt, int cap,
                                           int* gctr, u64* glist, int gcap) {
  __shared__ int gbase_s;
  int n = lcnt < cap ? lcnt : cap;
  if (threadIdx.x == 0) gbase_s = n ? atomicAdd(gctr, n) : 0;
  __syncthreads();
  const int gb = gbase_s;
  for (int i = threadIdx.x; i < n; i += 256) {
    int pos = gb + i;
    if (pos < gcap) glist[pos] = llist[i];
  }
}

// ---------------- merged gather (all 3 levels) with fused coarse boundary-bin scan ----------------
__global__ __launch_bounds__(256) void gather_all(const float* __restrict__ in0,
                         const float* __restrict__ in1, const float* __restrict__ in2,
                         const u32* __restrict__ hist, int* __restrict__ cnt,
                         u64* __restrict__ winners, u64* __restrict__ boundary) {
  __shared__ u64 lwin[LCAP];
  __shared__ u64 lbnd[LCAP];
  __shared__ int lwc, lbc;
  __shared__ u32 s_wsum[4];
  __shared__ int sB;
  const int img = blockIdx.y;
  const int c0 = blockIdx.z * GCH;
  const int t = threadIdx.x;
  if (t == 0) { lwc = 0; lbc = 0; sB = -1; }

  // fused scan over 512 coarse bins: B = boundary bin (suffix count crosses PREK)
  {
    const u32* gh = hist + (size_t)img * CBINS;
    u32 hv0 = gh[t * 2], hv1 = gh[t * 2 + 1];
    u32 s = hv0 + hv1;
    const int lane = t & 63;
    u32 v = s;
#pragma unroll
    for (int off = 1; off < 64; off <<= 1) {
      u32 o = __shfl_down(v, off);
      if (lane + off < 64) v += o;
    }
    if (lane == 0) s_wsum[t >> 6] = v;
    __syncthreads();
    u32 hi = 0;
    for (int w = (t >> 6) + 1; w < 4; ++w) hi += s_wsum[w];
    const u32 above = hi + (v - s);
    if (above < (u32)PREK && above + s >= (u32)PREK) {
      u32 cum = above + hv1;
      if (cum >= (u32)PREK) sB = t * 2 + 1;
      else sB = t * 2;
    }
    __syncthreads();
  }
  const int B = sB;

  int* cw = &cnt[img * 64];
  int* cb = &cnt[img * 64 + 32];
  u64* wl = winners + (size_t)img * PREK;
  u64* bl = boundary + (size_t)img * BCAP;
  const int bx = blockIdx.x;

  if (bx < 5) {
    // ---- level 0, scalar ----
    const int HW = 361;
    const int r = bx * 256 + t;
    if (r < 3 * HW) {
      const int a = r / HW, p = r - a * HW;
      const float* base = in0 + ((size_t)(img * 255 + a * 85)) * (size_t)HW + p;
      const int boxg = r;
      float l[GCH];
#pragma unroll
      for (int k = 0; k < GCH; ++k) l[k] = base[(size_t)(5 + c0 + k) * HW];
      const float conf = sigmf(base[4 * (size_t)HW]);
#pragma unroll
      for (int k = 0; k < GCH; ++k) {
        float s = conf * sigmf(l[k]);
        if (s > SCORE_TH) {
          u32 key = __float_as_uint(s);
          int wbin = (int)((key >> 17) - CBIN_BASE);
          if (wbin >= B) {
            u64 kv = ((u64)key << 32) | (u64)(~(u32)(boxg * NCLS + (c0 + k)));
            if (wbin > B) {
              int p2 = atomicAdd(&lwc, 1);
              if (p2 < LCAP) lwin[p2] = kv;
              else { int g = atomicAdd(cw, 1); if (g < PREK) wl[g] = kv; }
            } else {
              int p2 = atomicAdd(&lbc, 1);
              if (p2 < LCAP) lbnd[p2] = kv;
              else { int g = atomicAdd(cb, 1); if (g < BCAP) bl[g] = kv; }
            }
          }
        }
      }
    }
  } else {
    // ---- levels 1/2, vectorized ----
    const bool L1 = bx < 10;
    const float* in = L1 ? in1 : in2;
    const int HW = L1 ? 1444 : 5776;
    const int lvl_off = L1 ? 1083 : 5415;
    const int HW4 = HW >> 2;
    const int idx = (bx - (L1 ? 5 : 10)) * 256 + t;
    if (idx < 3 * HW4) {
      const int a = idx / HW4;
      const int p0 = (idx - a * HW4) << 2;
      const float* base = in + ((size_t)(img * 255 + a * 85)) * (size_t)HW + p0;
      const int boxg0 = lvl_off + a * HW + p0;
      float4 scv[GCH];
#pragma unroll
      for (int k = 0; k < GCH; ++k)
        scv[k] = *(const float4*)(base + (size_t)(5 + c0 + k) * HW);
      float4 v4 = *(const float4*)(base + 4 * (size_t)HW);
      const float* t4 = (const float*)&v4;
      float conf[4];
#pragma unroll
      for (int i = 0; i < 4; ++i) conf[i] = sigmf(t4[i]);
#pragma unroll
      for (int k = 0; k < GCH; ++k) {
        const float* s4 = (const float*)&scv[k];
        const int c = c0 + k;
#pragma unroll
        for (int i = 0; i < 4; ++i) {
          float s = conf[i] * sigmf(s4[i]);
          if (s > SCORE_TH) {
            u32 key = __float_as_uint(s);
            int wbin = (int)((key >> 17) - CBIN_BASE);
            if (wbin >= B) {
              u64 kv = ((u64)key << 32) | (u64)(~(u32)((boxg0 + i) * NCLS + c));
              if (wbin > B) {
                int p = atomicAdd(&lwc, 1);
                if (p < LCAP) lwin[p] = kv;
                else { int g = atomicAdd(cw, 1); if (g < PREK) wl[g] = kv; }
              } else {
                int p = atomicAdd(&lbc, 1);
                if (p < LCAP) lbnd[p] = kv;
                else { int g = atomicAdd(cb, 1); if (g < BCAP) bl[g] = kv; }
              }
            }
          }
        }
      }
    }
  }
  __syncthreads();
  flush_list(lwin, lwc, LCAP, cw, wl, PREK);
  flush_list(lbnd, lbc, LCAP, cb, bl, BCAP);
}

// ---------------- resolve boundary bin: pick exactly T more ----------------
// T = PREK - (#winners from gather). Refine on score bits [3,17) (8-ULP sub-bins);
// ties list sorts by FULL u64 key (score low bits then smaller idx) => exact.
__global__ void resolve_k(const u64* __restrict__ boundary,
                          int* __restrict__ cnt, u64* __restrict__ winners) {
  const int img = blockIdx.x;
  const int cw_pre = cnt[img * 64];
  const int T = PREK - cw_pre;
  int bc = cnt[img * 64 + 32];
  if (bc > BCAP) bc = BCAP;
  if (T <= 0 || bc <= 0) return;
  const u64* bnd = boundary + (size_t)img * BCAP;
  u64* wl = winners + (size_t)img * PREK;
  int* cw = &cnt[img * 64];

  __shared__ u32 h2[16384];
  __shared__ u32 lsum[256];
  __shared__ u32 above[256];
  __shared__ u32 s_total;
  __shared__ int sB2, sT2;
  __shared__ u64 ties[512];
  __shared__ int tcnt;
  __shared__ u64 lw2[PREK];
  __shared__ int lw2c;
  __shared__ int gbase_s;
  const int t = threadIdx.x;
  for (int i = t; i < 16384; i += 256) h2[i] = 0;
  if (t == 0) { tcnt = 0; sB2 = -1; sT2 = 0; lw2c = 0; }
  __syncthreads();
  for (int i = t; i < bc; i += 256) atomicAdd(&h2[(u32)(bnd[i] >> 35) & 0x3FFFu], 1u);
  __syncthreads();
  u32 s = 0;
  for (int j = 0; j < 64; ++j) s += h2[t * 64 + j];
  lsum[t] = s;
  __syncthreads();
  if (t == 0) {
    u32 acc = 0;
    for (int i = 255; i >= 0; --i) { above[i] = acc; acc += lsum[i]; }
    s_total = acc;
  }
  __syncthreads();
  if ((int)s_total > T) {
    if (above[t] < (u32)T && above[t] + lsum[t] >= (u32)T) {
      u32 cum = above[t];
      for (int j = 63; j >= 0; --j) {
        u32 hv = h2[t * 64 + j];
        cum += hv;
        if (cum >= (u32)T) { sB2 = t * 64 + j; sT2 = (int)((u32)T - (cum - hv)); break; }
      }
    }
  }
  __syncthreads();
  const int B2 = sB2, T2 = sT2;
  for (int i = t; i < bc; i += 256) {
    u64 e = bnd[i];
    int low = (int)((u32)(e >> 35) & 0x3FFFu);
    if (low > B2) {
      int p = atomicAdd(&lw2c, 1);
      if (p < PREK) lw2[p] = e;
    } else if (low == B2) {
      int tp = atomicAdd(&tcnt, 1);
      if (tp < 512) ties[tp] = e;
    }
  }
  __syncthreads();
  int n = lw2c < PREK ? lw2c : PREK;
  if (t == 0) gbase_s = n ? atomicAdd(cw, n) : 0;
  __syncthreads();
  for (int i = t; i < n; i += 256) {
    int pos = gbase_s + i;
    if (pos < PREK) wl[pos] = lw2[i];
  }
  __syncthreads();
  if (t == 0 && T2 > 0) {
    int tc = tcnt < 512 ? tcnt : 512;
    for (int k = 0; k < T2 && k < tc; ++k) {
      int bi = -1; u64 bk = 0;
      for (int i = 0; i < tc; ++i)
        if (ties[i] > bk) { bk = ties[i]; bi = i; }  // same score => larger ~idx = smaller idx first
      if (bi < 0) break;
      ties[bi] = 0;
      int pos = atomicAdd(cw, 1);
      if (pos < PREK) wl[pos] = bk;
    }
  }
}

// ---------------- rank, split j-dimension: partial ranks (plain stores, no atomics) ----------------
__global__ __launch_bounds__(256) void rank_part_k(const u64* __restrict__ winners,
                                                   const int* __restrict__ cnt,
                                                   int* __restrict__ part) {
  __shared__ u64 lk[RJW];
  const int img = blockIdx.y;
  const int kc = blockIdx.x >> 2;       // 16 key-chunks of 256
  const int jc = blockIdx.x & 3;        // 4 j-chunks of 1024
  const int t = threadIdx.x;
  int wc = cnt[img * 64]; if (wc > PREK) wc = PREK;
  const u64* wl = winners + (size_t)img * PREK;
  for (int i = t; i < RJW; i += 256) {
    const int gj = jc * RJW + i;
    lk[i] = (gj < wc) ? wl[gj] : pad_key(gj);
  }
  __syncthreads();
  const int ki_idx = kc * 256 + t;
  const u64 ki = (ki_idx < wc) ? wl[ki_idx] : pad_key(ki_idx);
  int rank = 0;
#pragma unroll 8
  for (int j = 0; j < RJW; ++j) rank += (lk[j] > ki) ? 1 : 0;
  part[(((size_t)img * RJC) + jc) * PREK + ki_idx] = rank;
}

// ---------------- rank scatter: sum partials, write sorted arrays ----------------
__global__ __launch_bounds__(256) void rank_scatter_k(const u64* __restrict__ winners,
                                              const int* __restrict__ cnt,
                                              const int* __restrict__ part,
                                              const float4* __restrict__ boxes,
                                              u64* __restrict__ skey,
                                              float4* __restrict__ sobox,
                                              float* __restrict__ sarea) {
  const int img = blockIdx.y;
  const int i = blockIdx.x * 256 + threadIdx.x;
  int wc = cnt[img * 64]; if (wc > PREK) wc = PREK;
  const u64* wl = winners + (size_t)img * PREK;
  const u64 ki = (i < wc) ? wl[i] : pad_key(i);
  const int* pb = part + (size_t)img * RJC * PREK + i;
  int rank = pb[0] + pb[PREK] + pb[2 * PREK] + pb[3 * PREK];
  skey[(size_t)img * PREK + rank] = ki;
  if (i < wc) {
    u32 ridx = ~(u32)ki;
    int c = (int)(ridx % NCLS);
    int bi = (int)(ridx / NCLS);
    float4 b = boxes[(size_t)img * NBOX + bi];
    float off = 4096.0f * (float)c;
    float4 ob = make_float4(b.x + off, b.y + off, b.z + off, b.w + off);
    sobox[(size_t)img * PREK + rank] = ob;
    sarea[(size_t)img * PREK + rank] = (ob.z - ob.x) * (ob.w - ob.y);
  } else {
    sobox[(size_t)img * PREK + rank] = make_float4(0.f, 0.f, 0.f, 0.f);
    sarea[(size_t)img * PREK + rank] = 0.f;
  }
}

// ---------------- sorted-scan greedy NMS: ballot class-match + bit-iterated pairs ----------------
__global__ __launch_bounds__(64) void scan_nms_k(const u64* __restrict__ skey,
                                                 const float4* __restrict__ sobox,
                                                 const float* __restrict__ sarea,
                                                 float* __restrict__ out) {
  __shared__ float4 bxc[NCLS][BKCAP];
  __shared__ float  arc[NCLS][BKCAP];
  __shared__ int    cntc[NCLS];
  __shared__ float4 bxa[TOPK];
  __shared__ float  ara[TOPK];
  __shared__ float4 bxh[HCAP];
  __shared__ float  arh[HCAP];
  __shared__ int    nhuge_s;
  __shared__ float4 chb[64];
  __shared__ float  cha[64];
  const int img = blockIdx.x;
  const int lane = threadIdx.x;
  float* orow = out + (size_t)img * (TOPK * 6);
  for (int i = lane; i < TOPK * 6; i += 64) orow[i] = 0.f;
  for (int i = lane; i < NCLS; i += 64) cntc[i] = 0;
  if (lane == 0) nhuge_s = 0;
  const u64* K = skey + (size_t)img * PREK;
  const float4* Bp = sobox + (size_t)img * PREK;
  const float* Ap = sarea + (size_t)img * PREK;
  int nsel = 0;
  u64 kj = K[lane];
  float4 ob = Bp[lane];
  float ar = Ap[lane];
  for (int chunk = 0; chunk < PREK / 64 && nsel < TOPK; ++chunk) {
    u64 kj_n = 0ull; float4 ob_n = make_float4(0.f, 0.f, 0.f, 0.f); float ar_n = 0.f;
    if (chunk + 1 < PREK / 64) {
      const int jn = (chunk + 1) * 64 + lane;
      kj_n = K[jn]; ob_n = Bp[jn]; ar_n = Ap[jn];
    }
    const float score = __uint_as_float((u32)(kj >> 32));
    bool alive = (score > SCORE_TH);
    if (__ballot(alive) == 0ull) break;   // sorted: nothing below passes either
    const u32 ridx = ~(u32)kj;
    const int myc = (int)(ridx % NCLS);
    const bool huge = (ob.z - ob.x > HUGE_TH) || (ob.w - ob.y > HUGE_TH);
    chb[lane] = ob; cha[lane] = ar;   // single wave: no barrier needed

    // 7-ballot class-match matrix
    u64 mm = ~0ull;
#pragma unroll
    for (int k = 0; k < 7; ++k) {
      const u64 bk = __ballot(((myc >> k) & 1) != 0);
      mm &= (((myc >> k) & 1) != 0) ? bk : ~bk;
    }
    const u64 hb = __ballot(huge);

    // phase 1a: same-class bucket walk (divergent; n<=8)
    {
      const int n0 = cntc[myc];
      const int n = n0 < BKCAP ? n0 : BKCAP;
      for (int k = 0; k < n && alive; ++k) {
        const float4 b0 = bxc[myc][k]; const float a0 = arc[myc][k];
        float xx1 = fmaxf(b0.x, ob.x), yy1 = fmaxf(b0.y, ob.y);
        float xx2 = fminf(b0.z, ob.z), yy2 = fminf(b0.w, ob.w);
        float inter = fmaxf(xx2 - xx1, 0.f) * fmaxf(yy2 - yy1, 0.f);
        float iou = inter / (a0 + ar - inter + 1e-9f);
        if (iou > IOU_TH) alive = false;
      }
    }
    // phase 1b: vs huge selected
    {
      const int nh = nhuge_s;
      for (int k = 0; k < nh; ++k) {
        if (alive) {
          const float4 b0 = bxh[k]; const float a0 = arh[k];
          float xx1 = fmaxf(b0.x, ob.x), yy1 = fmaxf(b0.y, ob.y);
          float xx2 = fminf(b0.z, ob.z), yy2 = fminf(b0.w, ob.w);
          float inter = fmaxf(xx2 - xx1, 0.f) * fmaxf(yy2 - yy1, 0.f);
          float iou = inter / (a0 + ar - inter + 1e-9f);
          if (iou > IOU_TH) alive = false;
        }
      }
    }
    // phase 1c: huge candidates vs ALL selected (rare)
    if (__ballot(alive && huge) != 0ull) {
      const int na = nsel;
      for (int k = 0; k < na; ++k) {
        if (alive && huge) {
          const float4 b0 = bxa[k]; const float a0 = ara[k];
          float xx1 = fmaxf(b0.x, ob.x), yy1 = fmaxf(b0.y, ob.y);
          float xx2 = fminf(b0.z, ob.z), yy2 = fminf(b0.w, ob.w);
          float inter = fmaxf(xx2 - xx1, 0.f) * fmaxf(yy2 - yy1, 0.f);
          float iou = inter / (a0 + ar - inter + 1e-9f);
          if (iou > IOU_TH) alive = false;
        }
      }
    }
    // in-chunk suppression: same-class / huge pairs among alive lanes
    const u64 amask = __ballot(alive);
    const u64 below = (1ull << lane) - 1ull;
    u64 tm = alive ? ((mm | hb | (huge ? ~0ull : 0ull)) & below & amask) : 0ull;
    u64 sup = 0ull;
    while (tm) {
      const int tb = (int)__builtin_ctzll(tm);
      tm &= tm - 1ull;
      const float4 bj = chb[tb];
      const float aj = cha[tb];
      float xx1 = fmaxf(bj.x, ob.x), yy1 = fmaxf(bj.y, ob.y);
      float xx2 = fminf(bj.z, ob.z), yy2 = fminf(bj.w, ob.w);
      float inter = fmaxf(xx2 - xx1, 0.f) * fmaxf(yy2 - yy1, 0.f);
      float iou = inter / (aj + ar - inter + 1e-9f);
      if (iou > IOU_TH) sup |= (1ull << tb);
    }
    // scalar greedy sweep
    u64 rem = amask;
    u64 selbits = 0ull;
    while (rem != 0ull && nsel + (int)__popcll(selbits) < TOPK) {
      const int b = __builtin_ctzll(rem);
      selbits |= (1ull << b);
      rem &= ~(1ull << b);
      const u64 colb = __ballot((sup >> b) & 1ull);
      rem &= ~colb;
    }
    // parallel commit
    const bool selme = (selbits >> lane) & 1ull;
    if (selme) {
      const int slot = nsel + (int)__popcll(selbits & ((1ull << lane) - 1ull));
      bxa[slot] = ob; ara[slot] = ar;
      if (!huge) {
        int cc = atomicAdd(&cntc[myc], 1);
        if (cc < BKCAP) { bxc[myc][cc] = ob; arc[myc][cc] = ar; }
        else { int hn = atomicAdd(&nhuge_s, 1); if (hn < HCAP) { bxh[hn] = ob; arh[hn] = ar; } }
      } else {
        int hn = atomicAdd(&nhuge_s, 1);
        if (hn < HCAP) { bxh[hn] = ob; arh[hn] = ar; }
      }
      const float off = 4096.0f * (float)myc;
      orow[slot * 6 + 0] = ob.x - off;
      orow[slot * 6 + 1] = ob.y - off;
      orow[slot * 6 + 2] = ob.z - off;
      orow[slot * 6 + 3] = ob.w - off;
      orow[slot * 6 + 4] = (float)myc;
      orow[slot * 6 + 5] = score;
    }
    nsel += (int)__popcll(selbits);
    kj = kj_n; ob = ob_n; ar = ar_n;
  }
}

extern "C" void kernel_launch(void* const* d_in, const int* in_sizes, int n_in,
                              void* d_out, int out_size, void* d_ws, size_t ws_size,
                              hipStream_t stream) {
  const float* in0 = (const float*)d_in[0];
  const float* in1 = (const float*)d_in[5];
  const float* in2 = (const float*)d_in[10];
  char* ws = (char*)d_ws;
  u32* hist = (u32*)(ws + HIST_OFF);
  int* cnt = (int*)(ws + CNT_OFF);
  u64* winners = (u64*)(ws + WIN_OFF);
  u64* boundary = (u64*)(ws + BND_OFF);
  int* part = (int*)(ws + PART_OFF);   // overlays boundary (safe: sequential kernels)
  float4* boxes = (float4*)(ws + BOX_OFF);
  u64* skey = (u64*)(ws + SKEY_OFF);
  float4* sobox = (float4*)(ws + SOBOX_OFF);
  float* sarea = (float*)(ws + SAREA_OFF);
  float* out = (float*)d_out;

  init_k<<<(ZERO_BYTES / 16 + 255) / 256, 256, 0, stream>>>((uint4*)ws);

  decode_hist_all<<<dim3(27, 8, DNCH), 256, 0, stream>>>(in0, in1, in2, boxes, hist);

  gather_all<<<dim3(27, 8, GNCH), 256, 0, stream>>>(in0, in1, in2, hist, cnt, winners, boundary);

  resolve_k<<<8, 256, 0, stream>>>(boundary, cnt, winners);

  rank_part_k<<<dim3(64, 8), 256, 0, stream>>>(winners, cnt, part);
  rank_scatter_k<<<dim3(16, 8), 256, 0, stream>>>(winners, cnt, part, boxes, skey, sobox, sarea);
  scan_nms_k<<<8, 64, 0, stream>>>(skey, sobox, sarea, out);
}